// Round 11
// baseline (2027.003 us; speedup 1.0000x reference)
//
#include <hip/hip_runtime.h>
#include <math.h>

#define LPAD  10240
#define NSEQ  10001
#define PADT  239
#define NPIX  10000

typedef unsigned short u16;
typedef __attribute__((ext_vector_type(8))) short short8;
typedef __attribute__((ext_vector_type(4))) float floatx4;

__device__ __forceinline__ float b2f(u16 u){ return __uint_as_float(((unsigned)u)<<16); }
__device__ __forceinline__ u16 f2b(float f){
    unsigned x = __float_as_uint(f);
    return (u16)((x + 0x7FFFu + ((x>>16)&1u)) >> 16);
}
__device__ __forceinline__ void gld16(const void* g, void* l){
    __builtin_amdgcn_global_load_lds(
        (const __attribute__((address_space(1))) unsigned int*)g,
        (__attribute__((address_space(3))) unsigned int*)l, 16, 0, 0);
}

// ---------------------------------------------------------------------------
// bf16 MFMA GEMM: C = A @ Bt^T (+bias)(+resid)(relu)(qscale). 64x128 tile,
// 4 waves, dbuf LDS, global_load_lds width-16 staging, k-slot XOR bank
// swizzle. Round-10: reverted to the round-8 BK=32 config — the BK=64
// 48KB-LDS variant zeroed bank conflicts but dropped occupancy 43->24%
// (conflicts were NOT the binding constraint; the barrier drain is, and
// it needs co-resident blocks to hide).
// ---------------------------------------------------------------------------
__global__ __launch_bounds__(256) void gemm_mfma(
    const u16* __restrict__ A, int lda, long sA,
    const u16* __restrict__ Bt, int ldb, long sB,
    void* __restrict__ Cv, int ldc, long sC,
    int M, int N, int K, int ksplit,
    const float* __restrict__ bias,
    const float* __restrict__ resid, int ldr,
    int relu, int qscale, int obf16, int atomic)
{
    __shared__ u16 As[2][64*32];
    __shared__ u16 Bs[2][128*32];

    int bz = blockIdx.z / ksplit;
    int ks = blockIdx.z - bz * ksplit;
    A  += (size_t)bz * sA;
    Bt += (size_t)bz * sB;

    int kchunk = (K + ksplit - 1) / ksplit;
    kchunk = (kchunk + 31) & ~31;
    int kbeg = ks * kchunk;
    int kend = kbeg + kchunk; if (kend > K) kend = K;

    int tid = threadIdx.x;
    int w = tid >> 6, lane = tid & 63;
    int wm = (w >> 1) * 32, wn = (w & 1) * 64;
    int m0 = blockIdx.y * 64, n0 = blockIdx.x * 128;

    int l4 = lane >> 2;
    // swizzled source k-offset: staging lane (row=l4, kpart=lane&3) fetches
    // global k-slot (kpart ^ (row&3)); LDS slot stays (row, kpart).
    int lk = (((lane & 3) ^ (l4 & 3)) * 8);
    int ra = w * 16 + l4;
    int rb = w * 32 + l4;
    int am0 = m0 + ra;      if (am0 > M-1) am0 = M-1;
    int bn0 = n0 + rb;      if (bn0 > N-1) bn0 = N-1;
    int bn1 = n0 + rb + 16; if (bn1 > N-1) bn1 = N-1;
    const u16* ag0 = A  + (size_t)am0 * lda + lk;
    const u16* bg0 = Bt + (size_t)bn0 * ldb + lk;
    const u16* bg1 = Bt + (size_t)bn1 * ldb + lk;
    int soA  = w * 512;
    int soB0 = w * 1024;
    int soB1 = w * 1024 + 512;

    floatx4 acc[2][4];
    #pragma unroll
    for (int i = 0; i < 2; i++)
        #pragma unroll
        for (int j = 0; j < 4; j++)
            acc[i][j] = (floatx4){0.f, 0.f, 0.f, 0.f};

    int arow = wm + (lane & 15);
    int nrow = wn + (lane & 15);
    // swizzled read k-offset: element kpart e = lane>>4 of tile row r lives
    // in slot e ^ (r&3); r&3 == lane&3 for all rows this lane reads.
    int koff = (((lane >> 4) ^ (lane & 3)) * 8);

    if (kbeg < kend) {
        gld16(ag0 + kbeg, &As[0][soA]);
        gld16(bg0 + kbeg, &Bs[0][soB0]);
        gld16(bg1 + kbeg, &Bs[0][soB1]);
    }
    __syncthreads();

    int cb = 0;
    for (int k0 = kbeg; k0 < kend; k0 += 32) {
        int kn = k0 + 32;
        if (kn < kend) {
            gld16(ag0 + kn, &As[cb ^ 1][soA]);
            gld16(bg0 + kn, &Bs[cb ^ 1][soB0]);
            gld16(bg1 + kn, &Bs[cb ^ 1][soB1]);
        }
        short8 af[2], bf[4];
        #pragma unroll
        for (int i = 0; i < 2; i++) af[i] = *(const short8*)&As[cb][(arow + i*16)*32 + koff];
        #pragma unroll
        for (int j = 0; j < 4; j++) bf[j] = *(const short8*)&Bs[cb][(nrow + j*16)*32 + koff];
        #pragma unroll
        for (int i = 0; i < 2; i++)
            #pragma unroll
            for (int j = 0; j < 4; j++)
                acc[i][j] = __builtin_amdgcn_mfma_f32_16x16x32_bf16(af[i], bf[j], acc[i][j], 0, 0, 0);
        __syncthreads();
        cb ^= 1;
    }

    float* Cf = (float*)Cv;
    u16*   Ch = (u16*)Cv;
    size_t cb2 = (size_t)bz * sC;
    int rbase = m0 + wm + (lane >> 4) * 4;
    int cbase = n0 + wn + (lane & 15);
    #pragma unroll
    for (int i = 0; i < 2; i++) {
        #pragma unroll
        for (int j = 0; j < 4; j++) {
            int col = cbase + j * 16;
            if (col >= N) continue;
            float bcol = bias ? bias[col] : 0.f;
            #pragma unroll
            for (int r = 0; r < 4; r++) {
                int row = rbase + i * 16 + r;
                if (row >= M) continue;
                float v = acc[i][j][r];
                if (qscale && col < 512) v *= 0.125f;
                v += bcol;
                if (resid) v += resid[(size_t)row * ldr + col];
                if (relu) v = fmaxf(v, 0.f);
                size_t ci = cb2 + (size_t)row * ldc + col;
                if (obf16) Ch[ci] = f2b(v);
                else if (atomic) atomicAdd(&Cf[ci], v);
                else Cf[ci] = v;
            }
        }
    }
}

// ---------------------------------------------------------------------------
// fp32 GEMM (Newton-Schulz chain + tiny gemms).
// C = alpha*A@B + diagc*I + bias + rescoef*resid.
// Round-10: barrier-free, no LDS. The operands (8x256x256 fp32 = 2MB/mat)
// are fully L2-resident; LDS staging was pure overhead (16 barrier drains
// per block at 2 blocks/CU). Each thread streams its A-row (broadcast
// across the 16 tx lanes, L1-hit) and B-panel directly with float4 loads —
// no drain points, compiler pipelines freely, occupancy uncapped by LDS.
// Per-acc summation is k-ascending exactly as before -> bit-identical.
// ---------------------------------------------------------------------------
__global__ __launch_bounds__(256) void gemm_big(
    const float* __restrict__ A, int lda, long sA,
    const float* __restrict__ B, int ldb, long sB,
    float* __restrict__ C, int ldc, long sC,
    int M, int N, int K,
    float alpha, float diagc,
    const float* __restrict__ bias,
    const float* __restrict__ resid, int ldr, long sR, float rescoef,
    int btrans)
{
    int bz = blockIdx.z;
    A += (size_t)bz * sA;
    B += (size_t)bz * sB;
    C += (size_t)bz * sC;

    int tid = threadIdx.x;
    int tx = tid & 15, ty = tid >> 4;
    int m  = blockIdx.y * 16 + ty;
    int n4 = blockIdx.x * 64 + tx * 4;

    if (m >= M) return;

    float acc[4] = {0.f, 0.f, 0.f, 0.f};
    const float* ap = A + (size_t)m * lda;

    if (!btrans) {
        #pragma unroll 4
        for (int k0 = 0; k0 < K; k0 += 4) {
            float4 a4 = *(const float4*)(ap + k0);
            const float* bp = B + (size_t)k0 * ldb + n4;
            float4 b0 = *(const float4*)(bp);
            float4 b1 = *(const float4*)(bp + ldb);
            float4 b2 = *(const float4*)(bp + 2 * (size_t)ldb);
            float4 b3 = *(const float4*)(bp + 3 * (size_t)ldb);
            acc[0] += a4.x * b0.x; acc[1] += a4.x * b0.y; acc[2] += a4.x * b0.z; acc[3] += a4.x * b0.w;
            acc[0] += a4.y * b1.x; acc[1] += a4.y * b1.y; acc[2] += a4.y * b1.z; acc[3] += a4.y * b1.w;
            acc[0] += a4.z * b2.x; acc[1] += a4.z * b2.y; acc[2] += a4.z * b2.z; acc[3] += a4.z * b2.w;
            acc[0] += a4.w * b3.x; acc[1] += a4.w * b3.y; acc[2] += a4.w * b3.z; acc[3] += a4.w * b3.w;
        }
    } else {
        const float* bp0 = B + (size_t)(n4 + 0) * ldb;
        const float* bp1 = B + (size_t)(n4 + 1) * ldb;
        const float* bp2 = B + (size_t)(n4 + 2) * ldb;
        const float* bp3 = B + (size_t)(n4 + 3) * ldb;
        #pragma unroll 4
        for (int k0 = 0; k0 < K; k0 += 4) {
            float4 a4 = *(const float4*)(ap + k0);
            float4 c0 = *(const float4*)(bp0 + k0);
            float4 c1 = *(const float4*)(bp1 + k0);
            float4 c2 = *(const float4*)(bp2 + k0);
            float4 c3 = *(const float4*)(bp3 + k0);
            acc[0] += a4.x * c0.x; acc[0] += a4.y * c0.y; acc[0] += a4.z * c0.z; acc[0] += a4.w * c0.w;
            acc[1] += a4.x * c1.x; acc[1] += a4.y * c1.y; acc[1] += a4.z * c1.z; acc[1] += a4.w * c1.w;
            acc[2] += a4.x * c2.x; acc[2] += a4.y * c2.y; acc[2] += a4.z * c2.z; acc[2] += a4.w * c2.w;
            acc[3] += a4.x * c3.x; acc[3] += a4.y * c3.y; acc[3] += a4.z * c3.z; acc[3] += a4.w * c3.w;
        }
    }

    #pragma unroll
    for (int j = 0; j < 4; j++) {
        int n = n4 + j;
        float v = alpha * acc[j];
        if (diagc != 0.f && m == n) v += diagc;
        if (bias) v += bias[n];
        if (resid) v += rescoef * resid[(size_t)bz * sR + (size_t)m * ldr + n];
        C[(size_t)m * ldc + n] = v;
    }
}

// ---------------------------------------------------------------------------
// Fused a1 chain (layer 0), wave-owns-rows; loads in groups of 8,
// __launch_bounds__(256,3).
// ---------------------------------------------------------------------------
__global__ __launch_bounds__(256, 3) void a1z_fused(
    const u16* __restrict__ QKVh, const u16* __restrict__ KLh,
    const u16* __restrict__ ZTh, float* __restrict__ OUT, int T0)
{
    __shared__ u16 Ps[64 * 264];

    int tid = threadIdx.x;
    int w = tid >> 6, lane = tid & 63;
    int lo = lane & 15, hi = lane >> 4;
    int koff = hi * 8;
    int hh = blockIdx.y;
    int tok0 = T0 + blockIdx.x * 64;

    int trow = tok0 + w * 16 + lo;
    if (trow > LPAD - 1) trow = LPAD - 1;

    const u16* qb = QKVh + (size_t)trow * 1536 + hh * 64 + koff;
    short8 aq0 = *(const short8*)(qb);
    short8 aq1 = *(const short8*)(qb + 32);

    floatx4 acc[16];
    #pragma unroll
    for (int j = 0; j < 16; j++) acc[j] = (floatx4){0.f, 0.f, 0.f, 0.f};

    const u16* klb = KLh + (size_t)hh * 256 * 64 + lo * 64 + koff;
    {
        short8 bk[8];
        #pragma unroll
        for (int j = 0; j < 8; j++) bk[j] = *(const short8*)(klb + (size_t)j * 1024);
        #pragma unroll
        for (int j = 0; j < 8; j++)
            acc[j] = __builtin_amdgcn_mfma_f32_16x16x32_bf16(aq0, bk[j], acc[j], 0, 0, 0);
    }
    {
        short8 bk[8];
        #pragma unroll
        for (int j = 0; j < 8; j++) bk[j] = *(const short8*)(klb + (size_t)(8 + j) * 1024);
        #pragma unroll
        for (int j = 0; j < 8; j++)
            acc[8 + j] = __builtin_amdgcn_mfma_f32_16x16x32_bf16(aq0, bk[j], acc[8 + j], 0, 0, 0);
    }
    {
        short8 bk[8];
        #pragma unroll
        for (int j = 0; j < 8; j++) bk[j] = *(const short8*)(klb + (size_t)j * 1024 + 32);
        #pragma unroll
        for (int j = 0; j < 8; j++)
            acc[j] = __builtin_amdgcn_mfma_f32_16x16x32_bf16(aq1, bk[j], acc[j], 0, 0, 0);
    }
    {
        short8 bk[8];
        #pragma unroll
        for (int j = 0; j < 8; j++) bk[j] = *(const short8*)(klb + (size_t)(8 + j) * 1024 + 32);
        #pragma unroll
        for (int j = 0; j < 8; j++)
            acc[8 + j] = __builtin_amdgcn_mfma_f32_16x16x32_bf16(aq1, bk[j], acc[8 + j], 0, 0, 0);
    }

    #pragma unroll
    for (int slot = 0; slot < 4; slot++) {
        float mx = acc[0][slot];
        #pragma unroll
        for (int j = 1; j < 16; j++) mx = fmaxf(mx, acc[j][slot]);
        mx = fmaxf(mx, __shfl_xor(mx, 1, 64));
        mx = fmaxf(mx, __shfl_xor(mx, 2, 64));
        mx = fmaxf(mx, __shfl_xor(mx, 4, 64));
        mx = fmaxf(mx, __shfl_xor(mx, 8, 64));
        float p[16];
        float s = 0.f;
        #pragma unroll
        for (int j = 0; j < 16; j++) { p[j] = __expf(acc[j][slot] - mx); s += p[j]; }
        s += __shfl_xor(s, 1, 64);
        s += __shfl_xor(s, 2, 64);
        s += __shfl_xor(s, 4, 64);
        s += __shfl_xor(s, 8, 64);
        float inv = 1.f / s;
        int row = w * 16 + hi * 4 + slot;
        #pragma unroll
        for (int j = 0; j < 16; j++)
            Ps[row * 264 + j * 16 + lo] = f2b(p[j] * inv);
    }
    // no barrier: each wave reads back only its own 16 rows (lgkmcnt orders it)

    floatx4 acc2[4];
    #pragma unroll
    for (int j = 0; j < 4; j++) acc2[j] = (floatx4){0.f, 0.f, 0.f, 0.f};
    const u16* ztb = ZTh + ((size_t)hh * 64 + lo) * 256 + koff;
    #pragma unroll
    for (int ks = 0; ks < 8; ks += 2) {
        short8 bz[8];
        #pragma unroll
        for (int j = 0; j < 4; j++)
            bz[j] = *(const short8*)(ztb + (size_t)j * 4096 + ks * 32);
        #pragma unroll
        for (int j = 0; j < 4; j++)
            bz[4 + j] = *(const short8*)(ztb + (size_t)j * 4096 + (ks + 1) * 32);
        short8 ap0 = *(const short8*)&Ps[(w * 16 + lo) * 264 + ks * 32 + koff];
        short8 ap1 = *(const short8*)&Ps[(w * 16 + lo) * 264 + (ks + 1) * 32 + koff];
        #pragma unroll
        for (int j = 0; j < 4; j++)
            acc2[j] = __builtin_amdgcn_mfma_f32_16x16x32_bf16(ap0, bz[j], acc2[j], 0, 0, 0);
        #pragma unroll
        for (int j = 0; j < 4; j++)
            acc2[j] = __builtin_amdgcn_mfma_f32_16x16x32_bf16(ap1, bz[4 + j], acc2[j], 0, 0, 0);
    }
    #pragma unroll
    for (int j = 0; j < 4; j++) {
        #pragma unroll
        for (int slot = 0; slot < 4; slot++) {
            int tok = tok0 + w * 16 + hi * 4 + slot;
            if (tok < LPAD)
                OUT[(size_t)tok * 512 + hh * 64 + j * 16 + lo] = acc2[j][slot];
        }
    }
}

// ---------------------------------------------------------------------------
__global__ __launch_bounds__(256) void ln_kernel(
    const float* __restrict__ X, float* __restrict__ OUT, u16* __restrict__ OUTH,
    const float* __restrict__ g, const float* __restrict__ b, int nrows)
{
    int row = blockIdx.x * 4 + (threadIdx.x >> 6);
    int lane = threadIdx.x & 63;
    if (row >= nrows) return;
    const float* xr = X + (size_t)row * 512;
    float v[8]; float s = 0.f, s2 = 0.f;
    #pragma unroll
    for (int i = 0; i < 8; i++) { float t = xr[lane + i * 64]; v[i] = t; s += t; s2 += t * t; }
    for (int o = 1; o < 64; o <<= 1) { s += __shfl_xor(s, o, 64); s2 += __shfl_xor(s2, o, 64); }
    float mu = s * (1.f / 512.f);
    float var = s2 * (1.f / 512.f) - mu * mu;
    float rs = rsqrtf(var + 1e-5f);
    float* orow = OUT + (size_t)row * 512;
    u16* hrow = OUTH + (size_t)row * 512;
    #pragma unroll
    for (int i = 0; i < 8; i++) {
        int j = lane + i * 64;
        float y = (v[i] - mu) * rs * g[j] + b[j];
        orow[j] = y;
        hrow[j] = f2b(y);
    }
}

// Landmark means from bf16 QKVh; writes fp32 and bf16 copies
__global__ __launch_bounds__(64) void landmarks_kernel(
    const u16* __restrict__ QKVh, float* __restrict__ QL, float* __restrict__ KL,
    u16* __restrict__ QLh, u16* __restrict__ KLh)
{
    int mm = blockIdx.x, hh = blockIdx.y;
    int d = threadIdx.x;
    const u16* base = QKVh + (size_t)(mm * 40) * 1536 + hh * 64 + d;
    float sq = 0.f, sk = 0.f;
    for (int li = 0; li < 40; li++) {
        sq += b2f(base[(size_t)li * 1536]);
        sk += b2f(base[(size_t)li * 1536 + 512]);
    }
    size_t o = ((size_t)hh * 256 + mm) * 64 + d;
    float q = sq * (1.f / 40.f), k = sk * (1.f / 40.f);
    QL[o] = q; KL[o] = k;
    QLh[o] = f2b(q); KLh[o] = f2b(k);
}

// a2 softmax: wave per row (256 cols), fp32 in place
__global__ __launch_bounds__(256) void softmax_a2(
    float* __restrict__ A2, int nrows)
{
    int row = blockIdx.x * 4 + (threadIdx.x >> 6);
    int lane = threadIdx.x & 63;
    if (row >= nrows) return;
    float* p = A2 + (size_t)row * 256 + lane * 4;
    float4 v = *(float4*)p;
    float mx = fmaxf(fmaxf(v.x, v.y), fmaxf(v.z, v.w));
    for (int o = 1; o < 64; o <<= 1) mx = fmaxf(mx, __shfl_xor(mx, o, 64));
    float4 e = make_float4(__expf(v.x - mx), __expf(v.y - mx),
                           __expf(v.z - mx), __expf(v.w - mx));
    float s = e.x + e.y + e.z + e.w;
    for (int o = 1; o < 64; o <<= 1) s += __shfl_xor(s, o, 64);
    float inv = 1.f / s;
    e.x *= inv; e.y *= inv; e.z *= inv; e.w *= inv;
    *(float4*)p = e;
}

// block-per-row softmax (wide rows) -> bf16 probs, single global read via
// LDS row staging, float4 loads, packed bf16 stores.
__global__ __launch_bounds__(256) void row_softmax_bf16(
    const float* __restrict__ S, u16* __restrict__ P, int ncols)
{
    __shared__ float buf[LPAD];
    __shared__ float sr[4];
    int row = blockIdx.x;
    const float* p = S + (size_t)row * ncols;
    u16* q = P + (size_t)row * ncols;
    int tid = threadIdx.x;

    float mx = -1e30f;
    for (int i = tid * 4; i < ncols; i += 1024) {
        float4 v = *(const float4*)(p + i);
        *(float4*)&buf[i] = v;
        mx = fmaxf(mx, fmaxf(fmaxf(v.x, v.y), fmaxf(v.z, v.w)));
    }
    for (int o = 1; o < 64; o <<= 1) mx = fmaxf(mx, __shfl_xor(mx, o, 64));
    if ((tid & 63) == 0) sr[tid >> 6] = mx;
    __syncthreads();
    mx = fmaxf(fmaxf(sr[0], sr[1]), fmaxf(sr[2], sr[3]));

    float s = 0.f;
    for (int i = tid * 4; i < ncols; i += 1024) {
        float4 v = *(const float4*)&buf[i];
        s += __expf(v.x - mx) + __expf(v.y - mx) + __expf(v.z - mx) + __expf(v.w - mx);
    }
    for (int o = 1; o < 64; o <<= 1) s += __shfl_xor(s, o, 64);
    __syncthreads();
    if ((tid & 63) == 0) sr[tid >> 6] = s;
    __syncthreads();
    s = sr[0] + sr[1] + sr[2] + sr[3];
    float inv = 1.f / s;

    for (int i = tid * 4; i < ncols; i += 1024) {
        float4 v = *(const float4*)&buf[i];
        ushort4 o4;
        o4.x = f2b(__expf(v.x - mx) * inv);
        o4.y = f2b(__expf(v.y - mx) * inv);
        o4.z = f2b(__expf(v.z - mx) * inv);
        o4.w = f2b(__expf(v.w - mx) * inv);
        *(ushort4*)(q + i) = o4;
    }
}

__global__ __launch_bounds__(256) void a2norms_kernel(
    const float* __restrict__ A2, float* __restrict__ scal)
{
    int hh = blockIdx.x, tid = threadIdx.x;
    const float* A = A2 + (size_t)hh * 65536;
    float rs = 0.f, cs = 0.f;
    for (int j = 0; j < 256; j++) {
        rs += fabsf(A[(size_t)tid * 256 + j]);
        cs += fabsf(A[(size_t)j * 256 + tid]);
    }
    __shared__ float sm[8];
    for (int o = 1; o < 64; o <<= 1) {
        rs = fmaxf(rs, __shfl_xor(rs, o, 64));
        cs = fmaxf(cs, __shfl_xor(cs, o, 64));
    }
    if ((tid & 63) == 0) { sm[tid >> 6] = rs; sm[4 + (tid >> 6)] = cs; }
    __syncthreads();
    if (tid == 0) {
        float rm = fmaxf(fmaxf(sm[0], sm[1]), fmaxf(sm[2], sm[3]));
        float cm = fmaxf(fmaxf(sm[4], sm[5]), fmaxf(sm[6], sm[7]));
        atomicMax((unsigned int*)&scal[0], __float_as_uint(rm));
        atomicMax((unsigned int*)&scal[1], __float_as_uint(cm));
    }
}

// z0 = a2^T / denom (fp32 only)
__global__ __launch_bounds__(256) void z0_kernel(
    const float* __restrict__ A2, const float* __restrict__ scal,
    float* __restrict__ Zf)
{
    int i = blockIdx.x, hh = blockIdx.y, j = threadIdx.x;
    float inv = 1.f / (scal[0] * scal[1]);
    Zf[((size_t)hh * 256 + i) * 256 + j] = A2[((size_t)hh * 256 + j) * 256 + i] * inv;
}

// Tiny fused a1@Z for layer 1 (single token)
__global__ __launch_bounds__(256) void a1z_single(
    const u16* __restrict__ QKVh, const float* __restrict__ KL,
    const float* __restrict__ ZM, float* __restrict__ OUT, int tok)
{
    int h = blockIdx.x, tid = threadIdx.x;
    __shared__ float q[64];
    __shared__ float p[256];
    __shared__ float red[4];
    if (tid < 64) q[tid] = b2f(QKVh[(size_t)tok * 1536 + h * 64 + tid]);
    __syncthreads();
    const float* kl = KL + ((size_t)h * 256 + tid) * 64;
    float s = 0.f;
    for (int d = 0; d < 64; d++) s += q[d] * kl[d];
    float mx = s;
    for (int o = 1; o < 64; o <<= 1) mx = fmaxf(mx, __shfl_xor(mx, o, 64));
    if ((tid & 63) == 0) red[tid >> 6] = mx;
    __syncthreads();
    mx = fmaxf(fmaxf(red[0], red[1]), fmaxf(red[2], red[3]));
    float e = __expf(s - mx);
    float sum = e;
    for (int o = 1; o < 64; o <<= 1) sum += __shfl_xor(sum, o, 64);
    __syncthreads();
    if ((tid & 63) == 0) red[tid >> 6] = sum;
    __syncthreads();
    sum = red[0] + red[1] + red[2] + red[3];
    p[tid] = e / sum;
    __syncthreads();
    if (tid < 64) {
        float a = 0.f;
        for (int j = 0; j < 256; j++) a += p[j] * ZM[((size_t)h * 256 + j) * 64 + tid];
        OUT[(size_t)tok * 512 + h * 64 + tid] = a;
    }
}

// Depthwise 33-tap token conv fused with the bf16 cast: reads the PV result
// (OUT fp32), adds the conv, writes OUTH bf16 directly.
__global__ __launch_bounds__(256) void conv_cast(
    const u16* __restrict__ QKVh, const float* __restrict__ OUT,
    u16* __restrict__ OUTH, const float* __restrict__ resw, int T0, int ntok)
{
    __shared__ u16 Vw[48][512];
    __shared__ float ws[264];
    int tid = threadIdx.x;
    int t0 = T0 + blockIdx.x * 16;
    int wv = tid >> 6, lnn = tid & 63;
    for (int r = wv; r < 48; r += 4) {
        int ts = t0 - 16 + r;
        short8 v = (short8){0,0,0,0,0,0,0,0};
        if (ts >= 0 && ts < LPAD)
            v = *(const short8*)(QKVh + (size_t)ts * 1536 + 1024 + lnn * 8);
        *(short8*)&Vw[r][lnn * 8] = v;
    }
    if (tid < 264) ws[tid] = resw[tid];
    __syncthreads();

    int c0 = tid * 2;
    int h = c0 >> 6;
    float wreg[33];
    #pragma unroll
    for (int r = 0; r < 33; r++) wreg[r] = ws[h * 33 + r];

    #pragma unroll 1
    for (int tk = 0; tk < 16; tk++) {
        int tok = t0 + tk;
        if (tok >= T0 + ntok) break;
        float a0 = 0.f, a1 = 0.f;
        #pragma unroll
        for (int r = 0; r < 33; r++) {
            unsigned pv = *(const unsigned*)&Vw[tk + r][c0];
            a0 += wreg[r] * __uint_as_float(pv << 16);
            a1 += wreg[r] * __uint_as_float(pv & 0xFFFF0000u);
        }
        float v0 = OUT[(size_t)tok * 512 + c0]     + a0;
        float v1 = OUT[(size_t)tok * 512 + c0 + 1] + a1;
        unsigned pk = ((unsigned)f2b(v1) << 16) | (unsigned)f2b(v0);
        *(unsigned*)&OUTH[(size_t)(tok - T0) * 512 + c0] = pk;
    }
}

// Old simple conv (layer 1, single token)
__global__ __launch_bounds__(256) void conv_res(
    const u16* __restrict__ QKVh, float* __restrict__ OUT,
    const float* __restrict__ resw, int t0, int ntok)
{
    int idx = blockIdx.x * 256 + threadIdx.x;
    if (idx >= ntok * 512) return;
    int tok = t0 + (idx >> 9);
    int c = idx & 511;
    int h = c >> 6;
    const u16* vbase = QKVh + 1024 + c;
    float acc = 0.f;
    #pragma unroll 1
    for (int r = 0; r < 33; r++) {
        int ts = tok - 16 + r;
        if (ts >= 0 && ts < LPAD)
            acc += resw[h * 33 + r] * b2f(vbase[(size_t)ts * 1536]);
    }
    OUT[(size_t)tok * 512 + c] += acc;
}

// V slice of QKVh -> Vt[h][d][t] (bf16)
__global__ __launch_bounds__(256) void vtrans(
    const u16* __restrict__ QKVh, u16* __restrict__ Vt)
{
    int t0 = blockIdx.x * 64, hh = blockIdx.y;
    __shared__ u16 tile[64][65];
    #pragma unroll
    for (int ii = 0; ii < 16; ii++) {
        int idx = threadIdx.x + ii * 256;
        int t = idx >> 6, d = idx & 63;
        tile[t][d] = QKVh[(size_t)(t0 + t) * 1536 + 1024 + hh * 64 + d];
    }
    __syncthreads();
    #pragma unroll
    for (int ii = 0; ii < 16; ii++) {
        int idx = threadIdx.x + ii * 256;
        int d = idx >> 6, t = idx & 63;
        Vt[((size_t)hh * 64 + d) * LPAD + t0 + t] = tile[t][d];
    }
}

// Combine PPEG weights: W49[tap][c] = w7 + w5(in range) + w3(in range)
__global__ void ppeg_combine(
    const float* __restrict__ w7, const float* __restrict__ w5,
    const float* __restrict__ w3, const float* __restrict__ b7,
    const float* __restrict__ b5, const float* __restrict__ b3,
    float* __restrict__ W49, float* __restrict__ BSUM)
{
    int idx = blockIdx.x * 256 + threadIdx.x;
    if (idx >= 49 * 512) return;
    int tap = idx >> 9, c = idx & 511;
    int dy = tap / 7 - 3, dx = tap % 7 - 3;
    float v = w7[c * 49 + tap];
    if (dy >= -2 && dy <= 2 && dx >= -2 && dx <= 2)
        v += w5[c * 25 + (dy + 2) * 5 + (dx + 2)];
    if (dy >= -1 && dy <= 1 && dx >= -1 && dx <= 1)
        v += w3[c * 9 + (dy + 1) * 3 + (dx + 1)];
    W49[tap * 512 + c] = v;
    if (tap == 0) BSUM[c] = b7[c] + b5[c] + b3[c];
}

// PPEG, tiled: block = 16x4 position tile x 64 channels, fully-unrolled
// float4 halo staging.
__global__ __launch_bounds__(256) void ppeg_tile(
    const float* __restrict__ S, float* __restrict__ O,
    const float* __restrict__ W49, const float* __restrict__ BSUM)
{
    __shared__ float Sw[10][22][64];
    int tid = threadIdx.x;
    int c = tid & 63;
    int sub = tid >> 6;
    int x0 = blockIdx.x * 16;
    int y0 = blockIdx.y * 4;
    int cg = blockIdx.z * 64;

    {
        int p = tid >> 4;
        int c4 = (tid & 15) * 4;
        #pragma unroll
        for (int i = 0; i < 14; i++) {
            int f = p + i * 16;
            if (f < 220) {
                int r = f / 22, xx = f - r * 22;
                int gy = y0 - 3 + r;
                int gx = x0 - 3 + xx;
                float4 v = make_float4(0.f, 0.f, 0.f, 0.f);
                if ((unsigned)gy < 100u && (unsigned)gx < 100u)
                    v = *(const float4*)(S + (size_t)(1 + gy * 100 + gx) * 512 + cg + c4);
                *(float4*)&Sw[r][xx][c4] = v;
            }
        }
    }
    float wreg[49];
    #pragma unroll
    for (int t = 0; t < 49; t++) wreg[t] = W49[t * 512 + cg + c];
    float bsum = BSUM[cg + c];
    __syncthreads();

    int xb = sub * 4;
    float acc[4][4];
    #pragma unroll
    for (int yy = 0; yy < 4; yy++)
        #pragma unroll
        for (int xq = 0; xq < 4; xq++)
            acc[yy][xq] = Sw[yy + 3][xb + xq + 3][c] + bsum;

    #pragma unroll
    for (int r = 0; r < 10; r++) {
        float v[10];
        #pragma unroll
        for (int j = 0; j < 10; j++) v[j] = Sw[r][xb + j][c];
        #pragma unroll
        for (int yy = 0; yy < 4; yy++) {
            int t = r - yy;
            if (t < 0 || t > 6) continue;
            #pragma unroll
            for (int dxt = 0; dxt < 7; dxt++) {
                float w = wreg[t * 7 + dxt];
                #pragma unroll
                for (int xq = 0; xq < 4; xq++)
                    acc[yy][xq] += v[xq + dxt] * w;
            }
        }
    }

    #pragma unroll
    for (int yy = 0; yy < 4; yy++) {
        int gy = y0 + yy;
        #pragma unroll
        for (int xq = 0; xq < 4; xq++) {
            int gx = x0 + xb + xq;
            if (gx < 100)
                O[(size_t)(1 + gy * 100 + gx) * 512 + cg + c] = acc[yy][xq];
        }
    }
}

__global__ __launch_bounds__(64) void final_kernel(
    const float* __restrict__ S, const float* __restrict__ g, const float* __restrict__ b,
    const float* __restrict__ w, const float* __restrict__ bb, float* __restrict__ out)
{
    int lane = threadIdx.x;
    float v[8]; float s = 0.f, s2 = 0.f;
    #pragma unroll
    for (int i = 0; i < 8; i++) { float t = S[lane + i * 64]; v[i] = t; s += t; s2 += t * t; }
    for (int o = 1; o < 64; o <<= 1) { s += __shfl_xor(s, o, 64); s2 += __shfl_xor(s2, o, 64); }
    float mu = s * (1.f / 512.f);
    float var = s2 * (1.f / 512.f) - mu * mu;
    float rs = rsqrtf(var + 1e-5f);
    float o0 = 0.f, o1 = 0.f;
    #pragma unroll
    for (int i = 0; i < 8; i++) {
        int j = lane + i * 64;
        float xn = (v[i] - mu) * rs * g[j] + b[j];
        o0 += xn * w[j * 2 + 0];
        o1 += xn * w[j * 2 + 1];
    }
    for (int o = 1; o < 64; o <<= 1) { o0 += __shfl_xor(o0, o, 64); o1 += __shfl_xor(o1, o, 64); }
    if (lane == 0) { out[0] = o0 + bb[0]; out[1] = o1 + bb[1]; }
}

__global__ void zerok(float* p, int n)
{
    int i = blockIdx.x * 256 + threadIdx.x;
    if (i < n) p[i] = 0.f;
}
__global__ void zero2k(float* p) { p[0] = 0.f; p[1] = 0.f; }
__global__ void copy512(float* dst, const float* src)
{
    int i = blockIdx.x * 256 + threadIdx.x;
    if (i < 512) dst[i] = src[i];
}
__global__ void cast_bf16(const float* __restrict__ src, u16* __restrict__ dst, int n)
{
    int i = (blockIdx.x * 256 + threadIdx.x) * 4;
    if (i >= n) return;
    float4 v = *(const float4*)(src + i);
    dst[i + 0] = f2b(v.x); dst[i + 1] = f2b(v.y);
    dst[i + 2] = f2b(v.z); dst[i + 3] = f2b(v.w);
}
// dst[b][c][r] = src[b][r][c]  (cast-transpose fp32 RxC -> bf16 CxR)
__global__ void castT(const float* __restrict__ src, u16* __restrict__ dst,
                      int R, int C, int nb)
{
    size_t idx = (size_t)blockIdx.x * 256 + threadIdx.x;
    size_t tot = (size_t)R * C * nb;
    if (idx >= tot) return;
    int rc = R * C;
    int b = (int)(idx / rc);
    int rem = (int)(idx - (size_t)b * rc);
    int c = rem / R, r = rem - c * R;
    dst[idx] = f2b(src[(size_t)b * rc + (size_t)r * C + c]);
}

// ---------------------------------------------------------------------------
extern "C" void kernel_launch(void* const* d_in, const int* in_sizes, int n_in,
                              void* d_out, int out_size, void* d_ws, size_t ws_size,
                              hipStream_t stream)
{
    const float* h     = (const float*)d_in[0];
    const float* fc1_w = (const float*)d_in[1];
    const float* fc1_b = (const float*)d_in[2];
    const float* cls   = (const float*)d_in[3];
    bool sigorder = (in_sizes[10] == 512 * 49);
    int i_l2 = sigorder ? 16 : 10;
    int i_pp = sigorder ? 10 : 16;
    const float* l_g[2]   = { (const float*)d_in[4], (const float*)d_in[i_l2 + 0] };
    const float* l_b[2]   = { (const float*)d_in[5], (const float*)d_in[i_l2 + 1] };
    const float* l_qkv[2] = { (const float*)d_in[6], (const float*)d_in[i_l2 + 2] };
    const float* l_ow[2]  = { (const float*)d_in[7], (const float*)d_in[i_l2 + 3] };
    const float* l_ob[2]  = { (const float*)d_in[8], (const float*)d_in[i_l2 + 4] };
    const float* l_rw[2]  = { (const float*)d_in[9], (const float*)d_in[i_l2 + 5] };
    const float* w7 = (const float*)d_in[i_pp + 0];
    const float* b7 = (const float*)d_in[i_pp + 1];
    const float* w5 = (const float*)d_in[i_pp + 2];
    const float* b5 = (const float*)d_in[i_pp + 3];
    const float* w3 = (const float*)d_in[i_pp + 4];
    const float* b3 = (const float*)d_in[i_pp + 5];
    const float* ng   = (const float*)d_in[22];
    const float* nbv  = (const float*)d_in[23];
    const float* fc2w = (const float*)d_in[24];
    const float* fc2b = (const float*)d_in[25];
    float* out = (float*)d_out;

    char* Wb = (char*)d_ws;
    size_t off = 0;
    auto allocB = [&](size_t bytes) { void* p = Wb + off; off = (off + bytes + 255) & ~(size_t)255; return p; };

    float* SEQ   = (float*)allocB((size_t)NSEQ * 512 * 4);
    float* XP    = (float*)allocB((size_t)LPAD * 512 * 4);
    u16*   XPh   = (u16*)  allocB((size_t)LPAD * 512 * 2);
    u16*   QKVh  = (u16*)  allocB((size_t)LPAD * 1536 * 2);
    float* QLKL  = (float*)allocB((size_t)262144 * 4);
    float* QL = QLKL, *KL = QLKL + 131072;
    u16*   QLKLh = (u16*)  allocB((size_t)262144 * 2);
    u16*   QLh = QLKLh, *KLh = QLKLh + 131072;
    float* A2   = (float*)allocB(524288 * 4);
    float* Zf0  = (float*)allocB(524288 * 4);
    float* Zf1  = (float*)allocB(524288 * 4);
    float* XZf  = (float*)allocB(524288 * 4);
    float* W2b  = (float*)allocB(524288 * 4);
    float* W3b  = (float*)allocB(524288 * 4);
    float* A3V  = (float*)allocB(131072 * 4);
    float* ZMATf= (float*)allocB(131072 * 4);
    u16*   ZMATt= (u16*)  allocB(131072 * 2);
    u16*   Vt   = (u16*)  allocB((size_t)8 * 64 * LPAD * 2);
    u16*   fc1wt= (u16*)  allocB(524288 * 2);
    u16*   qkvwt= (u16*)  allocB(786432 * 2);
    u16*   outwt= (u16*)  allocB(262144 * 2);
    float* W49  = (float*)allocB(49 * 512 * 4);
    float* BSUM = (float*)allocB(512 * 4);
    float* SCAL = (float*)allocB(16);
    void*  U1   = allocB((size_t)LPAD * 512 * 4);
    u16*   hbf  = (u16*)U1;
    float* OUT  = (float*)U1;
    float* SEQ2 = OUT;
    size_t fixed = off;

    size_t scB_b = (size_t)8 * 256 * LPAD * 4;
    size_t phB_b = (size_t)8 * 256 * LPAD * 2;
    bool batched = ws_size >= fixed + scB_b + phB_b;
    float* SC; u16* Ph;
    if (batched) {
        SC = (float*)(Wb + fixed);
        Ph = (u16*)(Wb + fixed + scB_b);
    } else {
        SC = (float*)(Wb + fixed);
        Ph = (u16*)(Wb + fixed + (size_t)256 * LPAD * 4);
    }
    u16* OUTh = (u16*)SC;   // alias: SC dead when OUTh materialized

    auto mgemm = [&](const u16* A, int lda, long sA, const u16* Bt, int ldb, long sB,
                     void* C, int ldc, long sC, int M, int N, int K,
                     const float* bias, const float* resid, int ldr,
                     int relu, int qscale, int obf16, int nbatch, int ksplit, int atomic) {
        dim3 grid((N + 127) / 128, (M + 63) / 64, nbatch * ksplit);
        gemm_mfma<<<grid, 256, 0, stream>>>(A, lda, sA, Bt, ldb, sB, C, ldc, sC,
            M, N, K, ksplit, bias, resid, ldr, relu, qscale, obf16, atomic);
    };
    auto fgemm = [&](const float* A, int lda, long sA, const float* B, int ldb, long sB,
                     float* C, int ldc, long sC, int M, int N, int K,
                     float alpha, float diagc, const float* bias,
                     const float* resid, int ldr, long sR, float rescoef,
                     int btrans, int nbatch) {
        dim3 grid(N / 64, (M + 15) / 16, nbatch);
        gemm_big<<<grid, 256, 0, stream>>>(A, lda, sA, B, ldb, sB, C, ldc, sC, M, N, K,
            alpha, diagc, bias, resid, ldr, sR, rescoef, btrans);
    };

    // ---- prologue
    cast_bf16<<<(NPIX * 1024 / 4 + 255) / 256, 256, 0, stream>>>(h, hbf, NPIX * 1024);
    castT<<<(524288 + 255) / 256, 256, 0, stream>>>(fc1_w, fc1wt, 1024, 512, 1);
    mgemm(hbf, 1024, 0, fc1wt, 1024, 0, SEQ + 512, 512, 0, NPIX, 512, 1024,
          fc1_b, nullptr, 0, 1, 0, 0, 1, 1, 0);
    copy512<<<2, 256, 0, stream>>>(SEQ, cls);
    zerok<<<(PADT * 512 + 255) / 256, 256, 0, stream>>>(XP, PADT * 512);
    zerok<<<(PADT * 256 + 255) / 256, 256, 0, stream>>>((float*)XPh, PADT * 256);
    ppeg_combine<<<(49 * 512 + 255) / 256, 256, 0, stream>>>(w7, w5, w3, b7, b5, b3, W49, BSUM);

    for (int layer = 0; layer < 2; layer++) {
        const float* curSEQ = (layer == 0) ? SEQ : SEQ2;
        ln_kernel<<<(NSEQ + 3) / 4, 256, 0, stream>>>(curSEQ, XP + (size_t)PADT * 512,
            XPh + (size_t)PADT * 512, l_g[layer], l_b[layer], NSEQ);
        castT<<<(786432 + 255) / 256, 256, 0, stream>>>(l_qkv[layer], qkvwt, 512, 1536, 1);
        mgemm(XPh, 512, 0, qkvwt, 512, 0, QKVh, 1536, 0, LPAD, 1536, 512,
              nullptr, nullptr, 0, 0, 1, 1, 1, 1, 0);
        landmarks_kernel<<<dim3(256, 8), 64, 0, stream>>>(QKVh, QL, KL, QLh, KLh);
        // a2 = softmax(ql @ kl^T)  (fp32)
        fgemm(QL, 64, 16384, KL, 64, 16384, A2, 256, 65536, 256, 256, 64,
              1.f, 0.f, nullptr, nullptr, 0, 0, 0.f, 1, 8);
        softmax_a2<<<512, 256, 0, stream>>>(A2, 2048);
        zero2k<<<1, 1, 0, stream>>>(SCAL);
        a2norms_kernel<<<8, 256, 0, stream>>>(A2, SCAL);
        z0_kernel<<<dim3(256, 8), 256, 0, stream>>>(A2, SCAL, Zf0);

        // Newton-Schulz: 6 fp32 iterations
        float* zc = Zf0; float* zn = Zf1;
        for (int it = 0; it < 6; it++) {
            fgemm(A2, 256, 65536, zc, 256, 65536, XZf, 256, 65536, 256, 256, 256,
                  1.f, 0.f, nullptr, nullptr, 0, 0, 0.f, 0, 8);
            fgemm(XZf, 256, 65536, XZf, 256, 65536, W2b, 256, 65536, 256, 256, 256,
                  1.f, 15.f, nullptr, XZf, 256, 65536, -7.f, 0, 8);
            fgemm(XZf, 256, 65536, W2b, 256, 65536, W3b, 256, 65536, 256, 256, 256,
                  -1.f, 13.f, nullptr, nullptr, 0, 0, 0.f, 0, 8);
            fgemm(zc, 256, 65536, W3b, 256, 65536, zn, 256, 65536, 256, 256, 256,
                  0.25f, 0.f, nullptr, nullptr, 0, 0, 0.f, 0, 8);
            float* t = zc; zc = zn; zn = t;
        }
        float* zfin = zc;

        // a3v = softmax(ql @ k^T) @ v  via MFMA
        vtrans<<<dim3(160, 8), 256, 0, stream>>>(QKVh, Vt);
        zerok<<<512, 256, 0, stream>>>(A3V, 131072);
        if (batched) {
            mgemm(QLh, 64, 16384, QKVh + 512, 1536, 64, SC, LPAD, (long)256 * LPAD,
                  256, LPAD, 64, nullptr, nullptr, 0, 0, 0, 0, 8, 1, 0);
            row_softmax_bf16<<<2048, 256, 0, stream>>>(SC, Ph, LPAD);
            mgemm(Ph, LPAD, (long)256 * LPAD, Vt, LPAD, (long)64 * LPAD, A3V, 64, 16384,
                  256, 64, LPAD, nullptr, nullptr, 0, 0, 0, 0, 8, 40, 1);
        } else {
            for (int hh = 0; hh < 8; hh++) {
                mgemm(QLh + (size_t)hh * 16384, 64, 0, QKVh + 512 + hh * 64, 1536, 0,
                      SC, LPAD, 0, 256, LPAD, 64, nullptr, nullptr, 0, 0, 0, 0, 1, 1, 0);
                row_softmax_bf16<<<256, 256, 0, stream>>>(SC, Ph, LPAD);
                mgemm(Ph, LPAD, 0, Vt + (size_t)hh * 64 * LPAD, LPAD, 0,
                      A3V + (size_t)hh * 16384, 64, 0, 256, 64, LPAD,
                      nullptr, nullptr, 0, 0, 0, 0, 1, 40, 1);
            }
        }
        // ZMAT = pinv(a2) @ a3v  (fp32)
        fgemm(zfin, 256, 65536, A3V, 64, 16384, ZMATf, 64, 16384, 256, 64, 256,
              1.f, 0.f, nullptr, nullptr, 0, 0, 0.f, 0, 8);

        if (layer == 0) {
            // Z^T bf16 for the fused a1 chain
            castT<<<(131072 + 255) / 256, 256, 0, stream>>>(ZMATf, ZMATt, 256, 64, 8);
            // fused scores+softmax+PZ: one launch, no SC/Ph traffic
            a1z_fused<<<dim3((NSEQ + 63) / 64, 8), 256, 0, stream>>>(
                QKVh, KLh, ZMATt, OUT, PADT);
            // conv + bf16 cast fused (writes OUTh directly)
            conv_cast<<<(NSEQ + 15) / 16, 256, 0, stream>>>(
                QKVh, OUT, OUTh, l_rw[0], PADT, NSEQ);
            castT<<<(262144 + 255) / 256, 256, 0, stream>>>(l_ow[0], outwt, 512, 512, 1);
            mgemm(OUTh, 512, 0, outwt, 512, 0, SEQ, 512, 0, NSEQ, 512, 512,
                  l_ob[0], XP + (size_t)PADT * 512, 512, 0, 0, 0, 1, 1, 0);
            // PPEG (tiled, unrolled float4 staging)
            ppeg_tile<<<dim3(7, 25, 8), 256, 0, stream>>>(SEQ, SEQ2, W49, BSUM);
            copy512<<<2, 256, 0, stream>>>(SEQ2, SEQ);
        } else {
            a1z_single<<<8, 256, 0, stream>>>(QKVh, KL, ZMATf, OUT, PADT);
            conv_res<<<2, 256, 0, stream>>>(QKVh, OUT, l_rw[1], PADT, 1);
            fgemm(OUT + (size_t)PADT * 512, 512, 0, l_ow[1], 512, 0, SEQ, 512, 0,
                  1, 512, 512, 1.f, 0.f, l_ob[1],
                  XP + (size_t)PADT * 512, 512, 0, 1.f, 0, 1);
        }
    }
    final_kernel<<<1, 64, 0, stream>>>(SEQ, ng, nbv, fc2w, fc2b, out);
    (void)n_in; (void)out_size;
}

// Round 12
// 1518.564 us; speedup vs baseline: 1.3348x; 1.3348x over previous
//
#include <hip/hip_runtime.h>
#include <math.h>

#define LPAD  10240
#define NSEQ  10001
#define PADT  239
#define NPIX  10000

typedef unsigned short u16;
typedef __attribute__((ext_vector_type(8))) short short8;
typedef __attribute__((ext_vector_type(4))) float floatx4;

__device__ __forceinline__ float b2f(u16 u){ return __uint_as_float(((unsigned)u)<<16); }
__device__ __forceinline__ u16 f2b(float f){
    unsigned x = __float_as_uint(f);
    return (u16)((x + 0x7FFFu + ((x>>16)&1u)) >> 16);
}
__device__ __forceinline__ void gld16(const void* g, void* l){
    __builtin_amdgcn_global_load_lds(
        (const __attribute__((address_space(1))) unsigned int*)g,
        (__attribute__((address_space(3))) unsigned int*)l, 16, 0, 0);
}

// ---------------------------------------------------------------------------
// bf16 MFMA GEMM: C = A @ Bt^T (+bias)(+resid)(relu)(qscale). 64x128 tile,
// 4 waves, dbuf LDS, global_load_lds width-16 staging, k-slot XOR bank
// swizzle (round-8 config — best measured).
// ---------------------------------------------------------------------------
__global__ __launch_bounds__(256) void gemm_mfma(
    const u16* __restrict__ A, int lda, long sA,
    const u16* __restrict__ Bt, int ldb, long sB,
    void* __restrict__ Cv, int ldc, long sC,
    int M, int N, int K, int ksplit,
    const float* __restrict__ bias,
    const float* __restrict__ resid, int ldr,
    int relu, int qscale, int obf16, int atomic)
{
    __shared__ u16 As[2][64*32];
    __shared__ u16 Bs[2][128*32];

    int bz = blockIdx.z / ksplit;
    int ks = blockIdx.z - bz * ksplit;
    A  += (size_t)bz * sA;
    Bt += (size_t)bz * sB;

    int kchunk = (K + ksplit - 1) / ksplit;
    kchunk = (kchunk + 31) & ~31;
    int kbeg = ks * kchunk;
    int kend = kbeg + kchunk; if (kend > K) kend = K;

    int tid = threadIdx.x;
    int w = tid >> 6, lane = tid & 63;
    int wm = (w >> 1) * 32, wn = (w & 1) * 64;
    int m0 = blockIdx.y * 64, n0 = blockIdx.x * 128;

    int l4 = lane >> 2;
    int lk = (((lane & 3) ^ (l4 & 3)) * 8);
    int ra = w * 16 + l4;
    int rb = w * 32 + l4;
    int am0 = m0 + ra;      if (am0 > M-1) am0 = M-1;
    int bn0 = n0 + rb;      if (bn0 > N-1) bn0 = N-1;
    int bn1 = n0 + rb + 16; if (bn1 > N-1) bn1 = N-1;
    const u16* ag0 = A  + (size_t)am0 * lda + lk;
    const u16* bg0 = Bt + (size_t)bn0 * ldb + lk;
    const u16* bg1 = Bt + (size_t)bn1 * ldb + lk;
    int soA  = w * 512;
    int soB0 = w * 1024;
    int soB1 = w * 1024 + 512;

    floatx4 acc[2][4];
    #pragma unroll
    for (int i = 0; i < 2; i++)
        #pragma unroll
        for (int j = 0; j < 4; j++)
            acc[i][j] = (floatx4){0.f, 0.f, 0.f, 0.f};

    int arow = wm + (lane & 15);
    int nrow = wn + (lane & 15);
    int koff = (((lane >> 4) ^ (lane & 3)) * 8);

    if (kbeg < kend) {
        gld16(ag0 + kbeg, &As[0][soA]);
        gld16(bg0 + kbeg, &Bs[0][soB0]);
        gld16(bg1 + kbeg, &Bs[0][soB1]);
    }
    __syncthreads();

    int cb = 0;
    for (int k0 = kbeg; k0 < kend; k0 += 32) {
        int kn = k0 + 32;
        if (kn < kend) {
            gld16(ag0 + kn, &As[cb ^ 1][soA]);
            gld16(bg0 + kn, &Bs[cb ^ 1][soB0]);
            gld16(bg1 + kn, &Bs[cb ^ 1][soB1]);
        }
        short8 af[2], bf[4];
        #pragma unroll
        for (int i = 0; i < 2; i++) af[i] = *(const short8*)&As[cb][(arow + i*16)*32 + koff];
        #pragma unroll
        for (int j = 0; j < 4; j++) bf[j] = *(const short8*)&Bs[cb][(nrow + j*16)*32 + koff];
        #pragma unroll
        for (int i = 0; i < 2; i++)
            #pragma unroll
            for (int j = 0; j < 4; j++)
                acc[i][j] = __builtin_amdgcn_mfma_f32_16x16x32_bf16(af[i], bf[j], acc[i][j], 0, 0, 0);
        __syncthreads();
        cb ^= 1;
    }

    float* Cf = (float*)Cv;
    u16*   Ch = (u16*)Cv;
    size_t cb2 = (size_t)bz * sC;
    int rbase = m0 + wm + (lane >> 4) * 4;
    int cbase = n0 + wn + (lane & 15);
    #pragma unroll
    for (int i = 0; i < 2; i++) {
        #pragma unroll
        for (int j = 0; j < 4; j++) {
            int col = cbase + j * 16;
            if (col >= N) continue;
            float bcol = bias ? bias[col] : 0.f;
            #pragma unroll
            for (int r = 0; r < 4; r++) {
                int row = rbase + i * 16 + r;
                if (row >= M) continue;
                float v = acc[i][j][r];
                if (qscale && col < 512) v *= 0.125f;
                v += bcol;
                if (resid) v += resid[(size_t)row * ldr + col];
                if (relu) v = fmaxf(v, 0.f);
                size_t ci = cb2 + (size_t)row * ldc + col;
                if (obf16) Ch[ci] = f2b(v);
                else if (atomic) atomicAdd(&Cf[ci], v);
                else Cf[ci] = v;
            }
        }
    }
}

// ---------------------------------------------------------------------------
// fp32 tiled GEMM (Newton-Schulz chain + tiny gemms).
// C = alpha*A@B + diagc*I + bias + rescoef*resid.
// 16x64 tile, 256 threads (1x4 per thread), double-buffered LDS staging.
// Round-11: reverted to this (round-9) version — the barrier-free rewrite
// regressed badly: block-cooperative LDS staging was latency AMORTIZATION,
// not overhead (barriers weren't the bottleneck), and the M=1 dispatch
// collapsed to 2 active waves chip-wide (64us matvec).
// ---------------------------------------------------------------------------
__global__ __launch_bounds__(256) void gemm_big(
    const float* __restrict__ A, int lda, long sA,
    const float* __restrict__ B, int ldb, long sB,
    float* __restrict__ C, int ldc, long sC,
    int M, int N, int K,
    float alpha, float diagc,
    const float* __restrict__ bias,
    const float* __restrict__ resid, int ldr, long sR, float rescoef,
    int btrans)
{
    __shared__ float As[2][16][20];
    __shared__ float Bs[2][16][64];

    int bz = blockIdx.z;
    A += (size_t)bz * sA;
    B += (size_t)bz * sB;
    C += (size_t)bz * sC;

    int tid = threadIdx.x;
    int tx = tid & 15, ty = tid >> 4;
    int m0 = blockIdx.y * 16, n0 = blockIdx.x * 64;

    int ar = tid >> 2;
    int ak = (tid & 3) * 4;
    int bkr = tid >> 4;
    int bc4 = (tid & 15) * 4;
    int bc  = tid >> 2;
    int bkq = (tid & 3) * 4;

    auto loadA = [&](int k0, float4& ra) {
        if (tid < 64) {
            int m = m0 + ar;
            ra = make_float4(0.f, 0.f, 0.f, 0.f);
            if (m < M) ra = *(const float4*)(A + (size_t)m * lda + k0 + ak);
        }
    };
    auto loadB = [&](int k0, float4& rb) {
        if (!btrans) rb = *(const float4*)(B + (size_t)(k0 + bkr) * ldb + n0 + bc4);
        else         rb = *(const float4*)(B + (size_t)(n0 + bc) * ldb + k0 + bkq);
    };
    auto storeA = [&](int buf, const float4& ra) {
        if (tid < 64) {
            As[buf][ak + 0][ar] = ra.x; As[buf][ak + 1][ar] = ra.y;
            As[buf][ak + 2][ar] = ra.z; As[buf][ak + 3][ar] = ra.w;
        }
    };
    auto storeB = [&](int buf, const float4& rb) {
        if (!btrans) {
            *(float4*)&Bs[buf][bkr][bc4] = rb;
        } else {
            Bs[buf][bkq + 0][bc] = rb.x; Bs[buf][bkq + 1][bc] = rb.y;
            Bs[buf][bkq + 2][bc] = rb.z; Bs[buf][bkq + 3][bc] = rb.w;
        }
    };

    float acc[4];
    #pragma unroll
    for (int j = 0; j < 4; j++) acc[j] = 0.f;

    float4 pa, pb;
    loadA(0, pa); loadB(0, pb);
    storeA(0, pa); storeB(0, pb);
    int cur = 0;

    for (int k0 = 0; k0 < K; k0 += 16) {
        bool more = (k0 + 16) < K;
        float4 na, nb;
        if (more) { loadA(k0 + 16, na); loadB(k0 + 16, nb); }
        __syncthreads();
        #pragma unroll
        for (int k = 0; k < 16; k++) {
            float a = As[cur][k][ty];
            float4 bv = *(const float4*)&Bs[cur][k][tx * 4];
            acc[0] += a * bv.x; acc[1] += a * bv.y;
            acc[2] += a * bv.z; acc[3] += a * bv.w;
        }
        if (more) { storeA(cur ^ 1, na); storeB(cur ^ 1, nb); cur ^= 1; }
    }

    int m = m0 + ty;
    if (m < M) {
        #pragma unroll
        for (int j = 0; j < 4; j++) {
            int n = n0 + tx * 4 + j;
            float v = alpha * acc[j];
            if (diagc != 0.f && m == n) v += diagc;
            if (bias) v += bias[n];
            if (resid) v += rescoef * resid[(size_t)bz * sR + (size_t)m * ldr + n];
            C[(size_t)m * ldc + n] = v;
        }
    }
}

// ---------------------------------------------------------------------------
// Dedicated M=1 out-projection matvec (layer 1):
// C[n] = sum_k x[k]*W[k][n] + bias[n] + resid[n], k ascending (same order as
// gemm_big -> same numerics class). The generic gemm ran this with grid=8
// blocks and (in round 10) 2 active waves chip-wide = 64us; here: x staged
// in LDS once, 512 threads, coalesced weight reads, ~4us.
// ---------------------------------------------------------------------------
__global__ __launch_bounds__(256) void matvec_out(
    const float* __restrict__ x, const float* __restrict__ W,
    const float* __restrict__ bias, const float* __restrict__ resid,
    float* __restrict__ C)
{
    __shared__ float xs[512];
    int tid = threadIdx.x;
    xs[tid] = x[tid];
    xs[tid + 256] = x[tid + 256];
    __syncthreads();
    int n = blockIdx.x * 256 + tid;
    float acc = 0.f;
    #pragma unroll 8
    for (int k = 0; k < 512; k++)
        acc += xs[k] * W[(size_t)k * 512 + n];
    C[n] = acc + bias[n] + resid[n];
}

// ---------------------------------------------------------------------------
// Fused a1 chain (layer 0), wave-owns-rows; loads in groups of 8,
// __launch_bounds__(256,3).
// ---------------------------------------------------------------------------
__global__ __launch_bounds__(256, 3) void a1z_fused(
    const u16* __restrict__ QKVh, const u16* __restrict__ KLh,
    const u16* __restrict__ ZTh, float* __restrict__ OUT, int T0)
{
    __shared__ u16 Ps[64 * 264];

    int tid = threadIdx.x;
    int w = tid >> 6, lane = tid & 63;
    int lo = lane & 15, hi = lane >> 4;
    int koff = hi * 8;
    int hh = blockIdx.y;
    int tok0 = T0 + blockIdx.x * 64;

    int trow = tok0 + w * 16 + lo;
    if (trow > LPAD - 1) trow = LPAD - 1;

    const u16* qb = QKVh + (size_t)trow * 1536 + hh * 64 + koff;
    short8 aq0 = *(const short8*)(qb);
    short8 aq1 = *(const short8*)(qb + 32);

    floatx4 acc[16];
    #pragma unroll
    for (int j = 0; j < 16; j++) acc[j] = (floatx4){0.f, 0.f, 0.f, 0.f};

    const u16* klb = KLh + (size_t)hh * 256 * 64 + lo * 64 + koff;
    {
        short8 bk[8];
        #pragma unroll
        for (int j = 0; j < 8; j++) bk[j] = *(const short8*)(klb + (size_t)j * 1024);
        #pragma unroll
        for (int j = 0; j < 8; j++)
            acc[j] = __builtin_amdgcn_mfma_f32_16x16x32_bf16(aq0, bk[j], acc[j], 0, 0, 0);
    }
    {
        short8 bk[8];
        #pragma unroll
        for (int j = 0; j < 8; j++) bk[j] = *(const short8*)(klb + (size_t)(8 + j) * 1024);
        #pragma unroll
        for (int j = 0; j < 8; j++)
            acc[8 + j] = __builtin_amdgcn_mfma_f32_16x16x32_bf16(aq0, bk[j], acc[8 + j], 0, 0, 0);
    }
    {
        short8 bk[8];
        #pragma unroll
        for (int j = 0; j < 8; j++) bk[j] = *(const short8*)(klb + (size_t)j * 1024 + 32);
        #pragma unroll
        for (int j = 0; j < 8; j++)
            acc[j] = __builtin_amdgcn_mfma_f32_16x16x32_bf16(aq1, bk[j], acc[j], 0, 0, 0);
    }
    {
        short8 bk[8];
        #pragma unroll
        for (int j = 0; j < 8; j++) bk[j] = *(const short8*)(klb + (size_t)(8 + j) * 1024 + 32);
        #pragma unroll
        for (int j = 0; j < 8; j++)
            acc[8 + j] = __builtin_amdgcn_mfma_f32_16x16x32_bf16(aq1, bk[j], acc[8 + j], 0, 0, 0);
    }

    #pragma unroll
    for (int slot = 0; slot < 4; slot++) {
        float mx = acc[0][slot];
        #pragma unroll
        for (int j = 1; j < 16; j++) mx = fmaxf(mx, acc[j][slot]);
        mx = fmaxf(mx, __shfl_xor(mx, 1, 64));
        mx = fmaxf(mx, __shfl_xor(mx, 2, 64));
        mx = fmaxf(mx, __shfl_xor(mx, 4, 64));
        mx = fmaxf(mx, __shfl_xor(mx, 8, 64));
        float p[16];
        float s = 0.f;
        #pragma unroll
        for (int j = 0; j < 16; j++) { p[j] = __expf(acc[j][slot] - mx); s += p[j]; }
        s += __shfl_xor(s, 1, 64);
        s += __shfl_xor(s, 2, 64);
        s += __shfl_xor(s, 4, 64);
        s += __shfl_xor(s, 8, 64);
        float inv = 1.f / s;
        int row = w * 16 + hi * 4 + slot;
        #pragma unroll
        for (int j = 0; j < 16; j++)
            Ps[row * 264 + j * 16 + lo] = f2b(p[j] * inv);
    }
    // no barrier: each wave reads back only its own 16 rows (lgkmcnt orders it)

    floatx4 acc2[4];
    #pragma unroll
    for (int j = 0; j < 4; j++) acc2[j] = (floatx4){0.f, 0.f, 0.f, 0.f};
    const u16* ztb = ZTh + ((size_t)hh * 64 + lo) * 256 + koff;
    #pragma unroll
    for (int ks = 0; ks < 8; ks += 2) {
        short8 bz[8];
        #pragma unroll
        for (int j = 0; j < 4; j++)
            bz[j] = *(const short8*)(ztb + (size_t)j * 4096 + ks * 32);
        #pragma unroll
        for (int j = 0; j < 4; j++)
            bz[4 + j] = *(const short8*)(ztb + (size_t)j * 4096 + (ks + 1) * 32);
        short8 ap0 = *(const short8*)&Ps[(w * 16 + lo) * 264 + ks * 32 + koff];
        short8 ap1 = *(const short8*)&Ps[(w * 16 + lo) * 264 + (ks + 1) * 32 + koff];
        #pragma unroll
        for (int j = 0; j < 4; j++)
            acc2[j] = __builtin_amdgcn_mfma_f32_16x16x32_bf16(ap0, bz[j], acc2[j], 0, 0, 0);
        #pragma unroll
        for (int j = 0; j < 4; j++)
            acc2[j] = __builtin_amdgcn_mfma_f32_16x16x32_bf16(ap1, bz[4 + j], acc2[j], 0, 0, 0);
    }
    #pragma unroll
    for (int j = 0; j < 4; j++) {
        #pragma unroll
        for (int slot = 0; slot < 4; slot++) {
            int tok = tok0 + w * 16 + hi * 4 + slot;
            if (tok < LPAD)
                OUT[(size_t)tok * 512 + hh * 64 + j * 16 + lo] = acc2[j][slot];
        }
    }
}

// ---------------------------------------------------------------------------
__global__ __launch_bounds__(256) void ln_kernel(
    const float* __restrict__ X, float* __restrict__ OUT, u16* __restrict__ OUTH,
    const float* __restrict__ g, const float* __restrict__ b, int nrows)
{
    int row = blockIdx.x * 4 + (threadIdx.x >> 6);
    int lane = threadIdx.x & 63;
    if (row >= nrows) return;
    const float* xr = X + (size_t)row * 512;
    float v[8]; float s = 0.f, s2 = 0.f;
    #pragma unroll
    for (int i = 0; i < 8; i++) { float t = xr[lane + i * 64]; v[i] = t; s += t; s2 += t * t; }
    for (int o = 1; o < 64; o <<= 1) { s += __shfl_xor(s, o, 64); s2 += __shfl_xor(s2, o, 64); }
    float mu = s * (1.f / 512.f);
    float var = s2 * (1.f / 512.f) - mu * mu;
    float rs = rsqrtf(var + 1e-5f);
    float* orow = OUT + (size_t)row * 512;
    u16* hrow = OUTH + (size_t)row * 512;
    #pragma unroll
    for (int i = 0; i < 8; i++) {
        int j = lane + i * 64;
        float y = (v[i] - mu) * rs * g[j] + b[j];
        orow[j] = y;
        hrow[j] = f2b(y);
    }
}

// Landmark means from bf16 QKVh; writes fp32 and bf16 copies
__global__ __launch_bounds__(64) void landmarks_kernel(
    const u16* __restrict__ QKVh, float* __restrict__ QL, float* __restrict__ KL,
    u16* __restrict__ QLh, u16* __restrict__ KLh)
{
    int mm = blockIdx.x, hh = blockIdx.y;
    int d = threadIdx.x;
    const u16* base = QKVh + (size_t)(mm * 40) * 1536 + hh * 64 + d;
    float sq = 0.f, sk = 0.f;
    for (int li = 0; li < 40; li++) {
        sq += b2f(base[(size_t)li * 1536]);
        sk += b2f(base[(size_t)li * 1536 + 512]);
    }
    size_t o = ((size_t)hh * 256 + mm) * 64 + d;
    float q = sq * (1.f / 40.f), k = sk * (1.f / 40.f);
    QL[o] = q; KL[o] = k;
    QLh[o] = f2b(q); KLh[o] = f2b(k);
}

// a2 softmax: wave per row (256 cols), fp32 in place
__global__ __launch_bounds__(256) void softmax_a2(
    float* __restrict__ A2, int nrows)
{
    int row = blockIdx.x * 4 + (threadIdx.x >> 6);
    int lane = threadIdx.x & 63;
    if (row >= nrows) return;
    float* p = A2 + (size_t)row * 256 + lane * 4;
    float4 v = *(float4*)p;
    float mx = fmaxf(fmaxf(v.x, v.y), fmaxf(v.z, v.w));
    for (int o = 1; o < 64; o <<= 1) mx = fmaxf(mx, __shfl_xor(mx, o, 64));
    float4 e = make_float4(__expf(v.x - mx), __expf(v.y - mx),
                           __expf(v.z - mx), __expf(v.w - mx));
    float s = e.x + e.y + e.z + e.w;
    for (int o = 1; o < 64; o <<= 1) s += __shfl_xor(s, o, 64);
    float inv = 1.f / s;
    e.x *= inv; e.y *= inv; e.z *= inv; e.w *= inv;
    *(float4*)p = e;
}

// block-per-row softmax (wide rows) -> bf16 probs, single global read via
// LDS row staging, float4 loads, packed bf16 stores.
__global__ __launch_bounds__(256) void row_softmax_bf16(
    const float* __restrict__ S, u16* __restrict__ P, int ncols)
{
    __shared__ float buf[LPAD];
    __shared__ float sr[4];
    int row = blockIdx.x;
    const float* p = S + (size_t)row * ncols;
    u16* q = P + (size_t)row * ncols;
    int tid = threadIdx.x;

    float mx = -1e30f;
    for (int i = tid * 4; i < ncols; i += 1024) {
        float4 v = *(const float4*)(p + i);
        *(float4*)&buf[i] = v;
        mx = fmaxf(mx, fmaxf(fmaxf(v.x, v.y), fmaxf(v.z, v.w)));
    }
    for (int o = 1; o < 64; o <<= 1) mx = fmaxf(mx, __shfl_xor(mx, o, 64));
    if ((tid & 63) == 0) sr[tid >> 6] = mx;
    __syncthreads();
    mx = fmaxf(fmaxf(sr[0], sr[1]), fmaxf(sr[2], sr[3]));

    float s = 0.f;
    for (int i = tid * 4; i < ncols; i += 1024) {
        float4 v = *(const float4*)&buf[i];
        s += __expf(v.x - mx) + __expf(v.y - mx) + __expf(v.z - mx) + __expf(v.w - mx);
    }
    for (int o = 1; o < 64; o <<= 1) s += __shfl_xor(s, o, 64);
    __syncthreads();
    if ((tid & 63) == 0) sr[tid >> 6] = s;
    __syncthreads();
    s = sr[0] + sr[1] + sr[2] + sr[3];
    float inv = 1.f / s;

    for (int i = tid * 4; i < ncols; i += 1024) {
        float4 v = *(const float4*)&buf[i];
        ushort4 o4;
        o4.x = f2b(__expf(v.x - mx) * inv);
        o4.y = f2b(__expf(v.y - mx) * inv);
        o4.z = f2b(__expf(v.z - mx) * inv);
        o4.w = f2b(__expf(v.w - mx) * inv);
        *(ushort4*)(q + i) = o4;
    }
}

__global__ __launch_bounds__(256) void a2norms_kernel(
    const float* __restrict__ A2, float* __restrict__ scal)
{
    int hh = blockIdx.x, tid = threadIdx.x;
    const float* A = A2 + (size_t)hh * 65536;
    float rs = 0.f, cs = 0.f;
    for (int j = 0; j < 256; j++) {
        rs += fabsf(A[(size_t)tid * 256 + j]);
        cs += fabsf(A[(size_t)j * 256 + tid]);
    }
    __shared__ float sm[8];
    for (int o = 1; o < 64; o <<= 1) {
        rs = fmaxf(rs, __shfl_xor(rs, o, 64));
        cs = fmaxf(cs, __shfl_xor(cs, o, 64));
    }
    if ((tid & 63) == 0) { sm[tid >> 6] = rs; sm[4 + (tid >> 6)] = cs; }
    __syncthreads();
    if (tid == 0) {
        float rm = fmaxf(fmaxf(sm[0], sm[1]), fmaxf(sm[2], sm[3]));
        float cm = fmaxf(fmaxf(sm[4], sm[5]), fmaxf(sm[6], sm[7]));
        atomicMax((unsigned int*)&scal[0], __float_as_uint(rm));
        atomicMax((unsigned int*)&scal[1], __float_as_uint(cm));
    }
}

// z0 = a2^T / denom (fp32 only)
__global__ __launch_bounds__(256) void z0_kernel(
    const float* __restrict__ A2, const float* __restrict__ scal,
    float* __restrict__ Zf)
{
    int i = blockIdx.x, hh = blockIdx.y, j = threadIdx.x;
    float inv = 1.f / (scal[0] * scal[1]);
    Zf[((size_t)hh * 256 + i) * 256 + j] = A2[((size_t)hh * 256 + j) * 256 + i] * inv;
}

// Tiny fused a1@Z for layer 1 (single token)
__global__ __launch_bounds__(256) void a1z_single(
    const u16* __restrict__ QKVh, const float* __restrict__ KL,
    const float* __restrict__ ZM, float* __restrict__ OUT, int tok)
{
    int h = blockIdx.x, tid = threadIdx.x;
    __shared__ float q[64];
    __shared__ float p[256];
    __shared__ float red[4];
    if (tid < 64) q[tid] = b2f(QKVh[(size_t)tok * 1536 + h * 64 + tid]);
    __syncthreads();
    const float* kl = KL + ((size_t)h * 256 + tid) * 64;
    float s = 0.f;
    for (int d = 0; d < 64; d++) s += q[d] * kl[d];
    float mx = s;
    for (int o = 1; o < 64; o <<= 1) mx = fmaxf(mx, __shfl_xor(mx, o, 64));
    if ((tid & 63) == 0) red[tid >> 6] = mx;
    __syncthreads();
    mx = fmaxf(fmaxf(red[0], red[1]), fmaxf(red[2], red[3]));
    float e = __expf(s - mx);
    float sum = e;
    for (int o = 1; o < 64; o <<= 1) sum += __shfl_xor(sum, o, 64);
    __syncthreads();
    if ((tid & 63) == 0) red[tid >> 6] = sum;
    __syncthreads();
    sum = red[0] + red[1] + red[2] + red[3];
    p[tid] = e / sum;
    __syncthreads();
    if (tid < 64) {
        float a = 0.f;
        for (int j = 0; j < 256; j++) a += p[j] * ZM[((size_t)h * 256 + j) * 64 + tid];
        OUT[(size_t)tok * 512 + h * 64 + tid] = a;
    }
}

// Depthwise 33-tap token conv fused with the bf16 cast: reads the PV result
// (OUT fp32), adds the conv, writes OUTH bf16 directly.
__global__ __launch_bounds__(256) void conv_cast(
    const u16* __restrict__ QKVh, const float* __restrict__ OUT,
    u16* __restrict__ OUTH, const float* __restrict__ resw, int T0, int ntok)
{
    __shared__ u16 Vw[48][512];
    __shared__ float ws[264];
    int tid = threadIdx.x;
    int t0 = T0 + blockIdx.x * 16;
    int wv = tid >> 6, lnn = tid & 63;
    for (int r = wv; r < 48; r += 4) {
        int ts = t0 - 16 + r;
        short8 v = (short8){0,0,0,0,0,0,0,0};
        if (ts >= 0 && ts < LPAD)
            v = *(const short8*)(QKVh + (size_t)ts * 1536 + 1024 + lnn * 8);
        *(short8*)&Vw[r][lnn * 8] = v;
    }
    if (tid < 264) ws[tid] = resw[tid];
    __syncthreads();

    int c0 = tid * 2;
    int h = c0 >> 6;
    float wreg[33];
    #pragma unroll
    for (int r = 0; r < 33; r++) wreg[r] = ws[h * 33 + r];

    #pragma unroll 1
    for (int tk = 0; tk < 16; tk++) {
        int tok = t0 + tk;
        if (tok >= T0 + ntok) break;
        float a0 = 0.f, a1 = 0.f;
        #pragma unroll
        for (int r = 0; r < 33; r++) {
            unsigned pv = *(const unsigned*)&Vw[tk + r][c0];
            a0 += wreg[r] * __uint_as_float(pv << 16);
            a1 += wreg[r] * __uint_as_float(pv & 0xFFFF0000u);
        }
        float v0 = OUT[(size_t)tok * 512 + c0]     + a0;
        float v1 = OUT[(size_t)tok * 512 + c0 + 1] + a1;
        unsigned pk = ((unsigned)f2b(v1) << 16) | (unsigned)f2b(v0);
        *(unsigned*)&OUTH[(size_t)(tok - T0) * 512 + c0] = pk;
    }
}

// Old simple conv (layer 1, single token)
__global__ __launch_bounds__(256) void conv_res(
    const u16* __restrict__ QKVh, float* __restrict__ OUT,
    const float* __restrict__ resw, int t0, int ntok)
{
    int idx = blockIdx.x * 256 + threadIdx.x;
    if (idx >= ntok * 512) return;
    int tok = t0 + (idx >> 9);
    int c = idx & 511;
    int h = c >> 6;
    const u16* vbase = QKVh + 1024 + c;
    float acc = 0.f;
    #pragma unroll 1
    for (int r = 0; r < 33; r++) {
        int ts = tok - 16 + r;
        if (ts >= 0 && ts < LPAD)
            acc += resw[h * 33 + r] * b2f(vbase[(size_t)ts * 1536]);
    }
    OUT[(size_t)tok * 512 + c] += acc;
}

// V slice of QKVh -> Vt[h][d][t] (bf16)
__global__ __launch_bounds__(256) void vtrans(
    const u16* __restrict__ QKVh, u16* __restrict__ Vt)
{
    int t0 = blockIdx.x * 64, hh = blockIdx.y;
    __shared__ u16 tile[64][65];
    #pragma unroll
    for (int ii = 0; ii < 16; ii++) {
        int idx = threadIdx.x + ii * 256;
        int t = idx >> 6, d = idx & 63;
        tile[t][d] = QKVh[(size_t)(t0 + t) * 1536 + 1024 + hh * 64 + d];
    }
    __syncthreads();
    #pragma unroll
    for (int ii = 0; ii < 16; ii++) {
        int idx = threadIdx.x + ii * 256;
        int d = idx >> 6, t = idx & 63;
        Vt[((size_t)hh * 64 + d) * LPAD + t0 + t] = tile[t][d];
    }
}

// Combine PPEG weights: W49[tap][c] = w7 + w5(in range) + w3(in range)
__global__ void ppeg_combine(
    const float* __restrict__ w7, const float* __restrict__ w5,
    const float* __restrict__ w3, const float* __restrict__ b7,
    const float* __restrict__ b5, const float* __restrict__ b3,
    float* __restrict__ W49, float* __restrict__ BSUM)
{
    int idx = blockIdx.x * 256 + threadIdx.x;
    if (idx >= 49 * 512) return;
    int tap = idx >> 9, c = idx & 511;
    int dy = tap / 7 - 3, dx = tap % 7 - 3;
    float v = w7[c * 49 + tap];
    if (dy >= -2 && dy <= 2 && dx >= -2 && dx <= 2)
        v += w5[c * 25 + (dy + 2) * 5 + (dx + 2)];
    if (dy >= -1 && dy <= 1 && dx >= -1 && dx <= 1)
        v += w3[c * 9 + (dy + 1) * 3 + (dx + 1)];
    W49[tap * 512 + c] = v;
    if (tap == 0) BSUM[c] = b7[c] + b5[c] + b3[c];
}

// PPEG, tiled: block = 16x4 position tile x 64 channels, fully-unrolled
// float4 halo staging.
__global__ __launch_bounds__(256) void ppeg_tile(
    const float* __restrict__ S, float* __restrict__ O,
    const float* __restrict__ W49, const float* __restrict__ BSUM)
{
    __shared__ float Sw[10][22][64];
    int tid = threadIdx.x;
    int c = tid & 63;
    int sub = tid >> 6;
    int x0 = blockIdx.x * 16;
    int y0 = blockIdx.y * 4;
    int cg = blockIdx.z * 64;

    {
        int p = tid >> 4;
        int c4 = (tid & 15) * 4;
        #pragma unroll
        for (int i = 0; i < 14; i++) {
            int f = p + i * 16;
            if (f < 220) {
                int r = f / 22, xx = f - r * 22;
                int gy = y0 - 3 + r;
                int gx = x0 - 3 + xx;
                float4 v = make_float4(0.f, 0.f, 0.f, 0.f);
                if ((unsigned)gy < 100u && (unsigned)gx < 100u)
                    v = *(const float4*)(S + (size_t)(1 + gy * 100 + gx) * 512 + cg + c4);
                *(float4*)&Sw[r][xx][c4] = v;
            }
        }
    }
    float wreg[49];
    #pragma unroll
    for (int t = 0; t < 49; t++) wreg[t] = W49[t * 512 + cg + c];
    float bsum = BSUM[cg + c];
    __syncthreads();

    int xb = sub * 4;
    float acc[4][4];
    #pragma unroll
    for (int yy = 0; yy < 4; yy++)
        #pragma unroll
        for (int xq = 0; xq < 4; xq++)
            acc[yy][xq] = Sw[yy + 3][xb + xq + 3][c] + bsum;

    #pragma unroll
    for (int r = 0; r < 10; r++) {
        float v[10];
        #pragma unroll
        for (int j = 0; j < 10; j++) v[j] = Sw[r][xb + j][c];
        #pragma unroll
        for (int yy = 0; yy < 4; yy++) {
            int t = r - yy;
            if (t < 0 || t > 6) continue;
            #pragma unroll
            for (int dxt = 0; dxt < 7; dxt++) {
                float w = wreg[t * 7 + dxt];
                #pragma unroll
                for (int xq = 0; xq < 4; xq++)
                    acc[yy][xq] += v[xq + dxt] * w;
            }
        }
    }

    #pragma unroll
    for (int yy = 0; yy < 4; yy++) {
        int gy = y0 + yy;
        #pragma unroll
        for (int xq = 0; xq < 4; xq++) {
            int gx = x0 + xb + xq;
            if (gx < 100)
                O[(size_t)(1 + gy * 100 + gx) * 512 + cg + c] = acc[yy][xq];
        }
    }
}

__global__ __launch_bounds__(64) void final_kernel(
    const float* __restrict__ S, const float* __restrict__ g, const float* __restrict__ b,
    const float* __restrict__ w, const float* __restrict__ bb, float* __restrict__ out)
{
    int lane = threadIdx.x;
    float v[8]; float s = 0.f, s2 = 0.f;
    #pragma unroll
    for (int i = 0; i < 8; i++) { float t = S[lane + i * 64]; v[i] = t; s += t; s2 += t * t; }
    for (int o = 1; o < 64; o <<= 1) { s += __shfl_xor(s, o, 64); s2 += __shfl_xor(s2, o, 64); }
    float mu = s * (1.f / 512.f);
    float var = s2 * (1.f / 512.f) - mu * mu;
    float rs = rsqrtf(var + 1e-5f);
    float o0 = 0.f, o1 = 0.f;
    #pragma unroll
    for (int i = 0; i < 8; i++) {
        int j = lane + i * 64;
        float xn = (v[i] - mu) * rs * g[j] + b[j];
        o0 += xn * w[j * 2 + 0];
        o1 += xn * w[j * 2 + 1];
    }
    for (int o = 1; o < 64; o <<= 1) { o0 += __shfl_xor(o0, o, 64); o1 += __shfl_xor(o1, o, 64); }
    if (lane == 0) { out[0] = o0 + bb[0]; out[1] = o1 + bb[1]; }
}

__global__ void zerok(float* p, int n)
{
    int i = blockIdx.x * 256 + threadIdx.x;
    if (i < n) p[i] = 0.f;
}
__global__ void zero2k(float* p) { p[0] = 0.f; p[1] = 0.f; }
__global__ void copy512(float* dst, const float* src)
{
    int i = blockIdx.x * 256 + threadIdx.x;
    if (i < 512) dst[i] = src[i];
}
__global__ void cast_bf16(const float* __restrict__ src, u16* __restrict__ dst, int n)
{
    int i = (blockIdx.x * 256 + threadIdx.x) * 4;
    if (i >= n) return;
    float4 v = *(const float4*)(src + i);
    dst[i + 0] = f2b(v.x); dst[i + 1] = f2b(v.y);
    dst[i + 2] = f2b(v.z); dst[i + 3] = f2b(v.w);
}
// dst[b][c][r] = src[b][r][c]  (cast-transpose fp32 RxC -> bf16 CxR)
__global__ void castT(const float* __restrict__ src, u16* __restrict__ dst,
                      int R, int C, int nb)
{
    size_t idx = (size_t)blockIdx.x * 256 + threadIdx.x;
    size_t tot = (size_t)R * C * nb;
    if (idx >= tot) return;
    int rc = R * C;
    int b = (int)(idx / rc);
    int rem = (int)(idx - (size_t)b * rc);
    int c = rem / R, r = rem - c * R;
    dst[idx] = f2b(src[(size_t)b * rc + (size_t)r * C + c]);
}

// ---------------------------------------------------------------------------
extern "C" void kernel_launch(void* const* d_in, const int* in_sizes, int n_in,
                              void* d_out, int out_size, void* d_ws, size_t ws_size,
                              hipStream_t stream)
{
    const float* h     = (const float*)d_in[0];
    const float* fc1_w = (const float*)d_in[1];
    const float* fc1_b = (const float*)d_in[2];
    const float* cls   = (const float*)d_in[3];
    bool sigorder = (in_sizes[10] == 512 * 49);
    int i_l2 = sigorder ? 16 : 10;
    int i_pp = sigorder ? 10 : 16;
    const float* l_g[2]   = { (const float*)d_in[4], (const float*)d_in[i_l2 + 0] };
    const float* l_b[2]   = { (const float*)d_in[5], (const float*)d_in[i_l2 + 1] };
    const float* l_qkv[2] = { (const float*)d_in[6], (const float*)d_in[i_l2 + 2] };
    const float* l_ow[2]  = { (const float*)d_in[7], (const float*)d_in[i_l2 + 3] };
    const float* l_ob[2]  = { (const float*)d_in[8], (const float*)d_in[i_l2 + 4] };
    const float* l_rw[2]  = { (const float*)d_in[9], (const float*)d_in[i_l2 + 5] };
    const float* w7 = (const float*)d_in[i_pp + 0];
    const float* b7 = (const float*)d_in[i_pp + 1];
    const float* w5 = (const float*)d_in[i_pp + 2];
    const float* b5 = (const float*)d_in[i_pp + 3];
    const float* w3 = (const float*)d_in[i_pp + 4];
    const float* b3 = (const float*)d_in[i_pp + 5];
    const float* ng   = (const float*)d_in[22];
    const float* nbv  = (const float*)d_in[23];
    const float* fc2w = (const float*)d_in[24];
    const float* fc2b = (const float*)d_in[25];
    float* out = (float*)d_out;

    char* Wb = (char*)d_ws;
    size_t off = 0;
    auto allocB = [&](size_t bytes) { void* p = Wb + off; off = (off + bytes + 255) & ~(size_t)255; return p; };

    float* SEQ   = (float*)allocB((size_t)NSEQ * 512 * 4);
    float* XP    = (float*)allocB((size_t)LPAD * 512 * 4);
    u16*   XPh   = (u16*)  allocB((size_t)LPAD * 512 * 2);
    u16*   QKVh  = (u16*)  allocB((size_t)LPAD * 1536 * 2);
    float* QLKL  = (float*)allocB((size_t)262144 * 4);
    float* QL = QLKL, *KL = QLKL + 131072;
    u16*   QLKLh = (u16*)  allocB((size_t)262144 * 2);
    u16*   QLh = QLKLh, *KLh = QLKLh + 131072;
    float* A2   = (float*)allocB(524288 * 4);
    float* Zf0  = (float*)allocB(524288 * 4);
    float* Zf1  = (float*)allocB(524288 * 4);
    float* XZf  = (float*)allocB(524288 * 4);
    float* W2b  = (float*)allocB(524288 * 4);
    float* W3b  = (float*)allocB(524288 * 4);
    float* A3V  = (float*)allocB(131072 * 4);
    float* ZMATf= (float*)allocB(131072 * 4);
    u16*   ZMATt= (u16*)  allocB(131072 * 2);
    u16*   Vt   = (u16*)  allocB((size_t)8 * 64 * LPAD * 2);
    u16*   fc1wt= (u16*)  allocB(524288 * 2);
    u16*   qkvwt= (u16*)  allocB(786432 * 2);
    u16*   outwt= (u16*)  allocB(262144 * 2);
    float* W49  = (float*)allocB(49 * 512 * 4);
    float* BSUM = (float*)allocB(512 * 4);
    float* SCAL = (float*)allocB(16);
    void*  U1   = allocB((size_t)LPAD * 512 * 4);
    u16*   hbf  = (u16*)U1;
    float* OUT  = (float*)U1;
    float* SEQ2 = OUT;
    size_t fixed = off;

    size_t scB_b = (size_t)8 * 256 * LPAD * 4;
    size_t phB_b = (size_t)8 * 256 * LPAD * 2;
    bool batched = ws_size >= fixed + scB_b + phB_b;
    float* SC; u16* Ph;
    if (batched) {
        SC = (float*)(Wb + fixed);
        Ph = (u16*)(Wb + fixed + scB_b);
    } else {
        SC = (float*)(Wb + fixed);
        Ph = (u16*)(Wb + fixed + (size_t)256 * LPAD * 4);
    }
    u16* OUTh = (u16*)SC;   // alias: SC dead when OUTh materialized

    auto mgemm = [&](const u16* A, int lda, long sA, const u16* Bt, int ldb, long sB,
                     void* C, int ldc, long sC, int M, int N, int K,
                     const float* bias, const float* resid, int ldr,
                     int relu, int qscale, int obf16, int nbatch, int ksplit, int atomic) {
        dim3 grid((N + 127) / 128, (M + 63) / 64, nbatch * ksplit);
        gemm_mfma<<<grid, 256, 0, stream>>>(A, lda, sA, Bt, ldb, sB, C, ldc, sC,
            M, N, K, ksplit, bias, resid, ldr, relu, qscale, obf16, atomic);
    };
    auto fgemm = [&](const float* A, int lda, long sA, const float* B, int ldb, long sB,
                     float* C, int ldc, long sC, int M, int N, int K,
                     float alpha, float diagc, const float* bias,
                     const float* resid, int ldr, long sR, float rescoef,
                     int btrans, int nbatch) {
        dim3 grid(N / 64, (M + 15) / 16, nbatch);
        gemm_big<<<grid, 256, 0, stream>>>(A, lda, sA, B, ldb, sB, C, ldc, sC, M, N, K,
            alpha, diagc, bias, resid, ldr, sR, rescoef, btrans);
    };

    // ---- prologue
    cast_bf16<<<(NPIX * 1024 / 4 + 255) / 256, 256, 0, stream>>>(h, hbf, NPIX * 1024);
    castT<<<(524288 + 255) / 256, 256, 0, stream>>>(fc1_w, fc1wt, 1024, 512, 1);
    mgemm(hbf, 1024, 0, fc1wt, 1024, 0, SEQ + 512, 512, 0, NPIX, 512, 1024,
          fc1_b, nullptr, 0, 1, 0, 0, 1, 1, 0);
    copy512<<<2, 256, 0, stream>>>(SEQ, cls);
    zerok<<<(PADT * 512 + 255) / 256, 256, 0, stream>>>(XP, PADT * 512);
    zerok<<<(PADT * 256 + 255) / 256, 256, 0, stream>>>((float*)XPh, PADT * 256);
    ppeg_combine<<<(49 * 512 + 255) / 256, 256, 0, stream>>>(w7, w5, w3, b7, b5, b3, W49, BSUM);

    for (int layer = 0; layer < 2; layer++) {
        const float* curSEQ = (layer == 0) ? SEQ : SEQ2;
        ln_kernel<<<(NSEQ + 3) / 4, 256, 0, stream>>>(curSEQ, XP + (size_t)PADT * 512,
            XPh + (size_t)PADT * 512, l_g[layer], l_b[layer], NSEQ);
        castT<<<(786432 + 255) / 256, 256, 0, stream>>>(l_qkv[layer], qkvwt, 512, 1536, 1);
        mgemm(XPh, 512, 0, qkvwt, 512, 0, QKVh, 1536, 0, LPAD, 1536, 512,
              nullptr, nullptr, 0, 0, 1, 1, 1, 1, 0);
        landmarks_kernel<<<dim3(256, 8), 64, 0, stream>>>(QKVh, QL, KL, QLh, KLh);
        // a2 = softmax(ql @ kl^T)  (fp32)
        fgemm(QL, 64, 16384, KL, 64, 16384, A2, 256, 65536, 256, 256, 64,
              1.f, 0.f, nullptr, nullptr, 0, 0, 0.f, 1, 8);
        softmax_a2<<<512, 256, 0, stream>>>(A2, 2048);
        zero2k<<<1, 1, 0, stream>>>(SCAL);
        a2norms_kernel<<<8, 256, 0, stream>>>(A2, SCAL);
        z0_kernel<<<dim3(256, 8), 256, 0, stream>>>(A2, SCAL, Zf0);

        // Newton-Schulz: 6 fp32 iterations
        float* zc = Zf0; float* zn = Zf1;
        for (int it = 0; it < 6; it++) {
            fgemm(A2, 256, 65536, zc, 256, 65536, XZf, 256, 65536, 256, 256, 256,
                  1.f, 0.f, nullptr, nullptr, 0, 0, 0.f, 0, 8);
            fgemm(XZf, 256, 65536, XZf, 256, 65536, W2b, 256, 65536, 256, 256, 256,
                  1.f, 15.f, nullptr, XZf, 256, 65536, -7.f, 0, 8);
            fgemm(XZf, 256, 65536, W2b, 256, 65536, W3b, 256, 65536, 256, 256, 256,
                  -1.f, 13.f, nullptr, nullptr, 0, 0, 0.f, 0, 8);
            fgemm(zc, 256, 65536, W3b, 256, 65536, zn, 256, 65536, 256, 256, 256,
                  0.25f, 0.f, nullptr, nullptr, 0, 0, 0.f, 0, 8);
            float* t = zc; zc = zn; zn = t;
        }
        float* zfin = zc;

        // a3v = softmax(ql @ k^T) @ v  via MFMA
        vtrans<<<dim3(160, 8), 256, 0, stream>>>(QKVh, Vt);
        zerok<<<512, 256, 0, stream>>>(A3V, 131072);
        if (batched) {
            mgemm(QLh, 64, 16384, QKVh + 512, 1536, 64, SC, LPAD, (long)256 * LPAD,
                  256, LPAD, 64, nullptr, nullptr, 0, 0, 0, 0, 8, 1, 0);
            row_softmax_bf16<<<2048, 256, 0, stream>>>(SC, Ph, LPAD);
            mgemm(Ph, LPAD, (long)256 * LPAD, Vt, LPAD, (long)64 * LPAD, A3V, 64, 16384,
                  256, 64, LPAD, nullptr, nullptr, 0, 0, 0, 0, 8, 40, 1);
        } else {
            for (int hh = 0; hh < 8; hh++) {
                mgemm(QLh + (size_t)hh * 16384, 64, 0, QKVh + 512 + hh * 64, 1536, 0,
                      SC, LPAD, 0, 256, LPAD, 64, nullptr, nullptr, 0, 0, 0, 0, 1, 1, 0);
                row_softmax_bf16<<<256, 256, 0, stream>>>(SC, Ph, LPAD);
                mgemm(Ph, LPAD, 0, Vt + (size_t)hh * 64 * LPAD, LPAD, 0,
                      A3V + (size_t)hh * 16384, 64, 0, 256, 64, LPAD,
                      nullptr, nullptr, 0, 0, 0, 0, 1, 40, 1);
            }
        }
        // ZMAT = pinv(a2) @ a3v  (fp32)
        fgemm(zfin, 256, 65536, A3V, 64, 16384, ZMATf, 64, 16384, 256, 64, 256,
              1.f, 0.f, nullptr, nullptr, 0, 0, 0.f, 0, 8);

        if (layer == 0) {
            // Z^T bf16 for the fused a1 chain
            castT<<<(131072 + 255) / 256, 256, 0, stream>>>(ZMATf, ZMATt, 256, 64, 8);
            // fused scores+softmax+PZ: one launch, no SC/Ph traffic
            a1z_fused<<<dim3((NSEQ + 63) / 64, 8), 256, 0, stream>>>(
                QKVh, KLh, ZMATt, OUT, PADT);
            // conv + bf16 cast fused (writes OUTh directly)
            conv_cast<<<(NSEQ + 15) / 16, 256, 0, stream>>>(
                QKVh, OUT, OUTh, l_rw[0], PADT, NSEQ);
            castT<<<(262144 + 255) / 256, 256, 0, stream>>>(l_ow[0], outwt, 512, 512, 1);
            mgemm(OUTh, 512, 0, outwt, 512, 0, SEQ, 512, 0, NSEQ, 512, 512,
                  l_ob[0], XP + (size_t)PADT * 512, 512, 0, 0, 0, 1, 1, 0);
            // PPEG (tiled, unrolled float4 staging)
            ppeg_tile<<<dim3(7, 25, 8), 256, 0, stream>>>(SEQ, SEQ2, W49, BSUM);
            copy512<<<2, 256, 0, stream>>>(SEQ2, SEQ);
        } else {
            a1z_single<<<8, 256, 0, stream>>>(QKVh, KL, ZMATf, OUT, PADT);
            conv_res<<<2, 256, 0, stream>>>(QKVh, OUT, l_rw[1], PADT, 1);
            // dedicated M=1 out-projection matvec (was a pathological
            // 8-block gemm dispatch)
            matvec_out<<<2, 256, 0, stream>>>(OUT + (size_t)PADT * 512, l_ow[1],
                                              l_ob[1], XP + (size_t)PADT * 512, SEQ);
        }
    }
    final_kernel<<<1, 64, 0, stream>>>(SEQ, ng, nbv, fc2w, fc2b, out);
    (void)n_in; (void)out_size;
}

// Round 13
// 1510.491 us; speedup vs baseline: 1.3419x; 1.0053x over previous
//
#include <hip/hip_runtime.h>
#include <math.h>

#define LPAD  10240
#define NSEQ  10001
#define PADT  239
#define NPIX  10000

typedef unsigned short u16;
typedef __attribute__((ext_vector_type(8))) short short8;
typedef __attribute__((ext_vector_type(4))) float floatx4;

__device__ __forceinline__ float b2f(u16 u){ return __uint_as_float(((unsigned)u)<<16); }
__device__ __forceinline__ u16 f2b(float f){
    unsigned x = __float_as_uint(f);
    return (u16)((x + 0x7FFFu + ((x>>16)&1u)) >> 16);
}
__device__ __forceinline__ void gld16(const void* g, void* l){
    __builtin_amdgcn_global_load_lds(
        (const __attribute__((address_space(1))) unsigned int*)g,
        (__attribute__((address_space(3))) unsigned int*)l, 16, 0, 0);
}

// ---------------------------------------------------------------------------
// bf16 MFMA GEMM: C = A @ Bt^T (+bias)(+resid)(relu)(qscale). 64x128 tile,
// 4 waves, dbuf LDS, global_load_lds width-16 staging, k-slot XOR bank
// swizzle (round-8 config — best measured).
// ---------------------------------------------------------------------------
__global__ __launch_bounds__(256) void gemm_mfma(
    const u16* __restrict__ A, int lda, long sA,
    const u16* __restrict__ Bt, int ldb, long sB,
    void* __restrict__ Cv, int ldc, long sC,
    int M, int N, int K, int ksplit,
    const float* __restrict__ bias,
    const float* __restrict__ resid, int ldr,
    int relu, int qscale, int obf16, int atomic)
{
    __shared__ u16 As[2][64*32];
    __shared__ u16 Bs[2][128*32];

    int bz = blockIdx.z / ksplit;
    int ks = blockIdx.z - bz * ksplit;
    A  += (size_t)bz * sA;
    Bt += (size_t)bz * sB;

    int kchunk = (K + ksplit - 1) / ksplit;
    kchunk = (kchunk + 31) & ~31;
    int kbeg = ks * kchunk;
    int kend = kbeg + kchunk; if (kend > K) kend = K;

    int tid = threadIdx.x;
    int w = tid >> 6, lane = tid & 63;
    int wm = (w >> 1) * 32, wn = (w & 1) * 64;
    int m0 = blockIdx.y * 64, n0 = blockIdx.x * 128;

    int l4 = lane >> 2;
    int lk = (((lane & 3) ^ (l4 & 3)) * 8);
    int ra = w * 16 + l4;
    int rb = w * 32 + l4;
    int am0 = m0 + ra;      if (am0 > M-1) am0 = M-1;
    int bn0 = n0 + rb;      if (bn0 > N-1) bn0 = N-1;
    int bn1 = n0 + rb + 16; if (bn1 > N-1) bn1 = N-1;
    const u16* ag0 = A  + (size_t)am0 * lda + lk;
    const u16* bg0 = Bt + (size_t)bn0 * ldb + lk;
    const u16* bg1 = Bt + (size_t)bn1 * ldb + lk;
    int soA  = w * 512;
    int soB0 = w * 1024;
    int soB1 = w * 1024 + 512;

    floatx4 acc[2][4];
    #pragma unroll
    for (int i = 0; i < 2; i++)
        #pragma unroll
        for (int j = 0; j < 4; j++)
            acc[i][j] = (floatx4){0.f, 0.f, 0.f, 0.f};

    int arow = wm + (lane & 15);
    int nrow = wn + (lane & 15);
    int koff = (((lane >> 4) ^ (lane & 3)) * 8);

    if (kbeg < kend) {
        gld16(ag0 + kbeg, &As[0][soA]);
        gld16(bg0 + kbeg, &Bs[0][soB0]);
        gld16(bg1 + kbeg, &Bs[0][soB1]);
    }
    __syncthreads();

    int cb = 0;
    for (int k0 = kbeg; k0 < kend; k0 += 32) {
        int kn = k0 + 32;
        if (kn < kend) {
            gld16(ag0 + kn, &As[cb ^ 1][soA]);
            gld16(bg0 + kn, &Bs[cb ^ 1][soB0]);
            gld16(bg1 + kn, &Bs[cb ^ 1][soB1]);
        }
        short8 af[2], bf[4];
        #pragma unroll
        for (int i = 0; i < 2; i++) af[i] = *(const short8*)&As[cb][(arow + i*16)*32 + koff];
        #pragma unroll
        for (int j = 0; j < 4; j++) bf[j] = *(const short8*)&Bs[cb][(nrow + j*16)*32 + koff];
        #pragma unroll
        for (int i = 0; i < 2; i++)
            #pragma unroll
            for (int j = 0; j < 4; j++)
                acc[i][j] = __builtin_amdgcn_mfma_f32_16x16x32_bf16(af[i], bf[j], acc[i][j], 0, 0, 0);
        __syncthreads();
        cb ^= 1;
    }

    float* Cf = (float*)Cv;
    u16*   Ch = (u16*)Cv;
    size_t cb2 = (size_t)bz * sC;
    int rbase = m0 + wm + (lane >> 4) * 4;
    int cbase = n0 + wn + (lane & 15);
    #pragma unroll
    for (int i = 0; i < 2; i++) {
        #pragma unroll
        for (int j = 0; j < 4; j++) {
            int col = cbase + j * 16;
            if (col >= N) continue;
            float bcol = bias ? bias[col] : 0.f;
            #pragma unroll
            for (int r = 0; r < 4; r++) {
                int row = rbase + i * 16 + r;
                if (row >= M) continue;
                float v = acc[i][j][r];
                if (qscale && col < 512) v *= 0.125f;
                v += bcol;
                if (resid) v += resid[(size_t)row * ldr + col];
                if (relu) v = fmaxf(v, 0.f);
                size_t ci = cb2 + (size_t)row * ldc + col;
                if (obf16) Ch[ci] = f2b(v);
                else if (atomic) atomicAdd(&Cf[ci], v);
                else Cf[ci] = v;
            }
        }
    }
}

// ---------------------------------------------------------------------------
// fp32 tiled GEMM (Newton-Schulz chain + tiny gemms).
// 16x64 tile, 256 threads, double-buffered LDS staging (known-good).
// ---------------------------------------------------------------------------
__global__ __launch_bounds__(256) void gemm_big(
    const float* __restrict__ A, int lda, long sA,
    const float* __restrict__ B, int ldb, long sB,
    float* __restrict__ C, int ldc, long sC,
    int M, int N, int K,
    float alpha, float diagc,
    const float* __restrict__ bias,
    const float* __restrict__ resid, int ldr, long sR, float rescoef,
    int btrans)
{
    __shared__ float As[2][16][20];
    __shared__ float Bs[2][16][64];

    int bz = blockIdx.z;
    A += (size_t)bz * sA;
    B += (size_t)bz * sB;
    C += (size_t)bz * sC;

    int tid = threadIdx.x;
    int tx = tid & 15, ty = tid >> 4;
    int m0 = blockIdx.y * 16, n0 = blockIdx.x * 64;

    int ar = tid >> 2;
    int ak = (tid & 3) * 4;
    int bkr = tid >> 4;
    int bc4 = (tid & 15) * 4;
    int bc  = tid >> 2;
    int bkq = (tid & 3) * 4;

    auto loadA = [&](int k0, float4& ra) {
        if (tid < 64) {
            int m = m0 + ar;
            ra = make_float4(0.f, 0.f, 0.f, 0.f);
            if (m < M) ra = *(const float4*)(A + (size_t)m * lda + k0 + ak);
        }
    };
    auto loadB = [&](int k0, float4& rb) {
        if (!btrans) rb = *(const float4*)(B + (size_t)(k0 + bkr) * ldb + n0 + bc4);
        else         rb = *(const float4*)(B + (size_t)(n0 + bc) * ldb + k0 + bkq);
    };
    auto storeA = [&](int buf, const float4& ra) {
        if (tid < 64) {
            As[buf][ak + 0][ar] = ra.x; As[buf][ak + 1][ar] = ra.y;
            As[buf][ak + 2][ar] = ra.z; As[buf][ak + 3][ar] = ra.w;
        }
    };
    auto storeB = [&](int buf, const float4& rb) {
        if (!btrans) {
            *(float4*)&Bs[buf][bkr][bc4] = rb;
        } else {
            Bs[buf][bkq + 0][bc] = rb.x; Bs[buf][bkq + 1][bc] = rb.y;
            Bs[buf][bkq + 2][bc] = rb.z; Bs[buf][bkq + 3][bc] = rb.w;
        }
    };

    float acc[4];
    #pragma unroll
    for (int j = 0; j < 4; j++) acc[j] = 0.f;

    float4 pa, pb;
    loadA(0, pa); loadB(0, pb);
    storeA(0, pa); storeB(0, pb);
    int cur = 0;

    for (int k0 = 0; k0 < K; k0 += 16) {
        bool more = (k0 + 16) < K;
        float4 na, nb;
        if (more) { loadA(k0 + 16, na); loadB(k0 + 16, nb); }
        __syncthreads();
        #pragma unroll
        for (int k = 0; k < 16; k++) {
            float a = As[cur][k][ty];
            float4 bv = *(const float4*)&Bs[cur][k][tx * 4];
            acc[0] += a * bv.x; acc[1] += a * bv.y;
            acc[2] += a * bv.z; acc[3] += a * bv.w;
        }
        if (more) { storeA(cur ^ 1, na); storeB(cur ^ 1, nb); cur ^= 1; }
    }

    int m = m0 + ty;
    if (m < M) {
        #pragma unroll
        for (int j = 0; j < 4; j++) {
            int n = n0 + tx * 4 + j;
            float v = alpha * acc[j];
            if (diagc != 0.f && m == n) v += diagc;
            if (bias) v += bias[n];
            if (resid) v += rescoef * resid[(size_t)bz * sR + (size_t)m * ldr + n];
            C[(size_t)m * ldc + n] = v;
        }
    }
}

// ---------------------------------------------------------------------------
// Dedicated M=1 out-projection matvec (layer 1).
// ---------------------------------------------------------------------------
__global__ __launch_bounds__(256) void matvec_out(
    const float* __restrict__ x, const float* __restrict__ W,
    const float* __restrict__ bias, const float* __restrict__ resid,
    float* __restrict__ C)
{
    __shared__ float xs[512];
    int tid = threadIdx.x;
    xs[tid] = x[tid];
    xs[tid + 256] = x[tid + 256];
    __syncthreads();
    int n = blockIdx.x * 256 + tid;
    float acc = 0.f;
    #pragma unroll 8
    for (int k = 0; k < 512; k++)
        acc += xs[k] * W[(size_t)k * 512 + n];
    C[n] = acc + bias[n] + resid[n];
}

// ---------------------------------------------------------------------------
// Fused a1 chain (layer 0), wave-owns-rows, round-12: TWO 16-row token
// groups per wave (block = 128 tokens). KL fragments (lo,j,hh) and ZT
// fragments (hh,j,lo,ks) are token-independent, so each fragment load now
// feeds 2x the MFMA (64->128 MFMA/wave, same KL/ZT load count). Per-token
// accumulation sequence unchanged (aq0 j0-7, aq0 j8-15, aq1 j0-7, aq1
// j8-15; PV ks-ascending) -> bit-identical. Ps: 128 rows (66 KB LDS,
// 2 blocks/CU).
// ---------------------------------------------------------------------------
__global__ __launch_bounds__(256, 2) void a1z_fused(
    const u16* __restrict__ QKVh, const u16* __restrict__ KLh,
    const u16* __restrict__ ZTh, float* __restrict__ OUT, int T0)
{
    __shared__ u16 Ps[128 * 264];

    int tid = threadIdx.x;
    int w = tid >> 6, lane = tid & 63;
    int lo = lane & 15, hi = lane >> 4;
    int koff = hi * 8;
    int hh = blockIdx.y;
    int tok0 = T0 + blockIdx.x * 128;

    int trowA = tok0 + w * 16 + lo;       if (trowA > LPAD - 1) trowA = LPAD - 1;
    int trowB = tok0 + 64 + w * 16 + lo;  if (trowB > LPAD - 1) trowB = LPAD - 1;

    const u16* qbA = QKVh + (size_t)trowA * 1536 + hh * 64 + koff;
    const u16* qbB = QKVh + (size_t)trowB * 1536 + hh * 64 + koff;
    short8 aqA0 = *(const short8*)(qbA);
    short8 aqA1 = *(const short8*)(qbA + 32);
    short8 aqB0 = *(const short8*)(qbB);
    short8 aqB1 = *(const short8*)(qbB + 32);

    floatx4 accA[16], accB[16];
    #pragma unroll
    for (int j = 0; j < 16; j++) {
        accA[j] = (floatx4){0.f, 0.f, 0.f, 0.f};
        accB[j] = (floatx4){0.f, 0.f, 0.f, 0.f};
    }

    const u16* klb = KLh + (size_t)hh * 256 * 64 + lo * 64 + koff;
    {
        short8 bk[8];
        #pragma unroll
        for (int j = 0; j < 8; j++) bk[j] = *(const short8*)(klb + (size_t)j * 1024);
        #pragma unroll
        for (int j = 0; j < 8; j++) {
            accA[j] = __builtin_amdgcn_mfma_f32_16x16x32_bf16(aqA0, bk[j], accA[j], 0, 0, 0);
            accB[j] = __builtin_amdgcn_mfma_f32_16x16x32_bf16(aqB0, bk[j], accB[j], 0, 0, 0);
        }
    }
    {
        short8 bk[8];
        #pragma unroll
        for (int j = 0; j < 8; j++) bk[j] = *(const short8*)(klb + (size_t)(8 + j) * 1024);
        #pragma unroll
        for (int j = 0; j < 8; j++) {
            accA[8 + j] = __builtin_amdgcn_mfma_f32_16x16x32_bf16(aqA0, bk[j], accA[8 + j], 0, 0, 0);
            accB[8 + j] = __builtin_amdgcn_mfma_f32_16x16x32_bf16(aqB0, bk[j], accB[8 + j], 0, 0, 0);
        }
    }
    {
        short8 bk[8];
        #pragma unroll
        for (int j = 0; j < 8; j++) bk[j] = *(const short8*)(klb + (size_t)j * 1024 + 32);
        #pragma unroll
        for (int j = 0; j < 8; j++) {
            accA[j] = __builtin_amdgcn_mfma_f32_16x16x32_bf16(aqA1, bk[j], accA[j], 0, 0, 0);
            accB[j] = __builtin_amdgcn_mfma_f32_16x16x32_bf16(aqB1, bk[j], accB[j], 0, 0, 0);
        }
    }
    {
        short8 bk[8];
        #pragma unroll
        for (int j = 0; j < 8; j++) bk[j] = *(const short8*)(klb + (size_t)(8 + j) * 1024 + 32);
        #pragma unroll
        for (int j = 0; j < 8; j++) {
            accA[8 + j] = __builtin_amdgcn_mfma_f32_16x16x32_bf16(aqA1, bk[j], accA[8 + j], 0, 0, 0);
            accB[8 + j] = __builtin_amdgcn_mfma_f32_16x16x32_bf16(aqB1, bk[j], accB[8 + j], 0, 0, 0);
        }
    }

    // ---- wave-local softmax, group A then group B (rows are wave-private)
    #pragma unroll
    for (int slot = 0; slot < 4; slot++) {
        float mx = accA[0][slot];
        #pragma unroll
        for (int j = 1; j < 16; j++) mx = fmaxf(mx, accA[j][slot]);
        mx = fmaxf(mx, __shfl_xor(mx, 1, 64));
        mx = fmaxf(mx, __shfl_xor(mx, 2, 64));
        mx = fmaxf(mx, __shfl_xor(mx, 4, 64));
        mx = fmaxf(mx, __shfl_xor(mx, 8, 64));
        float p[16];
        float s = 0.f;
        #pragma unroll
        for (int j = 0; j < 16; j++) { p[j] = __expf(accA[j][slot] - mx); s += p[j]; }
        s += __shfl_xor(s, 1, 64);
        s += __shfl_xor(s, 2, 64);
        s += __shfl_xor(s, 4, 64);
        s += __shfl_xor(s, 8, 64);
        float inv = 1.f / s;
        int row = w * 16 + hi * 4 + slot;
        #pragma unroll
        for (int j = 0; j < 16; j++)
            Ps[row * 264 + j * 16 + lo] = f2b(p[j] * inv);
    }
    #pragma unroll
    for (int slot = 0; slot < 4; slot++) {
        float mx = accB[0][slot];
        #pragma unroll
        for (int j = 1; j < 16; j++) mx = fmaxf(mx, accB[j][slot]);
        mx = fmaxf(mx, __shfl_xor(mx, 1, 64));
        mx = fmaxf(mx, __shfl_xor(mx, 2, 64));
        mx = fmaxf(mx, __shfl_xor(mx, 4, 64));
        mx = fmaxf(mx, __shfl_xor(mx, 8, 64));
        float p[16];
        float s = 0.f;
        #pragma unroll
        for (int j = 0; j < 16; j++) { p[j] = __expf(accB[j][slot] - mx); s += p[j]; }
        s += __shfl_xor(s, 1, 64);
        s += __shfl_xor(s, 2, 64);
        s += __shfl_xor(s, 4, 64);
        s += __shfl_xor(s, 8, 64);
        float inv = 1.f / s;
        int row = 64 + w * 16 + hi * 4 + slot;
        #pragma unroll
        for (int j = 0; j < 16; j++)
            Ps[row * 264 + j * 16 + lo] = f2b(p[j] * inv);
    }
    // no barrier: each wave reads back only its own rows (lgkmcnt orders it)

    // ---- PV: both row groups, ZT fragments shared
    floatx4 acc2A[4], acc2B[4];
    #pragma unroll
    for (int j = 0; j < 4; j++) {
        acc2A[j] = (floatx4){0.f, 0.f, 0.f, 0.f};
        acc2B[j] = (floatx4){0.f, 0.f, 0.f, 0.f};
    }
    const u16* ztb = ZTh + ((size_t)hh * 64 + lo) * 256 + koff;
    int prA = (w * 16 + lo) * 264;
    int prB = (64 + w * 16 + lo) * 264;
    #pragma unroll
    for (int ks = 0; ks < 8; ks += 2) {
        short8 bz[8];
        #pragma unroll
        for (int j = 0; j < 4; j++)
            bz[j] = *(const short8*)(ztb + (size_t)j * 4096 + ks * 32);
        #pragma unroll
        for (int j = 0; j < 4; j++)
            bz[4 + j] = *(const short8*)(ztb + (size_t)j * 4096 + (ks + 1) * 32);
        short8 apA0 = *(const short8*)&Ps[prA + ks * 32 + koff];
        short8 apA1 = *(const short8*)&Ps[prA + (ks + 1) * 32 + koff];
        short8 apB0 = *(const short8*)&Ps[prB + ks * 32 + koff];
        short8 apB1 = *(const short8*)&Ps[prB + (ks + 1) * 32 + koff];
        #pragma unroll
        for (int j = 0; j < 4; j++) {
            acc2A[j] = __builtin_amdgcn_mfma_f32_16x16x32_bf16(apA0, bz[j], acc2A[j], 0, 0, 0);
            acc2B[j] = __builtin_amdgcn_mfma_f32_16x16x32_bf16(apB0, bz[j], acc2B[j], 0, 0, 0);
        }
        #pragma unroll
        for (int j = 0; j < 4; j++) {
            acc2A[j] = __builtin_amdgcn_mfma_f32_16x16x32_bf16(apA1, bz[4 + j], acc2A[j], 0, 0, 0);
            acc2B[j] = __builtin_amdgcn_mfma_f32_16x16x32_bf16(apB1, bz[4 + j], acc2B[j], 0, 0, 0);
        }
    }
    #pragma unroll
    for (int j = 0; j < 4; j++) {
        #pragma unroll
        for (int slot = 0; slot < 4; slot++) {
            int tokA = tok0 + w * 16 + hi * 4 + slot;
            if (tokA < LPAD)
                OUT[(size_t)tokA * 512 + hh * 64 + j * 16 + lo] = acc2A[j][slot];
            int tokB = tokA + 64;
            if (tokB < LPAD)
                OUT[(size_t)tokB * 512 + hh * 64 + j * 16 + lo] = acc2B[j][slot];
        }
    }
}

// ---------------------------------------------------------------------------
__global__ __launch_bounds__(256) void ln_kernel(
    const float* __restrict__ X, float* __restrict__ OUT, u16* __restrict__ OUTH,
    const float* __restrict__ g, const float* __restrict__ b, int nrows)
{
    int row = blockIdx.x * 4 + (threadIdx.x >> 6);
    int lane = threadIdx.x & 63;
    if (row >= nrows) return;
    const float* xr = X + (size_t)row * 512;
    float v[8]; float s = 0.f, s2 = 0.f;
    #pragma unroll
    for (int i = 0; i < 8; i++) { float t = xr[lane + i * 64]; v[i] = t; s += t; s2 += t * t; }
    for (int o = 1; o < 64; o <<= 1) { s += __shfl_xor(s, o, 64); s2 += __shfl_xor(s2, o, 64); }
    float mu = s * (1.f / 512.f);
    float var = s2 * (1.f / 512.f) - mu * mu;
    float rs = rsqrtf(var + 1e-5f);
    float* orow = OUT + (size_t)row * 512;
    u16* hrow = OUTH + (size_t)row * 512;
    #pragma unroll
    for (int i = 0; i < 8; i++) {
        int j = lane + i * 64;
        float y = (v[i] - mu) * rs * g[j] + b[j];
        orow[j] = y;
        hrow[j] = f2b(y);
    }
}

// Landmark means from bf16 QKVh; writes fp32 and bf16 copies
__global__ __launch_bounds__(64) void landmarks_kernel(
    const u16* __restrict__ QKVh, float* __restrict__ QL, float* __restrict__ KL,
    u16* __restrict__ QLh, u16* __restrict__ KLh)
{
    int mm = blockIdx.x, hh = blockIdx.y;
    int d = threadIdx.x;
    const u16* base = QKVh + (size_t)(mm * 40) * 1536 + hh * 64 + d;
    float sq = 0.f, sk = 0.f;
    for (int li = 0; li < 40; li++) {
        sq += b2f(base[(size_t)li * 1536]);
        sk += b2f(base[(size_t)li * 1536 + 512]);
    }
    size_t o = ((size_t)hh * 256 + mm) * 64 + d;
    float q = sq * (1.f / 40.f), k = sk * (1.f / 40.f);
    QL[o] = q; KL[o] = k;
    QLh[o] = f2b(q); KLh[o] = f2b(k);
}

// a2 softmax: wave per row (256 cols), fp32 in place
__global__ __launch_bounds__(256) void softmax_a2(
    float* __restrict__ A2, int nrows)
{
    int row = blockIdx.x * 4 + (threadIdx.x >> 6);
    int lane = threadIdx.x & 63;
    if (row >= nrows) return;
    float* p = A2 + (size_t)row * 256 + lane * 4;
    float4 v = *(float4*)p;
    float mx = fmaxf(fmaxf(v.x, v.y), fmaxf(v.z, v.w));
    for (int o = 1; o < 64; o <<= 1) mx = fmaxf(mx, __shfl_xor(mx, o, 64));
    float4 e = make_float4(__expf(v.x - mx), __expf(v.y - mx),
                           __expf(v.z - mx), __expf(v.w - mx));
    float s = e.x + e.y + e.z + e.w;
    for (int o = 1; o < 64; o <<= 1) s += __shfl_xor(s, o, 64);
    float inv = 1.f / s;
    e.x *= inv; e.y *= inv; e.z *= inv; e.w *= inv;
    *(float4*)p = e;
}

// block-per-row softmax (wide rows) -> bf16 probs, single global read via
// LDS row staging, float4 loads, packed bf16 stores.
__global__ __launch_bounds__(256) void row_softmax_bf16(
    const float* __restrict__ S, u16* __restrict__ P, int ncols)
{
    __shared__ float buf[LPAD];
    __shared__ float sr[4];
    int row = blockIdx.x;
    const float* p = S + (size_t)row * ncols;
    u16* q = P + (size_t)row * ncols;
    int tid = threadIdx.x;

    float mx = -1e30f;
    for (int i = tid * 4; i < ncols; i += 1024) {
        float4 v = *(const float4*)(p + i);
        *(float4*)&buf[i] = v;
        mx = fmaxf(mx, fmaxf(fmaxf(v.x, v.y), fmaxf(v.z, v.w)));
    }
    for (int o = 1; o < 64; o <<= 1) mx = fmaxf(mx, __shfl_xor(mx, o, 64));
    if ((tid & 63) == 0) sr[tid >> 6] = mx;
    __syncthreads();
    mx = fmaxf(fmaxf(sr[0], sr[1]), fmaxf(sr[2], sr[3]));

    float s = 0.f;
    for (int i = tid * 4; i < ncols; i += 1024) {
        float4 v = *(const float4*)&buf[i];
        s += __expf(v.x - mx) + __expf(v.y - mx) + __expf(v.z - mx) + __expf(v.w - mx);
    }
    for (int o = 1; o < 64; o <<= 1) s += __shfl_xor(s, o, 64);
    __syncthreads();
    if ((tid & 63) == 0) sr[tid >> 6] = s;
    __syncthreads();
    s = sr[0] + sr[1] + sr[2] + sr[3];
    float inv = 1.f / s;

    for (int i = tid * 4; i < ncols; i += 1024) {
        float4 v = *(const float4*)&buf[i];
        ushort4 o4;
        o4.x = f2b(__expf(v.x - mx) * inv);
        o4.y = f2b(__expf(v.y - mx) * inv);
        o4.z = f2b(__expf(v.z - mx) * inv);
        o4.w = f2b(__expf(v.w - mx) * inv);
        *(ushort4*)(q + i) = o4;
    }
}

__global__ __launch_bounds__(256) void a2norms_kernel(
    const float* __restrict__ A2, float* __restrict__ scal)
{
    int hh = blockIdx.x, tid = threadIdx.x;
    const float* A = A2 + (size_t)hh * 65536;
    float rs = 0.f, cs = 0.f;
    for (int j = 0; j < 256; j++) {
        rs += fabsf(A[(size_t)tid * 256 + j]);
        cs += fabsf(A[(size_t)j * 256 + tid]);
    }
    __shared__ float sm[8];
    for (int o = 1; o < 64; o <<= 1) {
        rs = fmaxf(rs, __shfl_xor(rs, o, 64));
        cs = fmaxf(cs, __shfl_xor(cs, o, 64));
    }
    if ((tid & 63) == 0) { sm[tid >> 6] = rs; sm[4 + (tid >> 6)] = cs; }
    __syncthreads();
    if (tid == 0) {
        float rm = fmaxf(fmaxf(sm[0], sm[1]), fmaxf(sm[2], sm[3]));
        float cm = fmaxf(fmaxf(sm[4], sm[5]), fmaxf(sm[6], sm[7]));
        atomicMax((unsigned int*)&scal[0], __float_as_uint(rm));
        atomicMax((unsigned int*)&scal[1], __float_as_uint(cm));
    }
}

// z0 = a2^T / denom (fp32 only)
__global__ __launch_bounds__(256) void z0_kernel(
    const float* __restrict__ A2, const float* __restrict__ scal,
    float* __restrict__ Zf)
{
    int i = blockIdx.x, hh = blockIdx.y, j = threadIdx.x;
    float inv = 1.f / (scal[0] * scal[1]);
    Zf[((size_t)hh * 256 + i) * 256 + j] = A2[((size_t)hh * 256 + j) * 256 + i] * inv;
}

// Tiny fused a1@Z for layer 1 (single token)
__global__ __launch_bounds__(256) void a1z_single(
    const u16* __restrict__ QKVh, const float* __restrict__ KL,
    const float* __restrict__ ZM, float* __restrict__ OUT, int tok)
{
    int h = blockIdx.x, tid = threadIdx.x;
    __shared__ float q[64];
    __shared__ float p[256];
    __shared__ float red[4];
    if (tid < 64) q[tid] = b2f(QKVh[(size_t)tok * 1536 + h * 64 + tid]);
    __syncthreads();
    const float* kl = KL + ((size_t)h * 256 + tid) * 64;
    float s = 0.f;
    for (int d = 0; d < 64; d++) s += q[d] * kl[d];
    float mx = s;
    for (int o = 1; o < 64; o <<= 1) mx = fmaxf(mx, __shfl_xor(mx, o, 64));
    if ((tid & 63) == 0) red[tid >> 6] = mx;
    __syncthreads();
    mx = fmaxf(fmaxf(red[0], red[1]), fmaxf(red[2], red[3]));
    float e = __expf(s - mx);
    float sum = e;
    for (int o = 1; o < 64; o <<= 1) sum += __shfl_xor(sum, o, 64);
    __syncthreads();
    if ((tid & 63) == 0) red[tid >> 6] = sum;
    __syncthreads();
    sum = red[0] + red[1] + red[2] + red[3];
    p[tid] = e / sum;
    __syncthreads();
    if (tid < 64) {
        float a = 0.f;
        for (int j = 0; j < 256; j++) a += p[j] * ZM[((size_t)h * 256 + j) * 64 + tid];
        OUT[(size_t)tok * 512 + h * 64 + tid] = a;
    }
}

// Depthwise 33-tap token conv fused with the bf16 cast.
__global__ __launch_bounds__(256) void conv_cast(
    const u16* __restrict__ QKVh, const float* __restrict__ OUT,
    u16* __restrict__ OUTH, const float* __restrict__ resw, int T0, int ntok)
{
    __shared__ u16 Vw[48][512];
    __shared__ float ws[264];
    int tid = threadIdx.x;
    int t0 = T0 + blockIdx.x * 16;
    int wv = tid >> 6, lnn = tid & 63;
    for (int r = wv; r < 48; r += 4) {
        int ts = t0 - 16 + r;
        short8 v = (short8){0,0,0,0,0,0,0,0};
        if (ts >= 0 && ts < LPAD)
            v = *(const short8*)(QKVh + (size_t)ts * 1536 + 1024 + lnn * 8);
        *(short8*)&Vw[r][lnn * 8] = v;
    }
    if (tid < 264) ws[tid] = resw[tid];
    __syncthreads();

    int c0 = tid * 2;
    int h = c0 >> 6;
    float wreg[33];
    #pragma unroll
    for (int r = 0; r < 33; r++) wreg[r] = ws[h * 33 + r];

    #pragma unroll 1
    for (int tk = 0; tk < 16; tk++) {
        int tok = t0 + tk;
        if (tok >= T0 + ntok) break;
        float a0 = 0.f, a1 = 0.f;
        #pragma unroll
        for (int r = 0; r < 33; r++) {
            unsigned pv = *(const unsigned*)&Vw[tk + r][c0];
            a0 += wreg[r] * __uint_as_float(pv << 16);
            a1 += wreg[r] * __uint_as_float(pv & 0xFFFF0000u);
        }
        float v0 = OUT[(size_t)tok * 512 + c0]     + a0;
        float v1 = OUT[(size_t)tok * 512 + c0 + 1] + a1;
        unsigned pk = ((unsigned)f2b(v1) << 16) | (unsigned)f2b(v0);
        *(unsigned*)&OUTH[(size_t)(tok - T0) * 512 + c0] = pk;
    }
}

// Old simple conv (layer 1, single token)
__global__ __launch_bounds__(256) void conv_res(
    const u16* __restrict__ QKVh, float* __restrict__ OUT,
    const float* __restrict__ resw, int t0, int ntok)
{
    int idx = blockIdx.x * 256 + threadIdx.x;
    if (idx >= ntok * 512) return;
    int tok = t0 + (idx >> 9);
    int c = idx & 511;
    int h = c >> 6;
    const u16* vbase = QKVh + 1024 + c;
    float acc = 0.f;
    #pragma unroll 1
    for (int r = 0; r < 33; r++) {
        int ts = tok - 16 + r;
        if (ts >= 0 && ts < LPAD)
            acc += resw[h * 33 + r] * b2f(vbase[(size_t)ts * 1536]);
    }
    OUT[(size_t)tok * 512 + c] += acc;
}

// V slice of QKVh -> Vt[h][d][t] (bf16)
__global__ __launch_bounds__(256) void vtrans(
    const u16* __restrict__ QKVh, u16* __restrict__ Vt)
{
    int t0 = blockIdx.x * 64, hh = blockIdx.y;
    __shared__ u16 tile[64][65];
    #pragma unroll
    for (int ii = 0; ii < 16; ii++) {
        int idx = threadIdx.x + ii * 256;
        int t = idx >> 6, d = idx & 63;
        tile[t][d] = QKVh[(size_t)(t0 + t) * 1536 + 1024 + hh * 64 + d];
    }
    __syncthreads();
    #pragma unroll
    for (int ii = 0; ii < 16; ii++) {
        int idx = threadIdx.x + ii * 256;
        int d = idx >> 6, t = idx & 63;
        Vt[((size_t)hh * 64 + d) * LPAD + t0 + t] = tile[t][d];
    }
}

// Combine PPEG weights: W49[tap][c] = w7 + w5(in range) + w3(in range)
__global__ void ppeg_combine(
    const float* __restrict__ w7, const float* __restrict__ w5,
    const float* __restrict__ w3, const float* __restrict__ b7,
    const float* __restrict__ b5, const float* __restrict__ b3,
    float* __restrict__ W49, float* __restrict__ BSUM)
{
    int idx = blockIdx.x * 256 + threadIdx.x;
    if (idx >= 49 * 512) return;
    int tap = idx >> 9, c = idx & 511;
    int dy = tap / 7 - 3, dx = tap % 7 - 3;
    float v = w7[c * 49 + tap];
    if (dy >= -2 && dy <= 2 && dx >= -2 && dx <= 2)
        v += w5[c * 25 + (dy + 2) * 5 + (dx + 2)];
    if (dy >= -1 && dy <= 1 && dx >= -1 && dx <= 1)
        v += w3[c * 9 + (dy + 1) * 3 + (dx + 1)];
    W49[tap * 512 + c] = v;
    if (tap == 0) BSUM[c] = b7[c] + b5[c] + b3[c];
}

// PPEG, tiled: block = 16x4 position tile x 64 channels, fully-unrolled
// float4 halo staging.
__global__ __launch_bounds__(256) void ppeg_tile(
    const float* __restrict__ S, float* __restrict__ O,
    const float* __restrict__ W49, const float* __restrict__ BSUM)
{
    __shared__ float Sw[10][22][64];
    int tid = threadIdx.x;
    int c = tid & 63;
    int sub = tid >> 6;
    int x0 = blockIdx.x * 16;
    int y0 = blockIdx.y * 4;
    int cg = blockIdx.z * 64;

    {
        int p = tid >> 4;
        int c4 = (tid & 15) * 4;
        #pragma unroll
        for (int i = 0; i < 14; i++) {
            int f = p + i * 16;
            if (f < 220) {
                int r = f / 22, xx = f - r * 22;
                int gy = y0 - 3 + r;
                int gx = x0 - 3 + xx;
                float4 v = make_float4(0.f, 0.f, 0.f, 0.f);
                if ((unsigned)gy < 100u && (unsigned)gx < 100u)
                    v = *(const float4*)(S + (size_t)(1 + gy * 100 + gx) * 512 + cg + c4);
                *(float4*)&Sw[r][xx][c4] = v;
            }
        }
    }
    float wreg[49];
    #pragma unroll
    for (int t = 0; t < 49; t++) wreg[t] = W49[t * 512 + cg + c];
    float bsum = BSUM[cg + c];
    __syncthreads();

    int xb = sub * 4;
    float acc[4][4];
    #pragma unroll
    for (int yy = 0; yy < 4; yy++)
        #pragma unroll
        for (int xq = 0; xq < 4; xq++)
            acc[yy][xq] = Sw[yy + 3][xb + xq + 3][c] + bsum;

    #pragma unroll
    for (int r = 0; r < 10; r++) {
        float v[10];
        #pragma unroll
        for (int j = 0; j < 10; j++) v[j] = Sw[r][xb + j][c];
        #pragma unroll
        for (int yy = 0; yy < 4; yy++) {
            int t = r - yy;
            if (t < 0 || t > 6) continue;
            #pragma unroll
            for (int dxt = 0; dxt < 7; dxt++) {
                float w = wreg[t * 7 + dxt];
                #pragma unroll
                for (int xq = 0; xq < 4; xq++)
                    acc[yy][xq] += v[xq + dxt] * w;
            }
        }
    }

    #pragma unroll
    for (int yy = 0; yy < 4; yy++) {
        int gy = y0 + yy;
        #pragma unroll
        for (int xq = 0; xq < 4; xq++) {
            int gx = x0 + xb + xq;
            if (gx < 100)
                O[(size_t)(1 + gy * 100 + gx) * 512 + cg + c] = acc[yy][xq];
        }
    }
}

__global__ __launch_bounds__(64) void final_kernel(
    const float* __restrict__ S, const float* __restrict__ g, const float* __restrict__ b,
    const float* __restrict__ w, const float* __restrict__ bb, float* __restrict__ out)
{
    int lane = threadIdx.x;
    float v[8]; float s = 0.f, s2 = 0.f;
    #pragma unroll
    for (int i = 0; i < 8; i++) { float t = S[lane + i * 64]; v[i] = t; s += t; s2 += t * t; }
    for (int o = 1; o < 64; o <<= 1) { s += __shfl_xor(s, o, 64); s2 += __shfl_xor(s2, o, 64); }
    float mu = s * (1.f / 512.f);
    float var = s2 * (1.f / 512.f) - mu * mu;
    float rs = rsqrtf(var + 1e-5f);
    float o0 = 0.f, o1 = 0.f;
    #pragma unroll
    for (int i = 0; i < 8; i++) {
        int j = lane + i * 64;
        float xn = (v[i] - mu) * rs * g[j] + b[j];
        o0 += xn * w[j * 2 + 0];
        o1 += xn * w[j * 2 + 1];
    }
    for (int o = 1; o < 64; o <<= 1) { o0 += __shfl_xor(o0, o, 64); o1 += __shfl_xor(o1, o, 64); }
    if (lane == 0) { out[0] = o0 + bb[0]; out[1] = o1 + bb[1]; }
}

__global__ void zerok(float* p, int n)
{
    int i = blockIdx.x * 256 + threadIdx.x;
    if (i < n) p[i] = 0.f;
}
__global__ void zero2k(float* p) { p[0] = 0.f; p[1] = 0.f; }
__global__ void copy512(float* dst, const float* src)
{
    int i = blockIdx.x * 256 + threadIdx.x;
    if (i < 512) dst[i] = src[i];
}
__global__ void cast_bf16(const float* __restrict__ src, u16* __restrict__ dst, int n)
{
    int i = (blockIdx.x * 256 + threadIdx.x) * 4;
    if (i >= n) return;
    float4 v = *(const float4*)(src + i);
    dst[i + 0] = f2b(v.x); dst[i + 1] = f2b(v.y);
    dst[i + 2] = f2b(v.z); dst[i + 3] = f2b(v.w);
}
// dst[b][c][r] = src[b][r][c]  (cast-transpose fp32 RxC -> bf16 CxR)
__global__ void castT(const float* __restrict__ src, u16* __restrict__ dst,
                      int R, int C, int nb)
{
    size_t idx = (size_t)blockIdx.x * 256 + threadIdx.x;
    size_t tot = (size_t)R * C * nb;
    if (idx >= tot) return;
    int rc = R * C;
    int b = (int)(idx / rc);
    int rem = (int)(idx - (size_t)b * rc);
    int c = rem / R, r = rem - c * R;
    dst[idx] = f2b(src[(size_t)b * rc + (size_t)r * C + c]);
}

// ---------------------------------------------------------------------------
extern "C" void kernel_launch(void* const* d_in, const int* in_sizes, int n_in,
                              void* d_out, int out_size, void* d_ws, size_t ws_size,
                              hipStream_t stream)
{
    const float* h     = (const float*)d_in[0];
    const float* fc1_w = (const float*)d_in[1];
    const float* fc1_b = (const float*)d_in[2];
    const float* cls   = (const float*)d_in[3];
    bool sigorder = (in_sizes[10] == 512 * 49);
    int i_l2 = sigorder ? 16 : 10;
    int i_pp = sigorder ? 10 : 16;
    const float* l_g[2]   = { (const float*)d_in[4], (const float*)d_in[i_l2 + 0] };
    const float* l_b[2]   = { (const float*)d_in[5], (const float*)d_in[i_l2 + 1] };
    const float* l_qkv[2] = { (const float*)d_in[6], (const float*)d_in[i_l2 + 2] };
    const float* l_ow[2]  = { (const float*)d_in[7], (const float*)d_in[i_l2 + 3] };
    const float* l_ob[2]  = { (const float*)d_in[8], (const float*)d_in[i_l2 + 4] };
    const float* l_rw[2]  = { (const float*)d_in[9], (const float*)d_in[i_l2 + 5] };
    const float* w7 = (const float*)d_in[i_pp + 0];
    const float* b7 = (const float*)d_in[i_pp + 1];
    const float* w5 = (const float*)d_in[i_pp + 2];
    const float* b5 = (const float*)d_in[i_pp + 3];
    const float* w3 = (const float*)d_in[i_pp + 4];
    const float* b3 = (const float*)d_in[i_pp + 5];
    const float* ng   = (const float*)d_in[22];
    const float* nbv  = (const float*)d_in[23];
    const float* fc2w = (const float*)d_in[24];
    const float* fc2b = (const float*)d_in[25];
    float* out = (float*)d_out;

    char* Wb = (char*)d_ws;
    size_t off = 0;
    auto allocB = [&](size_t bytes) { void* p = Wb + off; off = (off + bytes + 255) & ~(size_t)255; return p; };

    float* SEQ   = (float*)allocB((size_t)NSEQ * 512 * 4);
    float* XP    = (float*)allocB((size_t)LPAD * 512 * 4);
    u16*   XPh   = (u16*)  allocB((size_t)LPAD * 512 * 2);
    u16*   QKVh  = (u16*)  allocB((size_t)LPAD * 1536 * 2);
    float* QLKL  = (float*)allocB((size_t)262144 * 4);
    float* QL = QLKL, *KL = QLKL + 131072;
    u16*   QLKLh = (u16*)  allocB((size_t)262144 * 2);
    u16*   QLh = QLKLh, *KLh = QLKLh + 131072;
    float* A2   = (float*)allocB(524288 * 4);
    float* Zf0  = (float*)allocB(524288 * 4);
    float* Zf1  = (float*)allocB(524288 * 4);
    float* XZf  = (float*)allocB(524288 * 4);
    float* W2b  = (float*)allocB(524288 * 4);
    float* W3b  = (float*)allocB(524288 * 4);
    float* A3V  = (float*)allocB(131072 * 4);
    float* ZMATf= (float*)allocB(131072 * 4);
    u16*   ZMATt= (u16*)  allocB(131072 * 2);
    u16*   Vt   = (u16*)  allocB((size_t)8 * 64 * LPAD * 2);
    u16*   fc1wt= (u16*)  allocB(524288 * 2);
    u16*   qkvwt= (u16*)  allocB(786432 * 2);
    u16*   outwt= (u16*)  allocB(262144 * 2);
    float* W49  = (float*)allocB(49 * 512 * 4);
    float* BSUM = (float*)allocB(512 * 4);
    float* SCAL = (float*)allocB(16);
    void*  U1   = allocB((size_t)LPAD * 512 * 4);
    u16*   hbf  = (u16*)U1;
    float* OUT  = (float*)U1;
    float* SEQ2 = OUT;
    size_t fixed = off;

    size_t scB_b = (size_t)8 * 256 * LPAD * 4;
    size_t phB_b = (size_t)8 * 256 * LPAD * 2;
    bool batched = ws_size >= fixed + scB_b + phB_b;
    float* SC; u16* Ph;
    if (batched) {
        SC = (float*)(Wb + fixed);
        Ph = (u16*)(Wb + fixed + scB_b);
    } else {
        SC = (float*)(Wb + fixed);
        Ph = (u16*)(Wb + fixed + (size_t)256 * LPAD * 4);
    }
    u16* OUTh = (u16*)SC;   // alias: SC dead when OUTh materialized

    auto mgemm = [&](const u16* A, int lda, long sA, const u16* Bt, int ldb, long sB,
                     void* C, int ldc, long sC, int M, int N, int K,
                     const float* bias, const float* resid, int ldr,
                     int relu, int qscale, int obf16, int nbatch, int ksplit, int atomic) {
        dim3 grid((N + 127) / 128, (M + 63) / 64, nbatch * ksplit);
        gemm_mfma<<<grid, 256, 0, stream>>>(A, lda, sA, Bt, ldb, sB, C, ldc, sC,
            M, N, K, ksplit, bias, resid, ldr, relu, qscale, obf16, atomic);
    };
    auto fgemm = [&](const float* A, int lda, long sA, const float* B, int ldb, long sB,
                     float* C, int ldc, long sC, int M, int N, int K,
                     float alpha, float diagc, const float* bias,
                     const float* resid, int ldr, long sR, float rescoef,
                     int btrans, int nbatch) {
        dim3 grid(N / 64, (M + 15) / 16, nbatch);
        gemm_big<<<grid, 256, 0, stream>>>(A, lda, sA, B, ldb, sB, C, ldc, sC, M, N, K,
            alpha, diagc, bias, resid, ldr, sR, rescoef, btrans);
    };

    // ---- prologue
    cast_bf16<<<(NPIX * 1024 / 4 + 255) / 256, 256, 0, stream>>>(h, hbf, NPIX * 1024);
    castT<<<(524288 + 255) / 256, 256, 0, stream>>>(fc1_w, fc1wt, 1024, 512, 1);
    mgemm(hbf, 1024, 0, fc1wt, 1024, 0, SEQ + 512, 512, 0, NPIX, 512, 1024,
          fc1_b, nullptr, 0, 1, 0, 0, 1, 1, 0);
    copy512<<<2, 256, 0, stream>>>(SEQ, cls);
    zerok<<<(PADT * 512 + 255) / 256, 256, 0, stream>>>(XP, PADT * 512);
    zerok<<<(PADT * 256 + 255) / 256, 256, 0, stream>>>((float*)XPh, PADT * 256);
    ppeg_combine<<<(49 * 512 + 255) / 256, 256, 0, stream>>>(w7, w5, w3, b7, b5, b3, W49, BSUM);

    for (int layer = 0; layer < 2; layer++) {
        const float* curSEQ = (layer == 0) ? SEQ : SEQ2;
        ln_kernel<<<(NSEQ + 3) / 4, 256, 0, stream>>>(curSEQ, XP + (size_t)PADT * 512,
            XPh + (size_t)PADT * 512, l_g[layer], l_b[layer], NSEQ);
        castT<<<(786432 + 255) / 256, 256, 0, stream>>>(l_qkv[layer], qkvwt, 512, 1536, 1);
        mgemm(XPh, 512, 0, qkvwt, 512, 0, QKVh, 1536, 0, LPAD, 1536, 512,
              nullptr, nullptr, 0, 0, 1, 1, 1, 1, 0);
        landmarks_kernel<<<dim3(256, 8), 64, 0, stream>>>(QKVh, QL, KL, QLh, KLh);
        // a2 = softmax(ql @ kl^T)  (fp32)
        fgemm(QL, 64, 16384, KL, 64, 16384, A2, 256, 65536, 256, 256, 64,
              1.f, 0.f, nullptr, nullptr, 0, 0, 0.f, 1, 8);
        softmax_a2<<<512, 256, 0, stream>>>(A2, 2048);
        zero2k<<<1, 1, 0, stream>>>(SCAL);
        a2norms_kernel<<<8, 256, 0, stream>>>(A2, SCAL);
        z0_kernel<<<dim3(256, 8), 256, 0, stream>>>(A2, SCAL, Zf0);

        // Newton-Schulz: 6 fp32 iterations
        float* zc = Zf0; float* zn = Zf1;
        for (int it = 0; it < 6; it++) {
            fgemm(A2, 256, 65536, zc, 256, 65536, XZf, 256, 65536, 256, 256, 256,
                  1.f, 0.f, nullptr, nullptr, 0, 0, 0.f, 0, 8);
            fgemm(XZf, 256, 65536, XZf, 256, 65536, W2b, 256, 65536, 256, 256, 256,
                  1.f, 15.f, nullptr, XZf, 256, 65536, -7.f, 0, 8);
            fgemm(XZf, 256, 65536, W2b, 256, 65536, W3b, 256, 65536, 256, 256, 256,
                  -1.f, 13.f, nullptr, nullptr, 0, 0, 0.f, 0, 8);
            fgemm(zc, 256, 65536, W3b, 256, 65536, zn, 256, 65536, 256, 256, 256,
                  0.25f, 0.f, nullptr, nullptr, 0, 0, 0.f, 0, 8);
            float* t = zc; zc = zn; zn = t;
        }
        float* zfin = zc;

        // a3v = softmax(ql @ k^T) @ v  via MFMA
        vtrans<<<dim3(160, 8), 256, 0, stream>>>(QKVh, Vt);
        zerok<<<512, 256, 0, stream>>>(A3V, 131072);
        if (batched) {
            mgemm(QLh, 64, 16384, QKVh + 512, 1536, 64, SC, LPAD, (long)256 * LPAD,
                  256, LPAD, 64, nullptr, nullptr, 0, 0, 0, 0, 8, 1, 0);
            row_softmax_bf16<<<2048, 256, 0, stream>>>(SC, Ph, LPAD);
            mgemm(Ph, LPAD, (long)256 * LPAD, Vt, LPAD, (long)64 * LPAD, A3V, 64, 16384,
                  256, 64, LPAD, nullptr, nullptr, 0, 0, 0, 0, 8, 40, 1);
        } else {
            for (int hh = 0; hh < 8; hh++) {
                mgemm(QLh + (size_t)hh * 16384, 64, 0, QKVh + 512 + hh * 64, 1536, 0,
                      SC, LPAD, 0, 256, LPAD, 64, nullptr, nullptr, 0, 0, 0, 0, 1, 1, 0);
                row_softmax_bf16<<<256, 256, 0, stream>>>(SC, Ph, LPAD);
                mgemm(Ph, LPAD, 0, Vt + (size_t)hh * 64 * LPAD, LPAD, 0,
                      A3V + (size_t)hh * 16384, 64, 0, 256, 64, LPAD,
                      nullptr, nullptr, 0, 0, 0, 0, 1, 40, 1);
            }
        }
        // ZMAT = pinv(a2) @ a3v  (fp32)
        fgemm(zfin, 256, 65536, A3V, 64, 16384, ZMATf, 64, 16384, 256, 64, 256,
              1.f, 0.f, nullptr, nullptr, 0, 0, 0.f, 0, 8);

        if (layer == 0) {
            // Z^T bf16 for the fused a1 chain
            castT<<<(131072 + 255) / 256, 256, 0, stream>>>(ZMATf, ZMATt, 256, 64, 8);
            // fused scores+softmax+PZ: one launch, 128 tokens/block
            a1z_fused<<<dim3((NSEQ + 127) / 128, 8), 256, 0, stream>>>(
                QKVh, KLh, ZMATt, OUT, PADT);
            // conv + bf16 cast fused (writes OUTh directly)
            conv_cast<<<(NSEQ + 15) / 16, 256, 0, stream>>>(
                QKVh, OUT, OUTh, l_rw[0], PADT, NSEQ);
            castT<<<(262144 + 255) / 256, 256, 0, stream>>>(l_ow[0], outwt, 512, 512, 1);
            mgemm(OUTh, 512, 0, outwt, 512, 0, SEQ, 512, 0, NSEQ, 512, 512,
                  l_ob[0], XP + (size_t)PADT * 512, 512, 0, 0, 0, 1, 1, 0);
            // PPEG (tiled, unrolled float4 staging)
            ppeg_tile<<<dim3(7, 25, 8), 256, 0, stream>>>(SEQ, SEQ2, W49, BSUM);
            copy512<<<2, 256, 0, stream>>>(SEQ2, SEQ);
        } else {
            a1z_single<<<8, 256, 0, stream>>>(QKVh, KL, ZMATf, OUT, PADT);
            conv_res<<<2, 256, 0, stream>>>(QKVh, OUT, l_rw[1], PADT, 1);
            // dedicated M=1 out-projection matvec
            matvec_out<<<2, 256, 0, stream>>>(OUT + (size_t)PADT * 512, l_ow[1],
                                              l_ob[1], XP + (size_t)PADT * 512, SEQ);
        }
    }
    final_kernel<<<1, 64, 0, stream>>>(SEQ, ng, nbv, fc2w, fc2b, out);
    (void)n_in; (void)out_size;
}

// Round 14
// 1381.565 us; speedup vs baseline: 1.4672x; 1.0933x over previous
//
#include <hip/hip_runtime.h>
#include <math.h>

#define LPAD  10240
#define NSEQ  10001
#define PADT  239
#define NPIX  10000

typedef unsigned short u16;
typedef __attribute__((ext_vector_type(8))) short short8;
typedef __attribute__((ext_vector_type(4))) float floatx4;

__device__ __forceinline__ float b2f(u16 u){ return __uint_as_float(((unsigned)u)<<16); }
__device__ __forceinline__ u16 f2b(float f){
    unsigned x = __float_as_uint(f);
    return (u16)((x + 0x7FFFu + ((x>>16)&1u)) >> 16);
}
__device__ __forceinline__ void gld16(const void* g, void* l){
    __builtin_amdgcn_global_load_lds(
        (const __attribute__((address_space(1))) unsigned int*)g,
        (__attribute__((address_space(3))) unsigned int*)l, 16, 0, 0);
}

// ---------------------------------------------------------------------------
// bf16 MFMA GEMM: C = A @ Bt^T (+bias)(+resid)(relu)(qscale). 64x128 tile,
// 4 waves, dbuf LDS, global_load_lds width-16 staging, k-slot XOR bank
// swizzle (round-8 config — best measured).
// ---------------------------------------------------------------------------
__global__ __launch_bounds__(256) void gemm_mfma(
    const u16* __restrict__ A, int lda, long sA,
    const u16* __restrict__ Bt, int ldb, long sB,
    void* __restrict__ Cv, int ldc, long sC,
    int M, int N, int K, int ksplit,
    const float* __restrict__ bias,
    const float* __restrict__ resid, int ldr,
    int relu, int qscale, int obf16, int atomic)
{
    __shared__ u16 As[2][64*32];
    __shared__ u16 Bs[2][128*32];

    int bz = blockIdx.z / ksplit;
    int ks = blockIdx.z - bz * ksplit;
    A  += (size_t)bz * sA;
    Bt += (size_t)bz * sB;

    int kchunk = (K + ksplit - 1) / ksplit;
    kchunk = (kchunk + 31) & ~31;
    int kbeg = ks * kchunk;
    int kend = kbeg + kchunk; if (kend > K) kend = K;

    int tid = threadIdx.x;
    int w = tid >> 6, lane = tid & 63;
    int wm = (w >> 1) * 32, wn = (w & 1) * 64;
    int m0 = blockIdx.y * 64, n0 = blockIdx.x * 128;

    int l4 = lane >> 2;
    int lk = (((lane & 3) ^ (l4 & 3)) * 8);
    int ra = w * 16 + l4;
    int rb = w * 32 + l4;
    int am0 = m0 + ra;      if (am0 > M-1) am0 = M-1;
    int bn0 = n0 + rb;      if (bn0 > N-1) bn0 = N-1;
    int bn1 = n0 + rb + 16; if (bn1 > N-1) bn1 = N-1;
    const u16* ag0 = A  + (size_t)am0 * lda + lk;
    const u16* bg0 = Bt + (size_t)bn0 * ldb + lk;
    const u16* bg1 = Bt + (size_t)bn1 * ldb + lk;
    int soA  = w * 512;
    int soB0 = w * 1024;
    int soB1 = w * 1024 + 512;

    floatx4 acc[2][4];
    #pragma unroll
    for (int i = 0; i < 2; i++)
        #pragma unroll
        for (int j = 0; j < 4; j++)
            acc[i][j] = (floatx4){0.f, 0.f, 0.f, 0.f};

    int arow = wm + (lane & 15);
    int nrow = wn + (lane & 15);
    int koff = (((lane >> 4) ^ (lane & 3)) * 8);

    if (kbeg < kend) {
        gld16(ag0 + kbeg, &As[0][soA]);
        gld16(bg0 + kbeg, &Bs[0][soB0]);
        gld16(bg1 + kbeg, &Bs[0][soB1]);
    }
    __syncthreads();

    int cb = 0;
    for (int k0 = kbeg; k0 < kend; k0 += 32) {
        int kn = k0 + 32;
        if (kn < kend) {
            gld16(ag0 + kn, &As[cb ^ 1][soA]);
            gld16(bg0 + kn, &Bs[cb ^ 1][soB0]);
            gld16(bg1 + kn, &Bs[cb ^ 1][soB1]);
        }
        short8 af[2], bf[4];
        #pragma unroll
        for (int i = 0; i < 2; i++) af[i] = *(const short8*)&As[cb][(arow + i*16)*32 + koff];
        #pragma unroll
        for (int j = 0; j < 4; j++) bf[j] = *(const short8*)&Bs[cb][(nrow + j*16)*32 + koff];
        #pragma unroll
        for (int i = 0; i < 2; i++)
            #pragma unroll
            for (int j = 0; j < 4; j++)
                acc[i][j] = __builtin_amdgcn_mfma_f32_16x16x32_bf16(af[i], bf[j], acc[i][j], 0, 0, 0);
        __syncthreads();
        cb ^= 1;
    }

    float* Cf = (float*)Cv;
    u16*   Ch = (u16*)Cv;
    size_t cb2 = (size_t)bz * sC;
    int rbase = m0 + wm + (lane >> 4) * 4;
    int cbase = n0 + wn + (lane & 15);
    #pragma unroll
    for (int i = 0; i < 2; i++) {
        #pragma unroll
        for (int j = 0; j < 4; j++) {
            int col = cbase + j * 16;
            if (col >= N) continue;
            float bcol = bias ? bias[col] : 0.f;
            #pragma unroll
            for (int r = 0; r < 4; r++) {
                int row = rbase + i * 16 + r;
                if (row >= M) continue;
                float v = acc[i][j][r];
                if (qscale && col < 512) v *= 0.125f;
                v += bcol;
                if (resid) v += resid[(size_t)row * ldr + col];
                if (relu) v = fmaxf(v, 0.f);
                size_t ci = cb2 + (size_t)row * ldc + col;
                if (obf16) Ch[ci] = f2b(v);
                else if (atomic) atomicAdd(&Cf[ci], v);
                else Cf[ci] = v;
            }
        }
    }
}

// ---------------------------------------------------------------------------
// fp32 tiled GEMM (Newton-Schulz chain + tiny gemms).
// C = alpha*A@B + diagc*I + bias + rescoef*resid.
// 16x64 tile, 256 threads (1x4 per thread), double-buffered LDS staging.
// Round-13: BK=32 (was 16) — halves the K-step/barrier count (16->8 for
// the K=256 NS gemms, the dominant unprofiled aggregate: 52 dispatches per
// iteration). Same tile/grid (parallelism unchanged), LDS 21.5 KB (still
// 6 blocks/CU capacity). Per-output accumulation remains strictly
// k-ascending -> bit-identical numerics; only staging grouping changes.
// All call sites have K in {64,256} (divisible by 32).
// ---------------------------------------------------------------------------
__global__ __launch_bounds__(256) void gemm_big(
    const float* __restrict__ A, int lda, long sA,
    const float* __restrict__ B, int ldb, long sB,
    float* __restrict__ C, int ldc, long sC,
    int M, int N, int K,
    float alpha, float diagc,
    const float* __restrict__ bias,
    const float* __restrict__ resid, int ldr, long sR, float rescoef,
    int btrans)
{
    __shared__ float As[2][32][20];
    __shared__ float Bs[2][32][64];

    int bz = blockIdx.z;
    A += (size_t)bz * sA;
    B += (size_t)bz * sB;
    C += (size_t)bz * sC;

    int tid = threadIdx.x;
    int tx = tid & 15, ty = tid >> 4;
    int m0 = blockIdx.y * 16, n0 = blockIdx.x * 64;

    // A staging (threads 0..127): row ar (0..15), k-quad ak (0..28)
    int ar = tid >> 3;
    int ak = (tid & 7) * 4;
    // B staging (!btrans): k-rows bkr and bkr+16, col-quad bc4
    int bkr = tid >> 4;
    int bc4 = (tid & 15) * 4;
    // B staging (btrans): col bc (0..63), k-octet bkq (0,8,16,24)
    int bc  = tid >> 2;
    int bkq = (tid & 3) * 8;

    auto loadA = [&](int k0, float4& ra) {
        if (tid < 128) {
            int m = m0 + ar;
            ra = make_float4(0.f, 0.f, 0.f, 0.f);
            if (m < M) ra = *(const float4*)(A + (size_t)m * lda + k0 + ak);
        }
    };
    auto loadB = [&](int k0, float4& rb0, float4& rb1) {
        if (!btrans) {
            rb0 = *(const float4*)(B + (size_t)(k0 + bkr) * ldb + n0 + bc4);
            rb1 = *(const float4*)(B + (size_t)(k0 + bkr + 16) * ldb + n0 + bc4);
        } else {
            const float* bp = B + (size_t)(n0 + bc) * ldb + k0 + bkq;
            rb0 = *(const float4*)(bp);
            rb1 = *(const float4*)(bp + 4);
        }
    };
    auto storeA = [&](int buf, const float4& ra) {
        if (tid < 128) {
            As[buf][ak + 0][ar] = ra.x; As[buf][ak + 1][ar] = ra.y;
            As[buf][ak + 2][ar] = ra.z; As[buf][ak + 3][ar] = ra.w;
        }
    };
    auto storeB = [&](int buf, const float4& rb0, const float4& rb1) {
        if (!btrans) {
            *(float4*)&Bs[buf][bkr][bc4] = rb0;
            *(float4*)&Bs[buf][bkr + 16][bc4] = rb1;
        } else {
            Bs[buf][bkq + 0][bc] = rb0.x; Bs[buf][bkq + 1][bc] = rb0.y;
            Bs[buf][bkq + 2][bc] = rb0.z; Bs[buf][bkq + 3][bc] = rb0.w;
            Bs[buf][bkq + 4][bc] = rb1.x; Bs[buf][bkq + 5][bc] = rb1.y;
            Bs[buf][bkq + 6][bc] = rb1.z; Bs[buf][bkq + 7][bc] = rb1.w;
        }
    };

    float acc[4];
    #pragma unroll
    for (int j = 0; j < 4; j++) acc[j] = 0.f;

    float4 pa, pb0, pb1;
    loadA(0, pa); loadB(0, pb0, pb1);
    storeA(0, pa); storeB(0, pb0, pb1);
    int cur = 0;

    for (int k0 = 0; k0 < K; k0 += 32) {
        bool more = (k0 + 32) < K;
        float4 na, nb0, nb1;
        if (more) { loadA(k0 + 32, na); loadB(k0 + 32, nb0, nb1); }
        __syncthreads();
        #pragma unroll
        for (int k = 0; k < 32; k++) {
            float a = As[cur][k][ty];
            float4 bv = *(const float4*)&Bs[cur][k][tx * 4];
            acc[0] += a * bv.x; acc[1] += a * bv.y;
            acc[2] += a * bv.z; acc[3] += a * bv.w;
        }
        if (more) { storeA(cur ^ 1, na); storeB(cur ^ 1, nb0, nb1); cur ^= 1; }
    }

    int m = m0 + ty;
    if (m < M) {
        #pragma unroll
        for (int j = 0; j < 4; j++) {
            int n = n0 + tx * 4 + j;
            float v = alpha * acc[j];
            if (diagc != 0.f && m == n) v += diagc;
            if (bias) v += bias[n];
            if (resid) v += rescoef * resid[(size_t)bz * sR + (size_t)m * ldr + n];
            C[(size_t)m * ldc + n] = v;
        }
    }
}

// ---------------------------------------------------------------------------
// Dedicated M=1 out-projection matvec (layer 1).
// ---------------------------------------------------------------------------
__global__ __launch_bounds__(256) void matvec_out(
    const float* __restrict__ x, const float* __restrict__ W,
    const float* __restrict__ bias, const float* __restrict__ resid,
    float* __restrict__ C)
{
    __shared__ float xs[512];
    int tid = threadIdx.x;
    xs[tid] = x[tid];
    xs[tid + 256] = x[tid + 256];
    __syncthreads();
    int n = blockIdx.x * 256 + tid;
    float acc = 0.f;
    #pragma unroll 8
    for (int k = 0; k < 512; k++)
        acc += xs[k] * W[(size_t)k * 512 + n];
    C[n] = acc + bias[n] + resid[n];
}

// ---------------------------------------------------------------------------
// Fused a1 chain (layer 0), wave-owns-rows, two 16-row token groups per
// wave (block = 128 tokens): KL/ZT fragment loads feed 2x the MFMA.
// ---------------------------------------------------------------------------
__global__ __launch_bounds__(256, 2) void a1z_fused(
    const u16* __restrict__ QKVh, const u16* __restrict__ KLh,
    const u16* __restrict__ ZTh, float* __restrict__ OUT, int T0)
{
    __shared__ u16 Ps[128 * 264];

    int tid = threadIdx.x;
    int w = tid >> 6, lane = tid & 63;
    int lo = lane & 15, hi = lane >> 4;
    int koff = hi * 8;
    int hh = blockIdx.y;
    int tok0 = T0 + blockIdx.x * 128;

    int trowA = tok0 + w * 16 + lo;       if (trowA > LPAD - 1) trowA = LPAD - 1;
    int trowB = tok0 + 64 + w * 16 + lo;  if (trowB > LPAD - 1) trowB = LPAD - 1;

    const u16* qbA = QKVh + (size_t)trowA * 1536 + hh * 64 + koff;
    const u16* qbB = QKVh + (size_t)trowB * 1536 + hh * 64 + koff;
    short8 aqA0 = *(const short8*)(qbA);
    short8 aqA1 = *(const short8*)(qbA + 32);
    short8 aqB0 = *(const short8*)(qbB);
    short8 aqB1 = *(const short8*)(qbB + 32);

    floatx4 accA[16], accB[16];
    #pragma unroll
    for (int j = 0; j < 16; j++) {
        accA[j] = (floatx4){0.f, 0.f, 0.f, 0.f};
        accB[j] = (floatx4){0.f, 0.f, 0.f, 0.f};
    }

    const u16* klb = KLh + (size_t)hh * 256 * 64 + lo * 64 + koff;
    {
        short8 bk[8];
        #pragma unroll
        for (int j = 0; j < 8; j++) bk[j] = *(const short8*)(klb + (size_t)j * 1024);
        #pragma unroll
        for (int j = 0; j < 8; j++) {
            accA[j] = __builtin_amdgcn_mfma_f32_16x16x32_bf16(aqA0, bk[j], accA[j], 0, 0, 0);
            accB[j] = __builtin_amdgcn_mfma_f32_16x16x32_bf16(aqB0, bk[j], accB[j], 0, 0, 0);
        }
    }
    {
        short8 bk[8];
        #pragma unroll
        for (int j = 0; j < 8; j++) bk[j] = *(const short8*)(klb + (size_t)(8 + j) * 1024);
        #pragma unroll
        for (int j = 0; j < 8; j++) {
            accA[8 + j] = __builtin_amdgcn_mfma_f32_16x16x32_bf16(aqA0, bk[j], accA[8 + j], 0, 0, 0);
            accB[8 + j] = __builtin_amdgcn_mfma_f32_16x16x32_bf16(aqB0, bk[j], accB[8 + j], 0, 0, 0);
        }
    }
    {
        short8 bk[8];
        #pragma unroll
        for (int j = 0; j < 8; j++) bk[j] = *(const short8*)(klb + (size_t)j * 1024 + 32);
        #pragma unroll
        for (int j = 0; j < 8; j++) {
            accA[j] = __builtin_amdgcn_mfma_f32_16x16x32_bf16(aqA1, bk[j], accA[j], 0, 0, 0);
            accB[j] = __builtin_amdgcn_mfma_f32_16x16x32_bf16(aqB1, bk[j], accB[j], 0, 0, 0);
        }
    }
    {
        short8 bk[8];
        #pragma unroll
        for (int j = 0; j < 8; j++) bk[j] = *(const short8*)(klb + (size_t)(8 + j) * 1024 + 32);
        #pragma unroll
        for (int j = 0; j < 8; j++) {
            accA[8 + j] = __builtin_amdgcn_mfma_f32_16x16x32_bf16(aqA1, bk[j], accA[8 + j], 0, 0, 0);
            accB[8 + j] = __builtin_amdgcn_mfma_f32_16x16x32_bf16(aqB1, bk[j], accB[8 + j], 0, 0, 0);
        }
    }

    // ---- wave-local softmax, group A then group B (rows are wave-private)
    #pragma unroll
    for (int slot = 0; slot < 4; slot++) {
        float mx = accA[0][slot];
        #pragma unroll
        for (int j = 1; j < 16; j++) mx = fmaxf(mx, accA[j][slot]);
        mx = fmaxf(mx, __shfl_xor(mx, 1, 64));
        mx = fmaxf(mx, __shfl_xor(mx, 2, 64));
        mx = fmaxf(mx, __shfl_xor(mx, 4, 64));
        mx = fmaxf(mx, __shfl_xor(mx, 8, 64));
        float p[16];
        float s = 0.f;
        #pragma unroll
        for (int j = 0; j < 16; j++) { p[j] = __expf(accA[j][slot] - mx); s += p[j]; }
        s += __shfl_xor(s, 1, 64);
        s += __shfl_xor(s, 2, 64);
        s += __shfl_xor(s, 4, 64);
        s += __shfl_xor(s, 8, 64);
        float inv = 1.f / s;
        int row = w * 16 + hi * 4 + slot;
        #pragma unroll
        for (int j = 0; j < 16; j++)
            Ps[row * 264 + j * 16 + lo] = f2b(p[j] * inv);
    }
    #pragma unroll
    for (int slot = 0; slot < 4; slot++) {
        float mx = accB[0][slot];
        #pragma unroll
        for (int j = 1; j < 16; j++) mx = fmaxf(mx, accB[j][slot]);
        mx = fmaxf(mx, __shfl_xor(mx, 1, 64));
        mx = fmaxf(mx, __shfl_xor(mx, 2, 64));
        mx = fmaxf(mx, __shfl_xor(mx, 4, 64));
        mx = fmaxf(mx, __shfl_xor(mx, 8, 64));
        float p[16];
        float s = 0.f;
        #pragma unroll
        for (int j = 0; j < 16; j++) { p[j] = __expf(accB[j][slot] - mx); s += p[j]; }
        s += __shfl_xor(s, 1, 64);
        s += __shfl_xor(s, 2, 64);
        s += __shfl_xor(s, 4, 64);
        s += __shfl_xor(s, 8, 64);
        float inv = 1.f / s;
        int row = 64 + w * 16 + hi * 4 + slot;
        #pragma unroll
        for (int j = 0; j < 16; j++)
            Ps[row * 264 + j * 16 + lo] = f2b(p[j] * inv);
    }
    // no barrier: each wave reads back only its own rows (lgkmcnt orders it)

    // ---- PV: both row groups, ZT fragments shared
    floatx4 acc2A[4], acc2B[4];
    #pragma unroll
    for (int j = 0; j < 4; j++) {
        acc2A[j] = (floatx4){0.f, 0.f, 0.f, 0.f};
        acc2B[j] = (floatx4){0.f, 0.f, 0.f, 0.f};
    }
    const u16* ztb = ZTh + ((size_t)hh * 64 + lo) * 256 + koff;
    int prA = (w * 16 + lo) * 264;
    int prB = (64 + w * 16 + lo) * 264;
    #pragma unroll
    for (int ks = 0; ks < 8; ks += 2) {
        short8 bz[8];
        #pragma unroll
        for (int j = 0; j < 4; j++)
            bz[j] = *(const short8*)(ztb + (size_t)j * 4096 + ks * 32);
        #pragma unroll
        for (int j = 0; j < 4; j++)
            bz[4 + j] = *(const short8*)(ztb + (size_t)j * 4096 + (ks + 1) * 32);
        short8 apA0 = *(const short8*)&Ps[prA + ks * 32 + koff];
        short8 apA1 = *(const short8*)&Ps[prA + (ks + 1) * 32 + koff];
        short8 apB0 = *(const short8*)&Ps[prB + ks * 32 + koff];
        short8 apB1 = *(const short8*)&Ps[prB + (ks + 1) * 32 + koff];
        #pragma unroll
        for (int j = 0; j < 4; j++) {
            acc2A[j] = __builtin_amdgcn_mfma_f32_16x16x32_bf16(apA0, bz[j], acc2A[j], 0, 0, 0);
            acc2B[j] = __builtin_amdgcn_mfma_f32_16x16x32_bf16(apB0, bz[j], acc2B[j], 0, 0, 0);
        }
        #pragma unroll
        for (int j = 0; j < 4; j++) {
            acc2A[j] = __builtin_amdgcn_mfma_f32_16x16x32_bf16(apA1, bz[4 + j], acc2A[j], 0, 0, 0);
            acc2B[j] = __builtin_amdgcn_mfma_f32_16x16x32_bf16(apB1, bz[4 + j], acc2B[j], 0, 0, 0);
        }
    }
    #pragma unroll
    for (int j = 0; j < 4; j++) {
        #pragma unroll
        for (int slot = 0; slot < 4; slot++) {
            int tokA = tok0 + w * 16 + hi * 4 + slot;
            if (tokA < LPAD)
                OUT[(size_t)tokA * 512 + hh * 64 + j * 16 + lo] = acc2A[j][slot];
            int tokB = tokA + 64;
            if (tokB < LPAD)
                OUT[(size_t)tokB * 512 + hh * 64 + j * 16 + lo] = acc2B[j][slot];
        }
    }
}

// ---------------------------------------------------------------------------
__global__ __launch_bounds__(256) void ln_kernel(
    const float* __restrict__ X, float* __restrict__ OUT, u16* __restrict__ OUTH,
    const float* __restrict__ g, const float* __restrict__ b, int nrows)
{
    int row = blockIdx.x * 4 + (threadIdx.x >> 6);
    int lane = threadIdx.x & 63;
    if (row >= nrows) return;
    const float* xr = X + (size_t)row * 512;
    float v[8]; float s = 0.f, s2 = 0.f;
    #pragma unroll
    for (int i = 0; i < 8; i++) { float t = xr[lane + i * 64]; v[i] = t; s += t; s2 += t * t; }
    for (int o = 1; o < 64; o <<= 1) { s += __shfl_xor(s, o, 64); s2 += __shfl_xor(s2, o, 64); }
    float mu = s * (1.f / 512.f);
    float var = s2 * (1.f / 512.f) - mu * mu;
    float rs = rsqrtf(var + 1e-5f);
    float* orow = OUT + (size_t)row * 512;
    u16* hrow = OUTH + (size_t)row * 512;
    #pragma unroll
    for (int i = 0; i < 8; i++) {
        int j = lane + i * 64;
        float y = (v[i] - mu) * rs * g[j] + b[j];
        orow[j] = y;
        hrow[j] = f2b(y);
    }
}

// Landmark means from bf16 QKVh; writes fp32 and bf16 copies
__global__ __launch_bounds__(64) void landmarks_kernel(
    const u16* __restrict__ QKVh, float* __restrict__ QL, float* __restrict__ KL,
    u16* __restrict__ QLh, u16* __restrict__ KLh)
{
    int mm = blockIdx.x, hh = blockIdx.y;
    int d = threadIdx.x;
    const u16* base = QKVh + (size_t)(mm * 40) * 1536 + hh * 64 + d;
    float sq = 0.f, sk = 0.f;
    for (int li = 0; li < 40; li++) {
        sq += b2f(base[(size_t)li * 1536]);
        sk += b2f(base[(size_t)li * 1536 + 512]);
    }
    size_t o = ((size_t)hh * 256 + mm) * 64 + d;
    float q = sq * (1.f / 40.f), k = sk * (1.f / 40.f);
    QL[o] = q; KL[o] = k;
    QLh[o] = f2b(q); KLh[o] = f2b(k);
}

// a2 softmax: wave per row (256 cols), fp32 in place
__global__ __launch_bounds__(256) void softmax_a2(
    float* __restrict__ A2, int nrows)
{
    int row = blockIdx.x * 4 + (threadIdx.x >> 6);
    int lane = threadIdx.x & 63;
    if (row >= nrows) return;
    float* p = A2 + (size_t)row * 256 + lane * 4;
    float4 v = *(float4*)p;
    float mx = fmaxf(fmaxf(v.x, v.y), fmaxf(v.z, v.w));
    for (int o = 1; o < 64; o <<= 1) mx = fmaxf(mx, __shfl_xor(mx, o, 64));
    float4 e = make_float4(__expf(v.x - mx), __expf(v.y - mx),
                           __expf(v.z - mx), __expf(v.w - mx));
    float s = e.x + e.y + e.z + e.w;
    for (int o = 1; o < 64; o <<= 1) s += __shfl_xor(s, o, 64);
    float inv = 1.f / s;
    e.x *= inv; e.y *= inv; e.z *= inv; e.w *= inv;
    *(float4*)p = e;
}

// block-per-row softmax (wide rows) -> bf16 probs, single global read via
// LDS row staging, float4 loads, packed bf16 stores.
__global__ __launch_bounds__(256) void row_softmax_bf16(
    const float* __restrict__ S, u16* __restrict__ P, int ncols)
{
    __shared__ float buf[LPAD];
    __shared__ float sr[4];
    int row = blockIdx.x;
    const float* p = S + (size_t)row * ncols;
    u16* q = P + (size_t)row * ncols;
    int tid = threadIdx.x;

    float mx = -1e30f;
    for (int i = tid * 4; i < ncols; i += 1024) {
        float4 v = *(const float4*)(p + i);
        *(float4*)&buf[i] = v;
        mx = fmaxf(mx, fmaxf(fmaxf(v.x, v.y), fmaxf(v.z, v.w)));
    }
    for (int o = 1; o < 64; o <<= 1) mx = fmaxf(mx, __shfl_xor(mx, o, 64));
    if ((tid & 63) == 0) sr[tid >> 6] = mx;
    __syncthreads();
    mx = fmaxf(fmaxf(sr[0], sr[1]), fmaxf(sr[2], sr[3]));

    float s = 0.f;
    for (int i = tid * 4; i < ncols; i += 1024) {
        float4 v = *(const float4*)&buf[i];
        s += __expf(v.x - mx) + __expf(v.y - mx) + __expf(v.z - mx) + __expf(v.w - mx);
    }
    for (int o = 1; o < 64; o <<= 1) s += __shfl_xor(s, o, 64);
    __syncthreads();
    if ((tid & 63) == 0) sr[tid >> 6] = s;
    __syncthreads();
    s = sr[0] + sr[1] + sr[2] + sr[3];
    float inv = 1.f / s;

    for (int i = tid * 4; i < ncols; i += 1024) {
        float4 v = *(const float4*)&buf[i];
        ushort4 o4;
        o4.x = f2b(__expf(v.x - mx) * inv);
        o4.y = f2b(__expf(v.y - mx) * inv);
        o4.z = f2b(__expf(v.z - mx) * inv);
        o4.w = f2b(__expf(v.w - mx) * inv);
        *(ushort4*)(q + i) = o4;
    }
}

__global__ __launch_bounds__(256) void a2norms_kernel(
    const float* __restrict__ A2, float* __restrict__ scal)
{
    int hh = blockIdx.x, tid = threadIdx.x;
    const float* A = A2 + (size_t)hh * 65536;
    float rs = 0.f, cs = 0.f;
    for (int j = 0; j < 256; j++) {
        rs += fabsf(A[(size_t)tid * 256 + j]);
        cs += fabsf(A[(size_t)j * 256 + tid]);
    }
    __shared__ float sm[8];
    for (int o = 1; o < 64; o <<= 1) {
        rs = fmaxf(rs, __shfl_xor(rs, o, 64));
        cs = fmaxf(cs, __shfl_xor(cs, o, 64));
    }
    if ((tid & 63) == 0) { sm[tid >> 6] = rs; sm[4 + (tid >> 6)] = cs; }
    __syncthreads();
    if (tid == 0) {
        float rm = fmaxf(fmaxf(sm[0], sm[1]), fmaxf(sm[2], sm[3]));
        float cm = fmaxf(fmaxf(sm[4], sm[5]), fmaxf(sm[6], sm[7]));
        atomicMax((unsigned int*)&scal[0], __float_as_uint(rm));
        atomicMax((unsigned int*)&scal[1], __float_as_uint(cm));
    }
}

// z0 = a2^T / denom (fp32 only)
__global__ __launch_bounds__(256) void z0_kernel(
    const float* __restrict__ A2, const float* __restrict__ scal,
    float* __restrict__ Zf)
{
    int i = blockIdx.x, hh = blockIdx.y, j = threadIdx.x;
    float inv = 1.f / (scal[0] * scal[1]);
    Zf[((size_t)hh * 256 + i) * 256 + j] = A2[((size_t)hh * 256 + j) * 256 + i] * inv;
}

// Tiny fused a1@Z for layer 1 (single token)
__global__ __launch_bounds__(256) void a1z_single(
    const u16* __restrict__ QKVh, const float* __restrict__ KL,
    const float* __restrict__ ZM, float* __restrict__ OUT, int tok)
{
    int h = blockIdx.x, tid = threadIdx.x;
    __shared__ float q[64];
    __shared__ float p[256];
    __shared__ float red[4];
    if (tid < 64) q[tid] = b2f(QKVh[(size_t)tok * 1536 + h * 64 + tid]);
    __syncthreads();
    const float* kl = KL + ((size_t)h * 256 + tid) * 64;
    float s = 0.f;
    for (int d = 0; d < 64; d++) s += q[d] * kl[d];
    float mx = s;
    for (int o = 1; o < 64; o <<= 1) mx = fmaxf(mx, __shfl_xor(mx, o, 64));
    if ((tid & 63) == 0) red[tid >> 6] = mx;
    __syncthreads();
    mx = fmaxf(fmaxf(red[0], red[1]), fmaxf(red[2], red[3]));
    float e = __expf(s - mx);
    float sum = e;
    for (int o = 1; o < 64; o <<= 1) sum += __shfl_xor(sum, o, 64);
    __syncthreads();
    if ((tid & 63) == 0) red[tid >> 6] = sum;
    __syncthreads();
    sum = red[0] + red[1] + red[2] + red[3];
    p[tid] = e / sum;
    __syncthreads();
    if (tid < 64) {
        float a = 0.f;
        for (int j = 0; j < 256; j++) a += p[j] * ZM[((size_t)h * 256 + j) * 64 + tid];
        OUT[(size_t)tok * 512 + h * 64 + tid] = a;
    }
}

// Depthwise 33-tap token conv fused with the bf16 cast.
__global__ __launch_bounds__(256) void conv_cast(
    const u16* __restrict__ QKVh, const float* __restrict__ OUT,
    u16* __restrict__ OUTH, const float* __restrict__ resw, int T0, int ntok)
{
    __shared__ u16 Vw[48][512];
    __shared__ float ws[264];
    int tid = threadIdx.x;
    int t0 = T0 + blockIdx.x * 16;
    int wv = tid >> 6, lnn = tid & 63;
    for (int r = wv; r < 48; r += 4) {
        int ts = t0 - 16 + r;
        short8 v = (short8){0,0,0,0,0,0,0,0};
        if (ts >= 0 && ts < LPAD)
            v = *(const short8*)(QKVh + (size_t)ts * 1536 + 1024 + lnn * 8);
        *(short8*)&Vw[r][lnn * 8] = v;
    }
    if (tid < 264) ws[tid] = resw[tid];
    __syncthreads();

    int c0 = tid * 2;
    int h = c0 >> 6;
    float wreg[33];
    #pragma unroll
    for (int r = 0; r < 33; r++) wreg[r] = ws[h * 33 + r];

    #pragma unroll 1
    for (int tk = 0; tk < 16; tk++) {
        int tok = t0 + tk;
        if (tok >= T0 + ntok) break;
        float a0 = 0.f, a1 = 0.f;
        #pragma unroll
        for (int r = 0; r < 33; r++) {
            unsigned pv = *(const unsigned*)&Vw[tk + r][c0];
            a0 += wreg[r] * __uint_as_float(pv << 16);
            a1 += wreg[r] * __uint_as_float(pv & 0xFFFF0000u);
        }
        float v0 = OUT[(size_t)tok * 512 + c0]     + a0;
        float v1 = OUT[(size_t)tok * 512 + c0 + 1] + a1;
        unsigned pk = ((unsigned)f2b(v1) << 16) | (unsigned)f2b(v0);
        *(unsigned*)&OUTH[(size_t)(tok - T0) * 512 + c0] = pk;
    }
}

// Old simple conv (layer 1, single token)
__global__ __launch_bounds__(256) void conv_res(
    const u16* __restrict__ QKVh, float* __restrict__ OUT,
    const float* __restrict__ resw, int t0, int ntok)
{
    int idx = blockIdx.x * 256 + threadIdx.x;
    if (idx >= ntok * 512) return;
    int tok = t0 + (idx >> 9);
    int c = idx & 511;
    int h = c >> 6;
    const u16* vbase = QKVh + 1024 + c;
    float acc = 0.f;
    #pragma unroll 1
    for (int r = 0; r < 33; r++) {
        int ts = tok - 16 + r;
        if (ts >= 0 && ts < LPAD)
            acc += resw[h * 33 + r] * b2f(vbase[(size_t)ts * 1536]);
    }
    OUT[(size_t)tok * 512 + c] += acc;
}

// V slice of QKVh -> Vt[h][d][t] (bf16)
__global__ __launch_bounds__(256) void vtrans(
    const u16* __restrict__ QKVh, u16* __restrict__ Vt)
{
    int t0 = blockIdx.x * 64, hh = blockIdx.y;
    __shared__ u16 tile[64][65];
    #pragma unroll
    for (int ii = 0; ii < 16; ii++) {
        int idx = threadIdx.x + ii * 256;
        int t = idx >> 6, d = idx & 63;
        tile[t][d] = QKVh[(size_t)(t0 + t) * 1536 + 1024 + hh * 64 + d];
    }
    __syncthreads();
    #pragma unroll
    for (int ii = 0; ii < 16; ii++) {
        int idx = threadIdx.x + ii * 256;
        int d = idx >> 6, t = idx & 63;
        Vt[((size_t)hh * 64 + d) * LPAD + t0 + t] = tile[t][d];
    }
}

// Combine PPEG weights: W49[tap][c] = w7 + w5(in range) + w3(in range)
__global__ void ppeg_combine(
    const float* __restrict__ w7, const float* __restrict__ w5,
    const float* __restrict__ w3, const float* __restrict__ b7,
    const float* __restrict__ b5, const float* __restrict__ b3,
    float* __restrict__ W49, float* __restrict__ BSUM)
{
    int idx = blockIdx.x * 256 + threadIdx.x;
    if (idx >= 49 * 512) return;
    int tap = idx >> 9, c = idx & 511;
    int dy = tap / 7 - 3, dx = tap % 7 - 3;
    float v = w7[c * 49 + tap];
    if (dy >= -2 && dy <= 2 && dx >= -2 && dx <= 2)
        v += w5[c * 25 + (dy + 2) * 5 + (dx + 2)];
    if (dy >= -1 && dy <= 1 && dx >= -1 && dx <= 1)
        v += w3[c * 9 + (dy + 1) * 3 + (dx + 1)];
    W49[tap * 512 + c] = v;
    if (tap == 0) BSUM[c] = b7[c] + b5[c] + b3[c];
}

// PPEG, tiled: block = 16x4 position tile x 64 channels, fully-unrolled
// float4 halo staging.
__global__ __launch_bounds__(256) void ppeg_tile(
    const float* __restrict__ S, float* __restrict__ O,
    const float* __restrict__ W49, const float* __restrict__ BSUM)
{
    __shared__ float Sw[10][22][64];
    int tid = threadIdx.x;
    int c = tid & 63;
    int sub = tid >> 6;
    int x0 = blockIdx.x * 16;
    int y0 = blockIdx.y * 4;
    int cg = blockIdx.z * 64;

    {
        int p = tid >> 4;
        int c4 = (tid & 15) * 4;
        #pragma unroll
        for (int i = 0; i < 14; i++) {
            int f = p + i * 16;
            if (f < 220) {
                int r = f / 22, xx = f - r * 22;
                int gy = y0 - 3 + r;
                int gx = x0 - 3 + xx;
                float4 v = make_float4(0.f, 0.f, 0.f, 0.f);
                if ((unsigned)gy < 100u && (unsigned)gx < 100u)
                    v = *(const float4*)(S + (size_t)(1 + gy * 100 + gx) * 512 + cg + c4);
                *(float4*)&Sw[r][xx][c4] = v;
            }
        }
    }
    float wreg[49];
    #pragma unroll
    for (int t = 0; t < 49; t++) wreg[t] = W49[t * 512 + cg + c];
    float bsum = BSUM[cg + c];
    __syncthreads();

    int xb = sub * 4;
    float acc[4][4];
    #pragma unroll
    for (int yy = 0; yy < 4; yy++)
        #pragma unroll
        for (int xq = 0; xq < 4; xq++)
            acc[yy][xq] = Sw[yy + 3][xb + xq + 3][c] + bsum;

    #pragma unroll
    for (int r = 0; r < 10; r++) {
        float v[10];
        #pragma unroll
        for (int j = 0; j < 10; j++) v[j] = Sw[r][xb + j][c];
        #pragma unroll
        for (int yy = 0; yy < 4; yy++) {
            int t = r - yy;
            if (t < 0 || t > 6) continue;
            #pragma unroll
            for (int dxt = 0; dxt < 7; dxt++) {
                float w = wreg[t * 7 + dxt];
                #pragma unroll
                for (int xq = 0; xq < 4; xq++)
                    acc[yy][xq] += v[xq + dxt] * w;
            }
        }
    }

    #pragma unroll
    for (int yy = 0; yy < 4; yy++) {
        int gy = y0 + yy;
        #pragma unroll
        for (int xq = 0; xq < 4; xq++) {
            int gx = x0 + xb + xq;
            if (gx < 100)
                O[(size_t)(1 + gy * 100 + gx) * 512 + cg + c] = acc[yy][xq];
        }
    }
}

__global__ __launch_bounds__(64) void final_kernel(
    const float* __restrict__ S, const float* __restrict__ g, const float* __restrict__ b,
    const float* __restrict__ w, const float* __restrict__ bb, float* __restrict__ out)
{
    int lane = threadIdx.x;
    float v[8]; float s = 0.f, s2 = 0.f;
    #pragma unroll
    for (int i = 0; i < 8; i++) { float t = S[lane + i * 64]; v[i] = t; s += t; s2 += t * t; }
    for (int o = 1; o < 64; o <<= 1) { s += __shfl_xor(s, o, 64); s2 += __shfl_xor(s2, o, 64); }
    float mu = s * (1.f / 512.f);
    float var = s2 * (1.f / 512.f) - mu * mu;
    float rs = rsqrtf(var + 1e-5f);
    float o0 = 0.f, o1 = 0.f;
    #pragma unroll
    for (int i = 0; i < 8; i++) {
        int j = lane + i * 64;
        float xn = (v[i] - mu) * rs * g[j] + b[j];
        o0 += xn * w[j * 2 + 0];
        o1 += xn * w[j * 2 + 1];
    }
    for (int o = 1; o < 64; o <<= 1) { o0 += __shfl_xor(o0, o, 64); o1 += __shfl_xor(o1, o, 64); }
    if (lane == 0) { out[0] = o0 + bb[0]; out[1] = o1 + bb[1]; }
}

__global__ void zerok(float* p, int n)
{
    int i = blockIdx.x * 256 + threadIdx.x;
    if (i < n) p[i] = 0.f;
}
__global__ void zero2k(float* p) { p[0] = 0.f; p[1] = 0.f; }
__global__ void copy512(float* dst, const float* src)
{
    int i = blockIdx.x * 256 + threadIdx.x;
    if (i < 512) dst[i] = src[i];
}
__global__ void cast_bf16(const float* __restrict__ src, u16* __restrict__ dst, int n)
{
    int i = (blockIdx.x * 256 + threadIdx.x) * 4;
    if (i >= n) return;
    float4 v = *(const float4*)(src + i);
    dst[i + 0] = f2b(v.x); dst[i + 1] = f2b(v.y);
    dst[i + 2] = f2b(v.z); dst[i + 3] = f2b(v.w);
}
// dst[b][c][r] = src[b][r][c]  (cast-transpose fp32 RxC -> bf16 CxR)
__global__ void castT(const float* __restrict__ src, u16* __restrict__ dst,
                      int R, int C, int nb)
{
    size_t idx = (size_t)blockIdx.x * 256 + threadIdx.x;
    size_t tot = (size_t)R * C * nb;
    if (idx >= tot) return;
    int rc = R * C;
    int b = (int)(idx / rc);
    int rem = (int)(idx - (size_t)b * rc);
    int c = rem / R, r = rem - c * R;
    dst[idx] = f2b(src[(size_t)b * rc + (size_t)r * C + c]);
}

// ---------------------------------------------------------------------------
extern "C" void kernel_launch(void* const* d_in, const int* in_sizes, int n_in,
                              void* d_out, int out_size, void* d_ws, size_t ws_size,
                              hipStream_t stream)
{
    const float* h     = (const float*)d_in[0];
    const float* fc1_w = (const float*)d_in[1];
    const float* fc1_b = (const float*)d_in[2];
    const float* cls   = (const float*)d_in[3];
    bool sigorder = (in_sizes[10] == 512 * 49);
    int i_l2 = sigorder ? 16 : 10;
    int i_pp = sigorder ? 10 : 16;
    const float* l_g[2]   = { (const float*)d_in[4], (const float*)d_in[i_l2 + 0] };
    const float* l_b[2]   = { (const float*)d_in[5], (const float*)d_in[i_l2 + 1] };
    const float* l_qkv[2] = { (const float*)d_in[6], (const float*)d_in[i_l2 + 2] };
    const float* l_ow[2]  = { (const float*)d_in[7], (const float*)d_in[i_l2 + 3] };
    const float* l_ob[2]  = { (const float*)d_in[8], (const float*)d_in[i_l2 + 4] };
    const float* l_rw[2]  = { (const float*)d_in[9], (const float*)d_in[i_l2 + 5] };
    const float* w7 = (const float*)d_in[i_pp + 0];
    const float* b7 = (const float*)d_in[i_pp + 1];
    const float* w5 = (const float*)d_in[i_pp + 2];
    const float* b5 = (const float*)d_in[i_pp + 3];
    const float* w3 = (const float*)d_in[i_pp + 4];
    const float* b3 = (const float*)d_in[i_pp + 5];
    const float* ng   = (const float*)d_in[22];
    const float* nbv  = (const float*)d_in[23];
    const float* fc2w = (const float*)d_in[24];
    const float* fc2b = (const float*)d_in[25];
    float* out = (float*)d_out;

    char* Wb = (char*)d_ws;
    size_t off = 0;
    auto allocB = [&](size_t bytes) { void* p = Wb + off; off = (off + bytes + 255) & ~(size_t)255; return p; };

    float* SEQ   = (float*)allocB((size_t)NSEQ * 512 * 4);
    float* XP    = (float*)allocB((size_t)LPAD * 512 * 4);
    u16*   XPh   = (u16*)  allocB((size_t)LPAD * 512 * 2);
    u16*   QKVh  = (u16*)  allocB((size_t)LPAD * 1536 * 2);
    float* QLKL  = (float*)allocB((size_t)262144 * 4);
    float* QL = QLKL, *KL = QLKL + 131072;
    u16*   QLKLh = (u16*)  allocB((size_t)262144 * 2);
    u16*   QLh = QLKLh, *KLh = QLKLh + 131072;
    float* A2   = (float*)allocB(524288 * 4);
    float* Zf0  = (float*)allocB(524288 * 4);
    float* Zf1  = (float*)allocB(524288 * 4);
    float* XZf  = (float*)allocB(524288 * 4);
    float* W2b  = (float*)allocB(524288 * 4);
    float* W3b  = (float*)allocB(524288 * 4);
    float* A3V  = (float*)allocB(131072 * 4);
    float* ZMATf= (float*)allocB(131072 * 4);
    u16*   ZMATt= (u16*)  allocB(131072 * 2);
    u16*   Vt   = (u16*)  allocB((size_t)8 * 64 * LPAD * 2);
    u16*   fc1wt= (u16*)  allocB(524288 * 2);
    u16*   qkvwt= (u16*)  allocB(786432 * 2);
    u16*   outwt= (u16*)  allocB(262144 * 2);
    float* W49  = (float*)allocB(49 * 512 * 4);
    float* BSUM = (float*)allocB(512 * 4);
    float* SCAL = (float*)allocB(16);
    void*  U1   = allocB((size_t)LPAD * 512 * 4);
    u16*   hbf  = (u16*)U1;
    float* OUT  = (float*)U1;
    float* SEQ2 = OUT;
    size_t fixed = off;

    size_t scB_b = (size_t)8 * 256 * LPAD * 4;
    size_t phB_b = (size_t)8 * 256 * LPAD * 2;
    bool batched = ws_size >= fixed + scB_b + phB_b;
    float* SC; u16* Ph;
    if (batched) {
        SC = (float*)(Wb + fixed);
        Ph = (u16*)(Wb + fixed + scB_b);
    } else {
        SC = (float*)(Wb + fixed);
        Ph = (u16*)(Wb + fixed + (size_t)256 * LPAD * 4);
    }
    u16* OUTh = (u16*)SC;   // alias: SC dead when OUTh materialized

    auto mgemm = [&](const u16* A, int lda, long sA, const u16* Bt, int ldb, long sB,
                     void* C, int ldc, long sC, int M, int N, int K,
                     const float* bias, const float* resid, int ldr,
                     int relu, int qscale, int obf16, int nbatch, int ksplit, int atomic) {
        dim3 grid((N + 127) / 128, (M + 63) / 64, nbatch * ksplit);
        gemm_mfma<<<grid, 256, 0, stream>>>(A, lda, sA, Bt, ldb, sB, C, ldc, sC,
            M, N, K, ksplit, bias, resid, ldr, relu, qscale, obf16, atomic);
    };
    auto fgemm = [&](const float* A, int lda, long sA, const float* B, int ldb, long sB,
                     float* C, int ldc, long sC, int M, int N, int K,
                     float alpha, float diagc, const float* bias,
                     const float* resid, int ldr, long sR, float rescoef,
                     int btrans, int nbatch) {
        dim3 grid(N / 64, (M + 15) / 16, nbatch);
        gemm_big<<<grid, 256, 0, stream>>>(A, lda, sA, B, ldb, sB, C, ldc, sC, M, N, K,
            alpha, diagc, bias, resid, ldr, sR, rescoef, btrans);
    };

    // ---- prologue
    cast_bf16<<<(NPIX * 1024 / 4 + 255) / 256, 256, 0, stream>>>(h, hbf, NPIX * 1024);
    castT<<<(524288 + 255) / 256, 256, 0, stream>>>(fc1_w, fc1wt, 1024, 512, 1);
    mgemm(hbf, 1024, 0, fc1wt, 1024, 0, SEQ + 512, 512, 0, NPIX, 512, 1024,
          fc1_b, nullptr, 0, 1, 0, 0, 1, 1, 0);
    copy512<<<2, 256, 0, stream>>>(SEQ, cls);
    zerok<<<(PADT * 512 + 255) / 256, 256, 0, stream>>>(XP, PADT * 512);
    zerok<<<(PADT * 256 + 255) / 256, 256, 0, stream>>>((float*)XPh, PADT * 256);
    ppeg_combine<<<(49 * 512 + 255) / 256, 256, 0, stream>>>(w7, w5, w3, b7, b5, b3, W49, BSUM);

    for (int layer = 0; layer < 2; layer++) {
        const float* curSEQ = (layer == 0) ? SEQ : SEQ2;
        ln_kernel<<<(NSEQ + 3) / 4, 256, 0, stream>>>(curSEQ, XP + (size_t)PADT * 512,
            XPh + (size_t)PADT * 512, l_g[layer], l_b[layer], NSEQ);
        castT<<<(786432 + 255) / 256, 256, 0, stream>>>(l_qkv[layer], qkvwt, 512, 1536, 1);
        mgemm(XPh, 512, 0, qkvwt, 512, 0, QKVh, 1536, 0, LPAD, 1536, 512,
              nullptr, nullptr, 0, 0, 1, 1, 1, 1, 0);
        landmarks_kernel<<<dim3(256, 8), 64, 0, stream>>>(QKVh, QL, KL, QLh, KLh);
        // a2 = softmax(ql @ kl^T)  (fp32)
        fgemm(QL, 64, 16384, KL, 64, 16384, A2, 256, 65536, 256, 256, 64,
              1.f, 0.f, nullptr, nullptr, 0, 0, 0.f, 1, 8);
        softmax_a2<<<512, 256, 0, stream>>>(A2, 2048);
        zero2k<<<1, 1, 0, stream>>>(SCAL);
        a2norms_kernel<<<8, 256, 0, stream>>>(A2, SCAL);
        z0_kernel<<<dim3(256, 8), 256, 0, stream>>>(A2, SCAL, Zf0);

        // Newton-Schulz: 6 fp32 iterations
        float* zc = Zf0; float* zn = Zf1;
        for (int it = 0; it < 6; it++) {
            fgemm(A2, 256, 65536, zc, 256, 65536, XZf, 256, 65536, 256, 256, 256,
                  1.f, 0.f, nullptr, nullptr, 0, 0, 0.f, 0, 8);
            fgemm(XZf, 256, 65536, XZf, 256, 65536, W2b, 256, 65536, 256, 256, 256,
                  1.f, 15.f, nullptr, XZf, 256, 65536, -7.f, 0, 8);
            fgemm(XZf, 256, 65536, W2b, 256, 65536, W3b, 256, 65536, 256, 256, 256,
                  -1.f, 13.f, nullptr, nullptr, 0, 0, 0.f, 0, 8);
            fgemm(zc, 256, 65536, W3b, 256, 65536, zn, 256, 65536, 256, 256, 256,
                  0.25f, 0.f, nullptr, nullptr, 0, 0, 0.f, 0, 8);
            float* t = zc; zc = zn; zn = t;
        }
        float* zfin = zc;

        // a3v = softmax(ql @ k^T) @ v  via MFMA
        vtrans<<<dim3(160, 8), 256, 0, stream>>>(QKVh, Vt);
        zerok<<<512, 256, 0, stream>>>(A3V, 131072);
        if (batched) {
            mgemm(QLh, 64, 16384, QKVh + 512, 1536, 64, SC, LPAD, (long)256 * LPAD,
                  256, LPAD, 64, nullptr, nullptr, 0, 0, 0, 0, 8, 1, 0);
            row_softmax_bf16<<<2048, 256, 0, stream>>>(SC, Ph, LPAD);
            mgemm(Ph, LPAD, (long)256 * LPAD, Vt, LPAD, (long)64 * LPAD, A3V, 64, 16384,
                  256, 64, LPAD, nullptr, nullptr, 0, 0, 0, 0, 8, 40, 1);
        } else {
            for (int hh = 0; hh < 8; hh++) {
                mgemm(QLh + (size_t)hh * 16384, 64, 0, QKVh + 512 + hh * 64, 1536, 0,
                      SC, LPAD, 0, 256, LPAD, 64, nullptr, nullptr, 0, 0, 0, 0, 1, 1, 0);
                row_softmax_bf16<<<256, 256, 0, stream>>>(SC, Ph, LPAD);
                mgemm(Ph, LPAD, 0, Vt + (size_t)hh * 64 * LPAD, LPAD, 0,
                      A3V + (size_t)hh * 16384, 64, 0, 256, 64, LPAD,
                      nullptr, nullptr, 0, 0, 0, 0, 1, 40, 1);
            }
        }
        // ZMAT = pinv(a2) @ a3v  (fp32)
        fgemm(zfin, 256, 65536, A3V, 64, 16384, ZMATf, 64, 16384, 256, 64, 256,
              1.f, 0.f, nullptr, nullptr, 0, 0, 0.f, 0, 8);

        if (layer == 0) {
            // Z^T bf16 for the fused a1 chain
            castT<<<(131072 + 255) / 256, 256, 0, stream>>>(ZMATf, ZMATt, 256, 64, 8);
            // fused scores+softmax+PZ: one launch, 128 tokens/block
            a1z_fused<<<dim3((NSEQ + 127) / 128, 8), 256, 0, stream>>>(
                QKVh, KLh, ZMATt, OUT, PADT);
            // conv + bf16 cast fused (writes OUTh directly)
            conv_cast<<<(NSEQ + 15) / 16, 256, 0, stream>>>(
                QKVh, OUT, OUTh, l_rw[0], PADT, NSEQ);
            castT<<<(262144 + 255) / 256, 256, 0, stream>>>(l_ow[0], outwt, 512, 512, 1);
            mgemm(OUTh, 512, 0, outwt, 512, 0, SEQ, 512, 0, NSEQ, 512, 512,
                  l_ob[0], XP + (size_t)PADT * 512, 512, 0, 0, 0, 1, 1, 0);
            // PPEG (tiled, unrolled float4 staging)
            ppeg_tile<<<dim3(7, 25, 8), 256, 0, stream>>>(SEQ, SEQ2, W49, BSUM);
            copy512<<<2, 256, 0, stream>>>(SEQ2, SEQ);
        } else {
            a1z_single<<<8, 256, 0, stream>>>(QKVh, KL, ZMATf, OUT, PADT);
            conv_res<<<2, 256, 0, stream>>>(QKVh, OUT, l_rw[1], PADT, 1);
            // dedicated M=1 out-projection matvec
            matvec_out<<<2, 256, 0, stream>>>(OUT + (size_t)PADT * 512, l_ow[1],
                                              l_ob[1], XP + (size_t)PADT * 512, SEQ);
        }
    }
    final_kernel<<<1, 64, 0, stream>>>(SEQ, ng, nbv, fc2w, fc2b, out);
    (void)n_in; (void)out_size;
}

// Round 15
// 1375.005 us; speedup vs baseline: 1.4742x; 1.0048x over previous
//
#include <hip/hip_runtime.h>
#include <math.h>

#define LPAD  10240
#define NSEQ  10001
#define PADT  239
#define NPIX  10000

typedef unsigned short u16;
typedef __attribute__((ext_vector_type(8))) short short8;
typedef __attribute__((ext_vector_type(4))) float floatx4;

__device__ __forceinline__ float b2f(u16 u){ return __uint_as_float(((unsigned)u)<<16); }
__device__ __forceinline__ u16 f2b(float f){
    unsigned x = __float_as_uint(f);
    return (u16)((x + 0x7FFFu + ((x>>16)&1u)) >> 16);
}
__device__ __forceinline__ void gld16(const void* g, void* l){
    __builtin_amdgcn_global_load_lds(
        (const __attribute__((address_space(1))) unsigned int*)g,
        (__attribute__((address_space(3))) unsigned int*)l, 16, 0, 0);
}

// ---------------------------------------------------------------------------
// bf16 MFMA GEMM: C = A @ Bt^T (+bias)(+resid)(relu)(qscale). 64x128 tile,
// 4 waves, dbuf LDS, global_load_lds width-16 staging, k-slot XOR bank
// swizzle (round-8 config — best measured).
// ---------------------------------------------------------------------------
__global__ __launch_bounds__(256) void gemm_mfma(
    const u16* __restrict__ A, int lda, long sA,
    const u16* __restrict__ Bt, int ldb, long sB,
    void* __restrict__ Cv, int ldc, long sC,
    int M, int N, int K, int ksplit,
    const float* __restrict__ bias,
    const float* __restrict__ resid, int ldr,
    int relu, int qscale, int obf16, int atomic)
{
    __shared__ u16 As[2][64*32];
    __shared__ u16 Bs[2][128*32];

    int bz = blockIdx.z / ksplit;
    int ks = blockIdx.z - bz * ksplit;
    A  += (size_t)bz * sA;
    Bt += (size_t)bz * sB;

    int kchunk = (K + ksplit - 1) / ksplit;
    kchunk = (kchunk + 31) & ~31;
    int kbeg = ks * kchunk;
    int kend = kbeg + kchunk; if (kend > K) kend = K;

    int tid = threadIdx.x;
    int w = tid >> 6, lane = tid & 63;
    int wm = (w >> 1) * 32, wn = (w & 1) * 64;
    int m0 = blockIdx.y * 64, n0 = blockIdx.x * 128;

    int l4 = lane >> 2;
    int lk = (((lane & 3) ^ (l4 & 3)) * 8);
    int ra = w * 16 + l4;
    int rb = w * 32 + l4;
    int am0 = m0 + ra;      if (am0 > M-1) am0 = M-1;
    int bn0 = n0 + rb;      if (bn0 > N-1) bn0 = N-1;
    int bn1 = n0 + rb + 16; if (bn1 > N-1) bn1 = N-1;
    const u16* ag0 = A  + (size_t)am0 * lda + lk;
    const u16* bg0 = Bt + (size_t)bn0 * ldb + lk;
    const u16* bg1 = Bt + (size_t)bn1 * ldb + lk;
    int soA  = w * 512;
    int soB0 = w * 1024;
    int soB1 = w * 1024 + 512;

    floatx4 acc[2][4];
    #pragma unroll
    for (int i = 0; i < 2; i++)
        #pragma unroll
        for (int j = 0; j < 4; j++)
            acc[i][j] = (floatx4){0.f, 0.f, 0.f, 0.f};

    int arow = wm + (lane & 15);
    int nrow = wn + (lane & 15);
    int koff = (((lane >> 4) ^ (lane & 3)) * 8);

    if (kbeg < kend) {
        gld16(ag0 + kbeg, &As[0][soA]);
        gld16(bg0 + kbeg, &Bs[0][soB0]);
        gld16(bg1 + kbeg, &Bs[0][soB1]);
    }
    __syncthreads();

    int cb = 0;
    for (int k0 = kbeg; k0 < kend; k0 += 32) {
        int kn = k0 + 32;
        if (kn < kend) {
            gld16(ag0 + kn, &As[cb ^ 1][soA]);
            gld16(bg0 + kn, &Bs[cb ^ 1][soB0]);
            gld16(bg1 + kn, &Bs[cb ^ 1][soB1]);
        }
        short8 af[2], bf[4];
        #pragma unroll
        for (int i = 0; i < 2; i++) af[i] = *(const short8*)&As[cb][(arow + i*16)*32 + koff];
        #pragma unroll
        for (int j = 0; j < 4; j++) bf[j] = *(const short8*)&Bs[cb][(nrow + j*16)*32 + koff];
        #pragma unroll
        for (int i = 0; i < 2; i++)
            #pragma unroll
            for (int j = 0; j < 4; j++)
                acc[i][j] = __builtin_amdgcn_mfma_f32_16x16x32_bf16(af[i], bf[j], acc[i][j], 0, 0, 0);
        __syncthreads();
        cb ^= 1;
    }

    float* Cf = (float*)Cv;
    u16*   Ch = (u16*)Cv;
    size_t cb2 = (size_t)bz * sC;
    int rbase = m0 + wm + (lane >> 4) * 4;
    int cbase = n0 + wn + (lane & 15);
    #pragma unroll
    for (int i = 0; i < 2; i++) {
        #pragma unroll
        for (int j = 0; j < 4; j++) {
            int col = cbase + j * 16;
            if (col >= N) continue;
            float bcol = bias ? bias[col] : 0.f;
            #pragma unroll
            for (int r = 0; r < 4; r++) {
                int row = rbase + i * 16 + r;
                if (row >= M) continue;
                float v = acc[i][j][r];
                if (qscale && col < 512) v *= 0.125f;
                v += bcol;
                if (resid) v += resid[(size_t)row * ldr + col];
                if (relu) v = fmaxf(v, 0.f);
                size_t ci = cb2 + (size_t)row * ldc + col;
                if (obf16) Ch[ci] = f2b(v);
                else if (atomic) atomicAdd(&Cf[ci], v);
                else Cf[ci] = v;
            }
        }
    }
}

// ---------------------------------------------------------------------------
// fp32 tiled GEMM (Newton-Schulz chain + tiny gemms).
// C = alpha*A@B + diagc*I + bias + rescoef*resid.
// 16x64 tile, 256 threads (1x4 per thread), double-buffered LDS staging.
// Round-14: BK=64 (was 32) — halves the K-step/barrier count again (8->4
// for K=256 NS gemms, 2->1 for K=64). LDS 43 KB -> 3 blocks/CU capacity;
// grid is 512 blocks = 2/CU so resident parallelism UNCHANGED (unlike the
// round-9 gemm_mfma BK=64 failure which cut residency). A-staging now uses
// all 256 threads (1 float4 each). Per-output accumulation remains strictly
// k-ascending -> bit-identical numerics. K call-sites in {64,256}.
// ---------------------------------------------------------------------------
__global__ __launch_bounds__(256) void gemm_big(
    const float* __restrict__ A, int lda, long sA,
    const float* __restrict__ B, int ldb, long sB,
    float* __restrict__ C, int ldc, long sC,
    int M, int N, int K,
    float alpha, float diagc,
    const float* __restrict__ bias,
    const float* __restrict__ resid, int ldr, long sR, float rescoef,
    int btrans)
{
    __shared__ float As[2][64][20];
    __shared__ float Bs[2][64][64];

    int bz = blockIdx.z;
    A += (size_t)bz * sA;
    B += (size_t)bz * sB;
    C += (size_t)bz * sC;

    int tid = threadIdx.x;
    int tx = tid & 15, ty = tid >> 4;
    int m0 = blockIdx.y * 16, n0 = blockIdx.x * 64;

    // A staging (all 256 threads): row ar (0..15), k-quad ak (0..60)
    int ar = tid >> 4;
    int ak = (tid & 15) * 4;
    // B staging (!btrans): k-rows bkr, +16, +32, +48; col-quad bc4
    int bkr = tid >> 4;
    int bc4 = (tid & 15) * 4;
    // B staging (btrans): col bc (0..63), k-base bkq (0,16,32,48)
    int bc  = tid >> 2;
    int bkq = (tid & 3) * 16;

    auto loadA = [&](int k0, float4& ra) {
        int m = m0 + ar;
        ra = make_float4(0.f, 0.f, 0.f, 0.f);
        if (m < M) ra = *(const float4*)(A + (size_t)m * lda + k0 + ak);
    };
    auto loadB = [&](int k0, float4 rb[4]) {
        if (!btrans) {
            #pragma unroll
            for (int i = 0; i < 4; i++)
                rb[i] = *(const float4*)(B + (size_t)(k0 + bkr + i * 16) * ldb + n0 + bc4);
        } else {
            const float* bp = B + (size_t)(n0 + bc) * ldb + k0 + bkq;
            #pragma unroll
            for (int i = 0; i < 4; i++)
                rb[i] = *(const float4*)(bp + i * 4);
        }
    };
    auto storeA = [&](int buf, const float4& ra) {
        As[buf][ak + 0][ar] = ra.x; As[buf][ak + 1][ar] = ra.y;
        As[buf][ak + 2][ar] = ra.z; As[buf][ak + 3][ar] = ra.w;
    };
    auto storeB = [&](int buf, const float4 rb[4]) {
        if (!btrans) {
            #pragma unroll
            for (int i = 0; i < 4; i++)
                *(float4*)&Bs[buf][bkr + i * 16][bc4] = rb[i];
        } else {
            #pragma unroll
            for (int i = 0; i < 4; i++) {
                Bs[buf][bkq + i * 4 + 0][bc] = rb[i].x;
                Bs[buf][bkq + i * 4 + 1][bc] = rb[i].y;
                Bs[buf][bkq + i * 4 + 2][bc] = rb[i].z;
                Bs[buf][bkq + i * 4 + 3][bc] = rb[i].w;
            }
        }
    };

    float acc[4];
    #pragma unroll
    for (int j = 0; j < 4; j++) acc[j] = 0.f;

    float4 pa, pb[4];
    loadA(0, pa); loadB(0, pb);
    storeA(0, pa); storeB(0, pb);
    int cur = 0;

    for (int k0 = 0; k0 < K; k0 += 64) {
        bool more = (k0 + 64) < K;
        float4 na, nb[4];
        if (more) { loadA(k0 + 64, na); loadB(k0 + 64, nb); }
        __syncthreads();
        #pragma unroll
        for (int k = 0; k < 64; k++) {
            float a = As[cur][k][ty];
            float4 bv = *(const float4*)&Bs[cur][k][tx * 4];
            acc[0] += a * bv.x; acc[1] += a * bv.y;
            acc[2] += a * bv.z; acc[3] += a * bv.w;
        }
        if (more) { storeA(cur ^ 1, na); storeB(cur ^ 1, nb); cur ^= 1; }
    }

    int m = m0 + ty;
    if (m < M) {
        #pragma unroll
        for (int j = 0; j < 4; j++) {
            int n = n0 + tx * 4 + j;
            float v = alpha * acc[j];
            if (diagc != 0.f && m == n) v += diagc;
            if (bias) v += bias[n];
            if (resid) v += rescoef * resid[(size_t)bz * sR + (size_t)m * ldr + n];
            C[(size_t)m * ldc + n] = v;
        }
    }
}

// ---------------------------------------------------------------------------
// Dedicated M=1 out-projection matvec (layer 1).
// ---------------------------------------------------------------------------
__global__ __launch_bounds__(256) void matvec_out(
    const float* __restrict__ x, const float* __restrict__ W,
    const float* __restrict__ bias, const float* __restrict__ resid,
    float* __restrict__ C)
{
    __shared__ float xs[512];
    int tid = threadIdx.x;
    xs[tid] = x[tid];
    xs[tid + 256] = x[tid + 256];
    __syncthreads();
    int n = blockIdx.x * 256 + tid;
    float acc = 0.f;
    #pragma unroll 8
    for (int k = 0; k < 512; k++)
        acc += xs[k] * W[(size_t)k * 512 + n];
    C[n] = acc + bias[n] + resid[n];
}

// ---------------------------------------------------------------------------
// Fused a1 chain (layer 0), wave-owns-rows, two 16-row token groups per
// wave (block = 128 tokens): KL/ZT fragment loads feed 2x the MFMA.
// ---------------------------------------------------------------------------
__global__ __launch_bounds__(256, 2) void a1z_fused(
    const u16* __restrict__ QKVh, const u16* __restrict__ KLh,
    const u16* __restrict__ ZTh, float* __restrict__ OUT, int T0)
{
    __shared__ u16 Ps[128 * 264];

    int tid = threadIdx.x;
    int w = tid >> 6, lane = tid & 63;
    int lo = lane & 15, hi = lane >> 4;
    int koff = hi * 8;
    int hh = blockIdx.y;
    int tok0 = T0 + blockIdx.x * 128;

    int trowA = tok0 + w * 16 + lo;       if (trowA > LPAD - 1) trowA = LPAD - 1;
    int trowB = tok0 + 64 + w * 16 + lo;  if (trowB > LPAD - 1) trowB = LPAD - 1;

    const u16* qbA = QKVh + (size_t)trowA * 1536 + hh * 64 + koff;
    const u16* qbB = QKVh + (size_t)trowB * 1536 + hh * 64 + koff;
    short8 aqA0 = *(const short8*)(qbA);
    short8 aqA1 = *(const short8*)(qbA + 32);
    short8 aqB0 = *(const short8*)(qbB);
    short8 aqB1 = *(const short8*)(qbB + 32);

    floatx4 accA[16], accB[16];
    #pragma unroll
    for (int j = 0; j < 16; j++) {
        accA[j] = (floatx4){0.f, 0.f, 0.f, 0.f};
        accB[j] = (floatx4){0.f, 0.f, 0.f, 0.f};
    }

    const u16* klb = KLh + (size_t)hh * 256 * 64 + lo * 64 + koff;
    {
        short8 bk[8];
        #pragma unroll
        for (int j = 0; j < 8; j++) bk[j] = *(const short8*)(klb + (size_t)j * 1024);
        #pragma unroll
        for (int j = 0; j < 8; j++) {
            accA[j] = __builtin_amdgcn_mfma_f32_16x16x32_bf16(aqA0, bk[j], accA[j], 0, 0, 0);
            accB[j] = __builtin_amdgcn_mfma_f32_16x16x32_bf16(aqB0, bk[j], accB[j], 0, 0, 0);
        }
    }
    {
        short8 bk[8];
        #pragma unroll
        for (int j = 0; j < 8; j++) bk[j] = *(const short8*)(klb + (size_t)(8 + j) * 1024);
        #pragma unroll
        for (int j = 0; j < 8; j++) {
            accA[8 + j] = __builtin_amdgcn_mfma_f32_16x16x32_bf16(aqA0, bk[j], accA[8 + j], 0, 0, 0);
            accB[8 + j] = __builtin_amdgcn_mfma_f32_16x16x32_bf16(aqB0, bk[j], accB[8 + j], 0, 0, 0);
        }
    }
    {
        short8 bk[8];
        #pragma unroll
        for (int j = 0; j < 8; j++) bk[j] = *(const short8*)(klb + (size_t)j * 1024 + 32);
        #pragma unroll
        for (int j = 0; j < 8; j++) {
            accA[j] = __builtin_amdgcn_mfma_f32_16x16x32_bf16(aqA1, bk[j], accA[j], 0, 0, 0);
            accB[j] = __builtin_amdgcn_mfma_f32_16x16x32_bf16(aqB1, bk[j], accB[j], 0, 0, 0);
        }
    }
    {
        short8 bk[8];
        #pragma unroll
        for (int j = 0; j < 8; j++) bk[j] = *(const short8*)(klb + (size_t)(8 + j) * 1024 + 32);
        #pragma unroll
        for (int j = 0; j < 8; j++) {
            accA[8 + j] = __builtin_amdgcn_mfma_f32_16x16x32_bf16(aqA1, bk[j], accA[8 + j], 0, 0, 0);
            accB[8 + j] = __builtin_amdgcn_mfma_f32_16x16x32_bf16(aqB1, bk[j], accB[8 + j], 0, 0, 0);
        }
    }

    // ---- wave-local softmax, group A then group B (rows are wave-private)
    #pragma unroll
    for (int slot = 0; slot < 4; slot++) {
        float mx = accA[0][slot];
        #pragma unroll
        for (int j = 1; j < 16; j++) mx = fmaxf(mx, accA[j][slot]);
        mx = fmaxf(mx, __shfl_xor(mx, 1, 64));
        mx = fmaxf(mx, __shfl_xor(mx, 2, 64));
        mx = fmaxf(mx, __shfl_xor(mx, 4, 64));
        mx = fmaxf(mx, __shfl_xor(mx, 8, 64));
        float p[16];
        float s = 0.f;
        #pragma unroll
        for (int j = 0; j < 16; j++) { p[j] = __expf(accA[j][slot] - mx); s += p[j]; }
        s += __shfl_xor(s, 1, 64);
        s += __shfl_xor(s, 2, 64);
        s += __shfl_xor(s, 4, 64);
        s += __shfl_xor(s, 8, 64);
        float inv = 1.f / s;
        int row = w * 16 + hi * 4 + slot;
        #pragma unroll
        for (int j = 0; j < 16; j++)
            Ps[row * 264 + j * 16 + lo] = f2b(p[j] * inv);
    }
    #pragma unroll
    for (int slot = 0; slot < 4; slot++) {
        float mx = accB[0][slot];
        #pragma unroll
        for (int j = 1; j < 16; j++) mx = fmaxf(mx, accB[j][slot]);
        mx = fmaxf(mx, __shfl_xor(mx, 1, 64));
        mx = fmaxf(mx, __shfl_xor(mx, 2, 64));
        mx = fmaxf(mx, __shfl_xor(mx, 4, 64));
        mx = fmaxf(mx, __shfl_xor(mx, 8, 64));
        float p[16];
        float s = 0.f;
        #pragma unroll
        for (int j = 0; j < 16; j++) { p[j] = __expf(accB[j][slot] - mx); s += p[j]; }
        s += __shfl_xor(s, 1, 64);
        s += __shfl_xor(s, 2, 64);
        s += __shfl_xor(s, 4, 64);
        s += __shfl_xor(s, 8, 64);
        float inv = 1.f / s;
        int row = 64 + w * 16 + hi * 4 + slot;
        #pragma unroll
        for (int j = 0; j < 16; j++)
            Ps[row * 264 + j * 16 + lo] = f2b(p[j] * inv);
    }
    // no barrier: each wave reads back only its own rows (lgkmcnt orders it)

    // ---- PV: both row groups, ZT fragments shared
    floatx4 acc2A[4], acc2B[4];
    #pragma unroll
    for (int j = 0; j < 4; j++) {
        acc2A[j] = (floatx4){0.f, 0.f, 0.f, 0.f};
        acc2B[j] = (floatx4){0.f, 0.f, 0.f, 0.f};
    }
    const u16* ztb = ZTh + ((size_t)hh * 64 + lo) * 256 + koff;
    int prA = (w * 16 + lo) * 264;
    int prB = (64 + w * 16 + lo) * 264;
    #pragma unroll
    for (int ks = 0; ks < 8; ks += 2) {
        short8 bz[8];
        #pragma unroll
        for (int j = 0; j < 4; j++)
            bz[j] = *(const short8*)(ztb + (size_t)j * 4096 + ks * 32);
        #pragma unroll
        for (int j = 0; j < 4; j++)
            bz[4 + j] = *(const short8*)(ztb + (size_t)j * 4096 + (ks + 1) * 32);
        short8 apA0 = *(const short8*)&Ps[prA + ks * 32 + koff];
        short8 apA1 = *(const short8*)&Ps[prA + (ks + 1) * 32 + koff];
        short8 apB0 = *(const short8*)&Ps[prB + ks * 32 + koff];
        short8 apB1 = *(const short8*)&Ps[prB + (ks + 1) * 32 + koff];
        #pragma unroll
        for (int j = 0; j < 4; j++) {
            acc2A[j] = __builtin_amdgcn_mfma_f32_16x16x32_bf16(apA0, bz[j], acc2A[j], 0, 0, 0);
            acc2B[j] = __builtin_amdgcn_mfma_f32_16x16x32_bf16(apB0, bz[j], acc2B[j], 0, 0, 0);
        }
        #pragma unroll
        for (int j = 0; j < 4; j++) {
            acc2A[j] = __builtin_amdgcn_mfma_f32_16x16x32_bf16(apA1, bz[4 + j], acc2A[j], 0, 0, 0);
            acc2B[j] = __builtin_amdgcn_mfma_f32_16x16x32_bf16(apB1, bz[4 + j], acc2B[j], 0, 0, 0);
        }
    }
    #pragma unroll
    for (int j = 0; j < 4; j++) {
        #pragma unroll
        for (int slot = 0; slot < 4; slot++) {
            int tokA = tok0 + w * 16 + hi * 4 + slot;
            if (tokA < LPAD)
                OUT[(size_t)tokA * 512 + hh * 64 + j * 16 + lo] = acc2A[j][slot];
            int tokB = tokA + 64;
            if (tokB < LPAD)
                OUT[(size_t)tokB * 512 + hh * 64 + j * 16 + lo] = acc2B[j][slot];
        }
    }
}

// ---------------------------------------------------------------------------
__global__ __launch_bounds__(256) void ln_kernel(
    const float* __restrict__ X, float* __restrict__ OUT, u16* __restrict__ OUTH,
    const float* __restrict__ g, const float* __restrict__ b, int nrows)
{
    int row = blockIdx.x * 4 + (threadIdx.x >> 6);
    int lane = threadIdx.x & 63;
    if (row >= nrows) return;
    const float* xr = X + (size_t)row * 512;
    float v[8]; float s = 0.f, s2 = 0.f;
    #pragma unroll
    for (int i = 0; i < 8; i++) { float t = xr[lane + i * 64]; v[i] = t; s += t; s2 += t * t; }
    for (int o = 1; o < 64; o <<= 1) { s += __shfl_xor(s, o, 64); s2 += __shfl_xor(s2, o, 64); }
    float mu = s * (1.f / 512.f);
    float var = s2 * (1.f / 512.f) - mu * mu;
    float rs = rsqrtf(var + 1e-5f);
    float* orow = OUT + (size_t)row * 512;
    u16* hrow = OUTH + (size_t)row * 512;
    #pragma unroll
    for (int i = 0; i < 8; i++) {
        int j = lane + i * 64;
        float y = (v[i] - mu) * rs * g[j] + b[j];
        orow[j] = y;
        hrow[j] = f2b(y);
    }
}

// Landmark means from bf16 QKVh; writes fp32 and bf16 copies
__global__ __launch_bounds__(64) void landmarks_kernel(
    const u16* __restrict__ QKVh, float* __restrict__ QL, float* __restrict__ KL,
    u16* __restrict__ QLh, u16* __restrict__ KLh)
{
    int mm = blockIdx.x, hh = blockIdx.y;
    int d = threadIdx.x;
    const u16* base = QKVh + (size_t)(mm * 40) * 1536 + hh * 64 + d;
    float sq = 0.f, sk = 0.f;
    for (int li = 0; li < 40; li++) {
        sq += b2f(base[(size_t)li * 1536]);
        sk += b2f(base[(size_t)li * 1536 + 512]);
    }
    size_t o = ((size_t)hh * 256 + mm) * 64 + d;
    float q = sq * (1.f / 40.f), k = sk * (1.f / 40.f);
    QL[o] = q; KL[o] = k;
    QLh[o] = f2b(q); KLh[o] = f2b(k);
}

// a2 softmax: wave per row (256 cols), fp32 in place
__global__ __launch_bounds__(256) void softmax_a2(
    float* __restrict__ A2, int nrows)
{
    int row = blockIdx.x * 4 + (threadIdx.x >> 6);
    int lane = threadIdx.x & 63;
    if (row >= nrows) return;
    float* p = A2 + (size_t)row * 256 + lane * 4;
    float4 v = *(float4*)p;
    float mx = fmaxf(fmaxf(v.x, v.y), fmaxf(v.z, v.w));
    for (int o = 1; o < 64; o <<= 1) mx = fmaxf(mx, __shfl_xor(mx, o, 64));
    float4 e = make_float4(__expf(v.x - mx), __expf(v.y - mx),
                           __expf(v.z - mx), __expf(v.w - mx));
    float s = e.x + e.y + e.z + e.w;
    for (int o = 1; o < 64; o <<= 1) s += __shfl_xor(s, o, 64);
    float inv = 1.f / s;
    e.x *= inv; e.y *= inv; e.z *= inv; e.w *= inv;
    *(float4*)p = e;
}

// block-per-row softmax (wide rows) -> bf16 probs, single global read via
// LDS row staging, float4 loads, packed bf16 stores.
__global__ __launch_bounds__(256) void row_softmax_bf16(
    const float* __restrict__ S, u16* __restrict__ P, int ncols)
{
    __shared__ float buf[LPAD];
    __shared__ float sr[4];
    int row = blockIdx.x;
    const float* p = S + (size_t)row * ncols;
    u16* q = P + (size_t)row * ncols;
    int tid = threadIdx.x;

    float mx = -1e30f;
    for (int i = tid * 4; i < ncols; i += 1024) {
        float4 v = *(const float4*)(p + i);
        *(float4*)&buf[i] = v;
        mx = fmaxf(mx, fmaxf(fmaxf(v.x, v.y), fmaxf(v.z, v.w)));
    }
    for (int o = 1; o < 64; o <<= 1) mx = fmaxf(mx, __shfl_xor(mx, o, 64));
    if ((tid & 63) == 0) sr[tid >> 6] = mx;
    __syncthreads();
    mx = fmaxf(fmaxf(sr[0], sr[1]), fmaxf(sr[2], sr[3]));

    float s = 0.f;
    for (int i = tid * 4; i < ncols; i += 1024) {
        float4 v = *(const float4*)&buf[i];
        s += __expf(v.x - mx) + __expf(v.y - mx) + __expf(v.z - mx) + __expf(v.w - mx);
    }
    for (int o = 1; o < 64; o <<= 1) s += __shfl_xor(s, o, 64);
    __syncthreads();
    if ((tid & 63) == 0) sr[tid >> 6] = s;
    __syncthreads();
    s = sr[0] + sr[1] + sr[2] + sr[3];
    float inv = 1.f / s;

    for (int i = tid * 4; i < ncols; i += 1024) {
        float4 v = *(const float4*)&buf[i];
        ushort4 o4;
        o4.x = f2b(__expf(v.x - mx) * inv);
        o4.y = f2b(__expf(v.y - mx) * inv);
        o4.z = f2b(__expf(v.z - mx) * inv);
        o4.w = f2b(__expf(v.w - mx) * inv);
        *(ushort4*)(q + i) = o4;
    }
}

__global__ __launch_bounds__(256) void a2norms_kernel(
    const float* __restrict__ A2, float* __restrict__ scal)
{
    int hh = blockIdx.x, tid = threadIdx.x;
    const float* A = A2 + (size_t)hh * 65536;
    float rs = 0.f, cs = 0.f;
    for (int j = 0; j < 256; j++) {
        rs += fabsf(A[(size_t)tid * 256 + j]);
        cs += fabsf(A[(size_t)j * 256 + tid]);
    }
    __shared__ float sm[8];
    for (int o = 1; o < 64; o <<= 1) {
        rs = fmaxf(rs, __shfl_xor(rs, o, 64));
        cs = fmaxf(cs, __shfl_xor(cs, o, 64));
    }
    if ((tid & 63) == 0) { sm[tid >> 6] = rs; sm[4 + (tid >> 6)] = cs; }
    __syncthreads();
    if (tid == 0) {
        float rm = fmaxf(fmaxf(sm[0], sm[1]), fmaxf(sm[2], sm[3]));
        float cm = fmaxf(fmaxf(sm[4], sm[5]), fmaxf(sm[6], sm[7]));
        atomicMax((unsigned int*)&scal[0], __float_as_uint(rm));
        atomicMax((unsigned int*)&scal[1], __float_as_uint(cm));
    }
}

// z0 = a2^T / denom (fp32 only)
__global__ __launch_bounds__(256) void z0_kernel(
    const float* __restrict__ A2, const float* __restrict__ scal,
    float* __restrict__ Zf)
{
    int i = blockIdx.x, hh = blockIdx.y, j = threadIdx.x;
    float inv = 1.f / (scal[0] * scal[1]);
    Zf[((size_t)hh * 256 + i) * 256 + j] = A2[((size_t)hh * 256 + j) * 256 + i] * inv;
}

// Tiny fused a1@Z for layer 1 (single token)
__global__ __launch_bounds__(256) void a1z_single(
    const u16* __restrict__ QKVh, const float* __restrict__ KL,
    const float* __restrict__ ZM, float* __restrict__ OUT, int tok)
{
    int h = blockIdx.x, tid = threadIdx.x;
    __shared__ float q[64];
    __shared__ float p[256];
    __shared__ float red[4];
    if (tid < 64) q[tid] = b2f(QKVh[(size_t)tok * 1536 + h * 64 + tid]);
    __syncthreads();
    const float* kl = KL + ((size_t)h * 256 + tid) * 64;
    float s = 0.f;
    for (int d = 0; d < 64; d++) s += q[d] * kl[d];
    float mx = s;
    for (int o = 1; o < 64; o <<= 1) mx = fmaxf(mx, __shfl_xor(mx, o, 64));
    if ((tid & 63) == 0) red[tid >> 6] = mx;
    __syncthreads();
    mx = fmaxf(fmaxf(red[0], red[1]), fmaxf(red[2], red[3]));
    float e = __expf(s - mx);
    float sum = e;
    for (int o = 1; o < 64; o <<= 1) sum += __shfl_xor(sum, o, 64);
    __syncthreads();
    if ((tid & 63) == 0) red[tid >> 6] = sum;
    __syncthreads();
    sum = red[0] + red[1] + red[2] + red[3];
    p[tid] = e / sum;
    __syncthreads();
    if (tid < 64) {
        float a = 0.f;
        for (int j = 0; j < 256; j++) a += p[j] * ZM[((size_t)h * 256 + j) * 64 + tid];
        OUT[(size_t)tok * 512 + h * 64 + tid] = a;
    }
}

// Depthwise 33-tap token conv fused with the bf16 cast.
__global__ __launch_bounds__(256) void conv_cast(
    const u16* __restrict__ QKVh, const float* __restrict__ OUT,
    u16* __restrict__ OUTH, const float* __restrict__ resw, int T0, int ntok)
{
    __shared__ u16 Vw[48][512];
    __shared__ float ws[264];
    int tid = threadIdx.x;
    int t0 = T0 + blockIdx.x * 16;
    int wv = tid >> 6, lnn = tid & 63;
    for (int r = wv; r < 48; r += 4) {
        int ts = t0 - 16 + r;
        short8 v = (short8){0,0,0,0,0,0,0,0};
        if (ts >= 0 && ts < LPAD)
            v = *(const short8*)(QKVh + (size_t)ts * 1536 + 1024 + lnn * 8);
        *(short8*)&Vw[r][lnn * 8] = v;
    }
    if (tid < 264) ws[tid] = resw[tid];
    __syncthreads();

    int c0 = tid * 2;
    int h = c0 >> 6;
    float wreg[33];
    #pragma unroll
    for (int r = 0; r < 33; r++) wreg[r] = ws[h * 33 + r];

    #pragma unroll 1
    for (int tk = 0; tk < 16; tk++) {
        int tok = t0 + tk;
        if (tok >= T0 + ntok) break;
        float a0 = 0.f, a1 = 0.f;
        #pragma unroll
        for (int r = 0; r < 33; r++) {
            unsigned pv = *(const unsigned*)&Vw[tk + r][c0];
            a0 += wreg[r] * __uint_as_float(pv << 16);
            a1 += wreg[r] * __uint_as_float(pv & 0xFFFF0000u);
        }
        float v0 = OUT[(size_t)tok * 512 + c0]     + a0;
        float v1 = OUT[(size_t)tok * 512 + c0 + 1] + a1;
        unsigned pk = ((unsigned)f2b(v1) << 16) | (unsigned)f2b(v0);
        *(unsigned*)&OUTH[(size_t)(tok - T0) * 512 + c0] = pk;
    }
}

// Old simple conv (layer 1, single token)
__global__ __launch_bounds__(256) void conv_res(
    const u16* __restrict__ QKVh, float* __restrict__ OUT,
    const float* __restrict__ resw, int t0, int ntok)
{
    int idx = blockIdx.x * 256 + threadIdx.x;
    if (idx >= ntok * 512) return;
    int tok = t0 + (idx >> 9);
    int c = idx & 511;
    int h = c >> 6;
    const u16* vbase = QKVh + 1024 + c;
    float acc = 0.f;
    #pragma unroll 1
    for (int r = 0; r < 33; r++) {
        int ts = tok - 16 + r;
        if (ts >= 0 && ts < LPAD)
            acc += resw[h * 33 + r] * b2f(vbase[(size_t)ts * 1536]);
    }
    OUT[(size_t)tok * 512 + c] += acc;
}

// V slice of QKVh -> Vt[h][d][t] (bf16)
__global__ __launch_bounds__(256) void vtrans(
    const u16* __restrict__ QKVh, u16* __restrict__ Vt)
{
    int t0 = blockIdx.x * 64, hh = blockIdx.y;
    __shared__ u16 tile[64][65];
    #pragma unroll
    for (int ii = 0; ii < 16; ii++) {
        int idx = threadIdx.x + ii * 256;
        int t = idx >> 6, d = idx & 63;
        tile[t][d] = QKVh[(size_t)(t0 + t) * 1536 + 1024 + hh * 64 + d];
    }
    __syncthreads();
    #pragma unroll
    for (int ii = 0; ii < 16; ii++) {
        int idx = threadIdx.x + ii * 256;
        int d = idx >> 6, t = idx & 63;
        Vt[((size_t)hh * 64 + d) * LPAD + t0 + t] = tile[t][d];
    }
}

// Combine PPEG weights: W49[tap][c] = w7 + w5(in range) + w3(in range)
__global__ void ppeg_combine(
    const float* __restrict__ w7, const float* __restrict__ w5,
    const float* __restrict__ w3, const float* __restrict__ b7,
    const float* __restrict__ b5, const float* __restrict__ b3,
    float* __restrict__ W49, float* __restrict__ BSUM)
{
    int idx = blockIdx.x * 256 + threadIdx.x;
    if (idx >= 49 * 512) return;
    int tap = idx >> 9, c = idx & 511;
    int dy = tap / 7 - 3, dx = tap % 7 - 3;
    float v = w7[c * 49 + tap];
    if (dy >= -2 && dy <= 2 && dx >= -2 && dx <= 2)
        v += w5[c * 25 + (dy + 2) * 5 + (dx + 2)];
    if (dy >= -1 && dy <= 1 && dx >= -1 && dx <= 1)
        v += w3[c * 9 + (dy + 1) * 3 + (dx + 1)];
    W49[tap * 512 + c] = v;
    if (tap == 0) BSUM[c] = b7[c] + b5[c] + b3[c];
}

// PPEG, tiled: block = 16x4 position tile x 64 channels, fully-unrolled
// float4 halo staging.
__global__ __launch_bounds__(256) void ppeg_tile(
    const float* __restrict__ S, float* __restrict__ O,
    const float* __restrict__ W49, const float* __restrict__ BSUM)
{
    __shared__ float Sw[10][22][64];
    int tid = threadIdx.x;
    int c = tid & 63;
    int sub = tid >> 6;
    int x0 = blockIdx.x * 16;
    int y0 = blockIdx.y * 4;
    int cg = blockIdx.z * 64;

    {
        int p = tid >> 4;
        int c4 = (tid & 15) * 4;
        #pragma unroll
        for (int i = 0; i < 14; i++) {
            int f = p + i * 16;
            if (f < 220) {
                int r = f / 22, xx = f - r * 22;
                int gy = y0 - 3 + r;
                int gx = x0 - 3 + xx;
                float4 v = make_float4(0.f, 0.f, 0.f, 0.f);
                if ((unsigned)gy < 100u && (unsigned)gx < 100u)
                    v = *(const float4*)(S + (size_t)(1 + gy * 100 + gx) * 512 + cg + c4);
                *(float4*)&Sw[r][xx][c4] = v;
            }
        }
    }
    float wreg[49];
    #pragma unroll
    for (int t = 0; t < 49; t++) wreg[t] = W49[t * 512 + cg + c];
    float bsum = BSUM[cg + c];
    __syncthreads();

    int xb = sub * 4;
    float acc[4][4];
    #pragma unroll
    for (int yy = 0; yy < 4; yy++)
        #pragma unroll
        for (int xq = 0; xq < 4; xq++)
            acc[yy][xq] = Sw[yy + 3][xb + xq + 3][c] + bsum;

    #pragma unroll
    for (int r = 0; r < 10; r++) {
        float v[10];
        #pragma unroll
        for (int j = 0; j < 10; j++) v[j] = Sw[r][xb + j][c];
        #pragma unroll
        for (int yy = 0; yy < 4; yy++) {
            int t = r - yy;
            if (t < 0 || t > 6) continue;
            #pragma unroll
            for (int dxt = 0; dxt < 7; dxt++) {
                float w = wreg[t * 7 + dxt];
                #pragma unroll
                for (int xq = 0; xq < 4; xq++)
                    acc[yy][xq] += v[xq + dxt] * w;
            }
        }
    }

    #pragma unroll
    for (int yy = 0; yy < 4; yy++) {
        int gy = y0 + yy;
        #pragma unroll
        for (int xq = 0; xq < 4; xq++) {
            int gx = x0 + xb + xq;
            if (gx < 100)
                O[(size_t)(1 + gy * 100 + gx) * 512 + cg + c] = acc[yy][xq];
        }
    }
}

__global__ __launch_bounds__(64) void final_kernel(
    const float* __restrict__ S, const float* __restrict__ g, const float* __restrict__ b,
    const float* __restrict__ w, const float* __restrict__ bb, float* __restrict__ out)
{
    int lane = threadIdx.x;
    float v[8]; float s = 0.f, s2 = 0.f;
    #pragma unroll
    for (int i = 0; i < 8; i++) { float t = S[lane + i * 64]; v[i] = t; s += t; s2 += t * t; }
    for (int o = 1; o < 64; o <<= 1) { s += __shfl_xor(s, o, 64); s2 += __shfl_xor(s2, o, 64); }
    float mu = s * (1.f / 512.f);
    float var = s2 * (1.f / 512.f) - mu * mu;
    float rs = rsqrtf(var + 1e-5f);
    float o0 = 0.f, o1 = 0.f;
    #pragma unroll
    for (int i = 0; i < 8; i++) {
        int j = lane + i * 64;
        float xn = (v[i] - mu) * rs * g[j] + b[j];
        o0 += xn * w[j * 2 + 0];
        o1 += xn * w[j * 2 + 1];
    }
    for (int o = 1; o < 64; o <<= 1) { o0 += __shfl_xor(o0, o, 64); o1 += __shfl_xor(o1, o, 64); }
    if (lane == 0) { out[0] = o0 + bb[0]; out[1] = o1 + bb[1]; }
}

__global__ void zerok(float* p, int n)
{
    int i = blockIdx.x * 256 + threadIdx.x;
    if (i < n) p[i] = 0.f;
}
__global__ void zero2k(float* p) { p[0] = 0.f; p[1] = 0.f; }
__global__ void copy512(float* dst, const float* src)
{
    int i = blockIdx.x * 256 + threadIdx.x;
    if (i < 512) dst[i] = src[i];
}
__global__ void cast_bf16(const float* __restrict__ src, u16* __restrict__ dst, int n)
{
    int i = (blockIdx.x * 256 + threadIdx.x) * 4;
    if (i >= n) return;
    float4 v = *(const float4*)(src + i);
    dst[i + 0] = f2b(v.x); dst[i + 1] = f2b(v.y);
    dst[i + 2] = f2b(v.z); dst[i + 3] = f2b(v.w);
}
// dst[b][c][r] = src[b][r][c]  (cast-transpose fp32 RxC -> bf16 CxR)
__global__ void castT(const float* __restrict__ src, u16* __restrict__ dst,
                      int R, int C, int nb)
{
    size_t idx = (size_t)blockIdx.x * 256 + threadIdx.x;
    size_t tot = (size_t)R * C * nb;
    if (idx >= tot) return;
    int rc = R * C;
    int b = (int)(idx / rc);
    int rem = (int)(idx - (size_t)b * rc);
    int c = rem / R, r = rem - c * R;
    dst[idx] = f2b(src[(size_t)b * rc + (size_t)r * C + c]);
}

// ---------------------------------------------------------------------------
extern "C" void kernel_launch(void* const* d_in, const int* in_sizes, int n_in,
                              void* d_out, int out_size, void* d_ws, size_t ws_size,
                              hipStream_t stream)
{
    const float* h     = (const float*)d_in[0];
    const float* fc1_w = (const float*)d_in[1];
    const float* fc1_b = (const float*)d_in[2];
    const float* cls   = (const float*)d_in[3];
    bool sigorder = (in_sizes[10] == 512 * 49);
    int i_l2 = sigorder ? 16 : 10;
    int i_pp = sigorder ? 10 : 16;
    const float* l_g[2]   = { (const float*)d_in[4], (const float*)d_in[i_l2 + 0] };
    const float* l_b[2]   = { (const float*)d_in[5], (const float*)d_in[i_l2 + 1] };
    const float* l_qkv[2] = { (const float*)d_in[6], (const float*)d_in[i_l2 + 2] };
    const float* l_ow[2]  = { (const float*)d_in[7], (const float*)d_in[i_l2 + 3] };
    const float* l_ob[2]  = { (const float*)d_in[8], (const float*)d_in[i_l2 + 4] };
    const float* l_rw[2]  = { (const float*)d_in[9], (const float*)d_in[i_l2 + 5] };
    const float* w7 = (const float*)d_in[i_pp + 0];
    const float* b7 = (const float*)d_in[i_pp + 1];
    const float* w5 = (const float*)d_in[i_pp + 2];
    const float* b5 = (const float*)d_in[i_pp + 3];
    const float* w3 = (const float*)d_in[i_pp + 4];
    const float* b3 = (const float*)d_in[i_pp + 5];
    const float* ng   = (const float*)d_in[22];
    const float* nbv  = (const float*)d_in[23];
    const float* fc2w = (const float*)d_in[24];
    const float* fc2b = (const float*)d_in[25];
    float* out = (float*)d_out;

    char* Wb = (char*)d_ws;
    size_t off = 0;
    auto allocB = [&](size_t bytes) { void* p = Wb + off; off = (off + bytes + 255) & ~(size_t)255; return p; };

    float* SEQ   = (float*)allocB((size_t)NSEQ * 512 * 4);
    float* XP    = (float*)allocB((size_t)LPAD * 512 * 4);
    u16*   XPh   = (u16*)  allocB((size_t)LPAD * 512 * 2);
    u16*   QKVh  = (u16*)  allocB((size_t)LPAD * 1536 * 2);
    float* QLKL  = (float*)allocB((size_t)262144 * 4);
    float* QL = QLKL, *KL = QLKL + 131072;
    u16*   QLKLh = (u16*)  allocB((size_t)262144 * 2);
    u16*   QLh = QLKLh, *KLh = QLKLh + 131072;
    float* A2   = (float*)allocB(524288 * 4);
    float* Zf0  = (float*)allocB(524288 * 4);
    float* Zf1  = (float*)allocB(524288 * 4);
    float* XZf  = (float*)allocB(524288 * 4);
    float* W2b  = (float*)allocB(524288 * 4);
    float* W3b  = (float*)allocB(524288 * 4);
    float* A3V  = (float*)allocB(131072 * 4);
    float* ZMATf= (float*)allocB(131072 * 4);
    u16*   ZMATt= (u16*)  allocB(131072 * 2);
    u16*   Vt   = (u16*)  allocB((size_t)8 * 64 * LPAD * 2);
    u16*   fc1wt= (u16*)  allocB(524288 * 2);
    u16*   qkvwt= (u16*)  allocB(786432 * 2);
    u16*   outwt= (u16*)  allocB(262144 * 2);
    float* W49  = (float*)allocB(49 * 512 * 4);
    float* BSUM = (float*)allocB(512 * 4);
    float* SCAL = (float*)allocB(16);
    void*  U1   = allocB((size_t)LPAD * 512 * 4);
    u16*   hbf  = (u16*)U1;
    float* OUT  = (float*)U1;
    float* SEQ2 = OUT;
    size_t fixed = off;

    size_t scB_b = (size_t)8 * 256 * LPAD * 4;
    size_t phB_b = (size_t)8 * 256 * LPAD * 2;
    bool batched = ws_size >= fixed + scB_b + phB_b;
    float* SC; u16* Ph;
    if (batched) {
        SC = (float*)(Wb + fixed);
        Ph = (u16*)(Wb + fixed + scB_b);
    } else {
        SC = (float*)(Wb + fixed);
        Ph = (u16*)(Wb + fixed + (size_t)256 * LPAD * 4);
    }
    u16* OUTh = (u16*)SC;   // alias: SC dead when OUTh materialized

    auto mgemm = [&](const u16* A, int lda, long sA, const u16* Bt, int ldb, long sB,
                     void* C, int ldc, long sC, int M, int N, int K,
                     const float* bias, const float* resid, int ldr,
                     int relu, int qscale, int obf16, int nbatch, int ksplit, int atomic) {
        dim3 grid((N + 127) / 128, (M + 63) / 64, nbatch * ksplit);
        gemm_mfma<<<grid, 256, 0, stream>>>(A, lda, sA, Bt, ldb, sB, C, ldc, sC,
            M, N, K, ksplit, bias, resid, ldr, relu, qscale, obf16, atomic);
    };
    auto fgemm = [&](const float* A, int lda, long sA, const float* B, int ldb, long sB,
                     float* C, int ldc, long sC, int M, int N, int K,
                     float alpha, float diagc, const float* bias,
                     const float* resid, int ldr, long sR, float rescoef,
                     int btrans, int nbatch) {
        dim3 grid(N / 64, (M + 15) / 16, nbatch);
        gemm_big<<<grid, 256, 0, stream>>>(A, lda, sA, B, ldb, sB, C, ldc, sC, M, N, K,
            alpha, diagc, bias, resid, ldr, sR, rescoef, btrans);
    };

    // ---- prologue
    cast_bf16<<<(NPIX * 1024 / 4 + 255) / 256, 256, 0, stream>>>(h, hbf, NPIX * 1024);
    castT<<<(524288 + 255) / 256, 256, 0, stream>>>(fc1_w, fc1wt, 1024, 512, 1);
    mgemm(hbf, 1024, 0, fc1wt, 1024, 0, SEQ + 512, 512, 0, NPIX, 512, 1024,
          fc1_b, nullptr, 0, 1, 0, 0, 1, 1, 0);
    copy512<<<2, 256, 0, stream>>>(SEQ, cls);
    zerok<<<(PADT * 512 + 255) / 256, 256, 0, stream>>>(XP, PADT * 512);
    zerok<<<(PADT * 256 + 255) / 256, 256, 0, stream>>>((float*)XPh, PADT * 256);
    ppeg_combine<<<(49 * 512 + 255) / 256, 256, 0, stream>>>(w7, w5, w3, b7, b5, b3, W49, BSUM);

    for (int layer = 0; layer < 2; layer++) {
        const float* curSEQ = (layer == 0) ? SEQ : SEQ2;
        ln_kernel<<<(NSEQ + 3) / 4, 256, 0, stream>>>(curSEQ, XP + (size_t)PADT * 512,
            XPh + (size_t)PADT * 512, l_g[layer], l_b[layer], NSEQ);
        castT<<<(786432 + 255) / 256, 256, 0, stream>>>(l_qkv[layer], qkvwt, 512, 1536, 1);
        mgemm(XPh, 512, 0, qkvwt, 512, 0, QKVh, 1536, 0, LPAD, 1536, 512,
              nullptr, nullptr, 0, 0, 1, 1, 1, 1, 0);
        landmarks_kernel<<<dim3(256, 8), 64, 0, stream>>>(QKVh, QL, KL, QLh, KLh);
        // a2 = softmax(ql @ kl^T)  (fp32)
        fgemm(QL, 64, 16384, KL, 64, 16384, A2, 256, 65536, 256, 256, 64,
              1.f, 0.f, nullptr, nullptr, 0, 0, 0.f, 1, 8);
        softmax_a2<<<512, 256, 0, stream>>>(A2, 2048);
        zero2k<<<1, 1, 0, stream>>>(SCAL);
        a2norms_kernel<<<8, 256, 0, stream>>>(A2, SCAL);
        z0_kernel<<<dim3(256, 8), 256, 0, stream>>>(A2, SCAL, Zf0);

        // Newton-Schulz: 6 fp32 iterations
        float* zc = Zf0; float* zn = Zf1;
        for (int it = 0; it < 6; it++) {
            fgemm(A2, 256, 65536, zc, 256, 65536, XZf, 256, 65536, 256, 256, 256,
                  1.f, 0.f, nullptr, nullptr, 0, 0, 0.f, 0, 8);
            fgemm(XZf, 256, 65536, XZf, 256, 65536, W2b, 256, 65536, 256, 256, 256,
                  1.f, 15.f, nullptr, XZf, 256, 65536, -7.f, 0, 8);
            fgemm(XZf, 256, 65536, W2b, 256, 65536, W3b, 256, 65536, 256, 256, 256,
                  -1.f, 13.f, nullptr, nullptr, 0, 0, 0.f, 0, 8);
            fgemm(zc, 256, 65536, W3b, 256, 65536, zn, 256, 65536, 256, 256, 256,
                  0.25f, 0.f, nullptr, nullptr, 0, 0, 0.f, 0, 8);
            float* t = zc; zc = zn; zn = t;
        }
        float* zfin = zc;

        // a3v = softmax(ql @ k^T) @ v  via MFMA
        vtrans<<<dim3(160, 8), 256, 0, stream>>>(QKVh, Vt);
        zerok<<<512, 256, 0, stream>>>(A3V, 131072);
        if (batched) {
            mgemm(QLh, 64, 16384, QKVh + 512, 1536, 64, SC, LPAD, (long)256 * LPAD,
                  256, LPAD, 64, nullptr, nullptr, 0, 0, 0, 0, 8, 1, 0);
            row_softmax_bf16<<<2048, 256, 0, stream>>>(SC, Ph, LPAD);
            mgemm(Ph, LPAD, (long)256 * LPAD, Vt, LPAD, (long)64 * LPAD, A3V, 64, 16384,
                  256, 64, LPAD, nullptr, nullptr, 0, 0, 0, 0, 8, 40, 1);
        } else {
            for (int hh = 0; hh < 8; hh++) {
                mgemm(QLh + (size_t)hh * 16384, 64, 0, QKVh + 512 + hh * 64, 1536, 0,
                      SC, LPAD, 0, 256, LPAD, 64, nullptr, nullptr, 0, 0, 0, 0, 1, 1, 0);
                row_softmax_bf16<<<256, 256, 0, stream>>>(SC, Ph, LPAD);
                mgemm(Ph, LPAD, 0, Vt + (size_t)hh * 64 * LPAD, LPAD, 0,
                      A3V + (size_t)hh * 16384, 64, 0, 256, 64, LPAD,
                      nullptr, nullptr, 0, 0, 0, 0, 1, 40, 1);
            }
        }
        // ZMAT = pinv(a2) @ a3v  (fp32)
        fgemm(zfin, 256, 65536, A3V, 64, 16384, ZMATf, 64, 16384, 256, 64, 256,
              1.f, 0.f, nullptr, nullptr, 0, 0, 0.f, 0, 8);

        if (layer == 0) {
            // Z^T bf16 for the fused a1 chain
            castT<<<(131072 + 255) / 256, 256, 0, stream>>>(ZMATf, ZMATt, 256, 64, 8);
            // fused scores+softmax+PZ: one launch, 128 tokens/block
            a1z_fused<<<dim3((NSEQ + 127) / 128, 8), 256, 0, stream>>>(
                QKVh, KLh, ZMATt, OUT, PADT);
            // conv + bf16 cast fused (writes OUTh directly)
            conv_cast<<<(NSEQ + 15) / 16, 256, 0, stream>>>(
                QKVh, OUT, OUTh, l_rw[0], PADT, NSEQ);
            castT<<<(262144 + 255) / 256, 256, 0, stream>>>(l_ow[0], outwt, 512, 512, 1);
            mgemm(OUTh, 512, 0, outwt, 512, 0, SEQ, 512, 0, NSEQ, 512, 512,
                  l_ob[0], XP + (size_t)PADT * 512, 512, 0, 0, 0, 1, 1, 0);
            // PPEG (tiled, unrolled float4 staging)
            ppeg_tile<<<dim3(7, 25, 8), 256, 0, stream>>>(SEQ, SEQ2, W49, BSUM);
            copy512<<<2, 256, 0, stream>>>(SEQ2, SEQ);
        } else {
            a1z_single<<<8, 256, 0, stream>>>(QKVh, KL, ZMATf, OUT, PADT);
            conv_res<<<2, 256, 0, stream>>>(QKVh, OUT, l_rw[1], PADT, 1);
            // dedicated M=1 out-projection matvec
            matvec_out<<<2, 256, 0, stream>>>(OUT + (size_t)PADT * 512, l_ow[1],
                                              l_ob[1], XP + (size_t)PADT * 512, SEQ);
        }
    }
    final_kernel<<<1, 64, 0, stream>>>(SEQ, ng, nbv, fc2w, fc2b, out);
    (void)n_in; (void)out_size;
}